// Round 13
// baseline (919.406 us; speedup 1.0000x reference)
//
#include <hip/hip_runtime.h>
#include <hip/hip_bf16.h>
#include <math.h>

#define Nn 512
#define Ee 768
#define Pp 64
#define PHh 32
#define Hh 8
#define Dd 96
#define NNe 262144      // N*N
#define LNEPS 1e-5f

typedef __attribute__((ext_vector_type(8))) short bf8;
typedef __attribute__((ext_vector_type(4))) short bf4;
typedef __attribute__((ext_vector_type(4))) float f32x4;
#define MFMA(a,b,c) __builtin_amdgcn_mfma_f32_16x16x32_bf16(a,b,c,0,0,0)

__device__ __forceinline__ short f2bf(float f) {
  __bf16 h = (__bf16)f;                 // native cast -> v_cvt_pk_bf16_f32 (RNE)
  return __builtin_bit_cast(short, h);
}
__device__ __forceinline__ float bf2f(short s) {
  unsigned u = ((unsigned)(unsigned short)s) << 16;
  return __builtin_bit_cast(float, u);
}

__device__ __forceinline__ float wave_red_sum(float v) {
#pragma unroll
  for (int off = 32; off > 0; off >>= 1) v += __shfl_xor(v, off);
  return v;
}
__device__ __forceinline__ float gelu_exact(float v) {
  return 0.5f * v * (1.f + erff(v * 0.70710678118654752f));
}
__device__ __forceinline__ float sigmoidf_(float v) {
  return 1.f / (1.f + __expf(-v));
}
__device__ __forceinline__ float gelu_fast(float v) {
  return v / (1.f + __expf(-1.702f * v));
}

// ---------------- weight casts to bf16 arena ----------------
__global__ __launch_bounds__(256) void castw_kernel(
    const float* __restrict__ wq, const float* __restrict__ wk,
    const float* __restrict__ wv, const float* __restrict__ wg,
    const float* __restrict__ wo, const float* __restrict__ f1,
    const float* __restrict__ f2, const float* __restrict__ wop,
    short* __restrict__ dst, float qs) {
  long i = (long)blockIdx.x * 256 + threadIdx.x;
  float v;
  if (i < 589824) v = wq[i] * qs;
  else if (i < 1179648) v = wk[i - 589824];
  else if (i < 1769472) v = wv[i - 1179648];
  else if (i < 2359296) v = wg[i - 1769472];
  else if (i < 2949120) v = wo[i - 2359296];
  else if (i < 5308416) v = f1[i - 2949120];
  else if (i < 7667712) v = f2[i - 5308416];
  else if (i < 7716864) v = wop[i - 7667712];
  else return;
  dst[i] = f2bf(v);
}

__global__ __launch_bounds__(256) void castw2_kernel(
    const float* __restrict__ wb, const float* __restrict__ abp,
    const float* __restrict__ abg, const float* __restrict__ wtg,
    const float* __restrict__ wtz, const float* __restrict__ p1,
    const float* __restrict__ p2, short* __restrict__ dst) {
  int i = blockIdx.x * 256 + threadIdx.x;
  float v;
  if (i < 512) v = wb[i];
  else if (i < 4608) v = abp[i - 512];
  else if (i < 8704) v = abg[i - 4608];
  else if (i < 12800) v = wtg[i - 8704];
  else if (i < 14848) v = wtz[i - 12800];
  else if (i < 18944) v = p1[i - 14848];
  else if (i < 23040) v = p2[i - 18944];
  else return;
  dst[i] = f2bf(v);
}

// ---------------- LayerNorm over last dim C -> bf16 out ----------------
__global__ __launch_bounds__(256) void ln_bf_kernel(const float* __restrict__ in,
                                                    short* __restrict__ out,
                                                    const float* __restrict__ gam,
                                                    const float* __restrict__ bet, int C) {
  int row = blockIdx.x;
  const float* xr = in + (long)row * C;
  short* yr = out + (long)row * C;
  float s = 0.f, ss = 0.f;
  for (int c = threadIdx.x; c < C; c += 256) { float v = xr[c]; s += v; ss += v * v; }
  s = wave_red_sum(s); ss = wave_red_sum(ss);
  __shared__ float sm[4][2];
  int wv = threadIdx.x >> 6, lane = threadIdx.x & 63;
  if (lane == 0) { sm[wv][0] = s; sm[wv][1] = ss; }
  __syncthreads();
  float ts = sm[0][0] + sm[1][0] + sm[2][0] + sm[3][0];
  float tss = sm[0][1] + sm[1][1] + sm[2][1] + sm[3][1];
  float mu = ts / C;
  float var = tss / C - mu * mu;
  float rs = rsqrtf(var + LNEPS);
  for (int c = threadIdx.x; c < C; c += 256) {
    float v = xr[c];
    yr[c] = f2bf((v - mu) * rs * gam[c] + bet[c]);
  }
}

// ---------------- bf16 MFMA NT GEMM, 64x64, BK=64 ----------------
__global__ __launch_bounds__(256) void gemm_bf(
    const short* __restrict__ A, int lda, long asB, long asH,
    const short* __restrict__ Bm, int ldb, long bsB, long bsH,
    float* __restrict__ outF, int ldf, long fsB, long fsH,
    short* __restrict__ outB, int ldob,
    const float* __restrict__ resid, int ldr, long rsB, long rsH,
    const float* __restrict__ bias,
    int M, int N, int K, int act, int vtrans, int Hdim) {
  int bz = blockIdx.z, bb = bz / Hdim, hh = bz % Hdim;
  A += bb * asB + hh * asH;
  Bm += bb * bsB + hh * bsH;
  if (outF) outF += bb * fsB + hh * fsH;
  if (outB) outB += bb * fsB + hh * fsH;
  if (resid) resid += bb * rsB + hh * rsH;
  __shared__ __align__(16) short As[64 * 72];
  __shared__ __align__(16) short Bs[64 * 72];
  int m0 = blockIdx.y * 64, n0 = blockIdx.x * 64;
  int tid = threadIdx.x;
  int wv = tid >> 6, lane = tid & 63;
  int wr = wv >> 1, wc = wv & 1;
  int lhi = lane >> 4, llo = lane & 15;
  int r4 = tid >> 2, c8 = (tid & 3) * 8;
  f32x4 acc[2][2] = {};
  for (int k0 = 0; k0 < K; k0 += 64) {
    *(bf8*)&As[r4 * 72 + c8] = *(const bf8*)(A + (long)(m0 + r4) * lda + k0 + c8);
    *(bf8*)&As[r4 * 72 + 32 + c8] =
        *(const bf8*)(A + (long)(m0 + r4) * lda + k0 + 32 + c8);
    bf8 bv0 = {}, bv1 = {};
    if (n0 + r4 < N) {
      bv0 = *(const bf8*)(Bm + (long)(n0 + r4) * ldb + k0 + c8);
      bv1 = *(const bf8*)(Bm + (long)(n0 + r4) * ldb + k0 + 32 + c8);
    }
    *(bf8*)&Bs[r4 * 72 + c8] = bv0;
    *(bf8*)&Bs[r4 * 72 + 32 + c8] = bv1;
    __syncthreads();
#pragma unroll
    for (int ks = 0; ks < 2; ++ks) {
      bf8 a0 = *(const bf8*)&As[(wr * 32 + llo) * 72 + ks * 32 + lhi * 8];
      bf8 a1 = *(const bf8*)&As[(wr * 32 + 16 + llo) * 72 + ks * 32 + lhi * 8];
      bf8 b0 = *(const bf8*)&Bs[(wc * 32 + llo) * 72 + ks * 32 + lhi * 8];
      bf8 b1 = *(const bf8*)&Bs[(wc * 32 + 16 + llo) * 72 + ks * 32 + lhi * 8];
      acc[0][0] = MFMA(a0, b0, acc[0][0]);
      acc[0][1] = MFMA(a0, b1, acc[0][1]);
      acc[1][0] = MFMA(a1, b0, acc[1][0]);
      acc[1][1] = MFMA(a1, b1, acc[1][1]);
    }
    __syncthreads();
  }
#pragma unroll
  for (int mi = 0; mi < 2; ++mi) {
    int gmb = m0 + wr * 32 + mi * 16 + lhi * 4;
#pragma unroll
    for (int ni = 0; ni < 2; ++ni) {
      int gn = n0 + wc * 32 + ni * 16 + llo;
      if (gn >= N) continue;
      float bv = bias ? bias[gn] : 0.f;
      float vr[4];
#pragma unroll
      for (int r = 0; r < 4; ++r) {
        float v = acc[mi][ni][r] + bv;
        if (resid) {
          float rv = resid[(long)(gmb + r) * ldr + gn];
          if (act == 2) v = sigmoidf_(rv) * acc[mi][ni][r];
          else v += rv;
        }
        if (act == 1) v = gelu_exact(v);
        vr[r] = v;
      }
      if (outF) {
#pragma unroll
        for (int r = 0; r < 4; ++r) outF[(long)(gmb + r) * ldf + gn] = vr[r];
      }
      if (outB) {
        if (vtrans) {
          bf4 pk;
#pragma unroll
          for (int r = 0; r < 4; ++r) pk[r] = f2bf(vr[r]);
          *(bf4*)(outB + ((long)((gmb >> 9) * 768 + gn) * 512 + (gmb & 511))) = pk;
        } else {
#pragma unroll
          for (int r = 0; r < 4; ++r) outB[(long)(gmb + r) * ldob + gn] = f2bf(vr[r]);
        }
      }
    }
  }
}

// ---------------- 128x128 tile: QKVG projection ----------------
__global__ __launch_bounds__(256) void gemm_qkvg(
    const short* __restrict__ A, const short* __restrict__ W,
    short* __restrict__ q_bf, short* __restrict__ k_bf,
    short* __restrict__ vT_bf, float* __restrict__ gb,
    const float* __restrict__ bg) {
  __shared__ __align__(16) short As[128 * 40];
  __shared__ __align__(16) short Bs[128 * 40];
  int m0 = blockIdx.y * 128, n0 = blockIdx.x * 128;
  int sec = n0 / 768;
  int cbase = n0 - sec * 768;
  int tid = threadIdx.x;
  int wv = tid >> 6, lane = tid & 63;
  int wr = wv >> 1, wc = wv & 1;
  int lhi = lane >> 4, llo = lane & 15;
  int r4 = tid >> 2, c8 = (tid & 3) * 8;
  f32x4 acc[4][4] = {};
  for (int k0 = 0; k0 < 768; k0 += 32) {
    *(bf8*)&As[r4 * 40 + c8] = *(const bf8*)(A + (long)(m0 + r4) * 768 + k0 + c8);
    *(bf8*)&As[(r4 + 64) * 40 + c8] =
        *(const bf8*)(A + (long)(m0 + r4 + 64) * 768 + k0 + c8);
    *(bf8*)&Bs[r4 * 40 + c8] = *(const bf8*)(W + (long)(n0 + r4) * 768 + k0 + c8);
    *(bf8*)&Bs[(r4 + 64) * 40 + c8] =
        *(const bf8*)(W + (long)(n0 + r4 + 64) * 768 + k0 + c8);
    __syncthreads();
    bf8 af[4], bfm[4];
#pragma unroll
    for (int mi = 0; mi < 4; ++mi)
      af[mi] = *(const bf8*)&As[(wr * 64 + mi * 16 + llo) * 40 + lhi * 8];
#pragma unroll
    for (int ni = 0; ni < 4; ++ni)
      bfm[ni] = *(const bf8*)&Bs[(wc * 64 + ni * 16 + llo) * 40 + lhi * 8];
#pragma unroll
    for (int mi = 0; mi < 4; ++mi)
#pragma unroll
      for (int ni = 0; ni < 4; ++ni)
        acc[mi][ni] = MFMA(af[mi], bfm[ni], acc[mi][ni]);
    __syncthreads();
  }
#pragma unroll
  for (int mi = 0; mi < 4; ++mi) {
    int gmb = m0 + wr * 64 + mi * 16 + lhi * 4;
#pragma unroll
    for (int ni = 0; ni < 4; ++ni) {
      int cn = cbase + wc * 64 + ni * 16 + llo;
      if (sec == 0) {
#pragma unroll
        for (int r = 0; r < 4; ++r) q_bf[(long)(gmb + r) * 768 + cn] = f2bf(acc[mi][ni][r]);
      } else if (sec == 1) {
#pragma unroll
        for (int r = 0; r < 4; ++r) k_bf[(long)(gmb + r) * 768 + cn] = f2bf(acc[mi][ni][r]);
      } else if (sec == 2) {
        bf4 pk;
#pragma unroll
        for (int r = 0; r < 4; ++r) pk[r] = f2bf(acc[mi][ni][r]);
        *(bf4*)(vT_bf + ((long)((gmb >> 9) * 768 + cn) * 512 + (gmb & 511))) = pk;
      } else {
        float bv = bg[cn];
#pragma unroll
        for (int r = 0; r < 4; ++r) gb[(long)(gmb + r) * 768 + cn] = acc[mi][ni][r] + bv;
      }
    }
  }
}

// ---------------- 128x128 tile: FFN1 (gelu exact, bf16 out) ----------------
__global__ __launch_bounds__(256) void gemm_ffn1(
    const short* __restrict__ A, const short* __restrict__ W,
    short* __restrict__ outB, const float* __restrict__ bias) {
  __shared__ __align__(16) short As[128 * 40];
  __shared__ __align__(16) short Bs[128 * 40];
  int m0 = blockIdx.y * 128, n0 = blockIdx.x * 128;
  int tid = threadIdx.x;
  int wv = tid >> 6, lane = tid & 63;
  int wr = wv >> 1, wc = wv & 1;
  int lhi = lane >> 4, llo = lane & 15;
  int r4 = tid >> 2, c8 = (tid & 3) * 8;
  f32x4 acc[4][4] = {};
  for (int k0 = 0; k0 < 768; k0 += 32) {
    *(bf8*)&As[r4 * 40 + c8] = *(const bf8*)(A + (long)(m0 + r4) * 768 + k0 + c8);
    *(bf8*)&As[(r4 + 64) * 40 + c8] =
        *(const bf8*)(A + (long)(m0 + r4 + 64) * 768 + k0 + c8);
    *(bf8*)&Bs[r4 * 40 + c8] = *(const bf8*)(W + (long)(n0 + r4) * 768 + k0 + c8);
    *(bf8*)&Bs[(r4 + 64) * 40 + c8] =
        *(const bf8*)(W + (long)(n0 + r4 + 64) * 768 + k0 + c8);
    __syncthreads();
    bf8 af[4], bfm[4];
#pragma unroll
    for (int mi = 0; mi < 4; ++mi)
      af[mi] = *(const bf8*)&As[(wr * 64 + mi * 16 + llo) * 40 + lhi * 8];
#pragma unroll
    for (int ni = 0; ni < 4; ++ni)
      bfm[ni] = *(const bf8*)&Bs[(wc * 64 + ni * 16 + llo) * 40 + lhi * 8];
#pragma unroll
    for (int mi = 0; mi < 4; ++mi)
#pragma unroll
      for (int ni = 0; ni < 4; ++ni)
        acc[mi][ni] = MFMA(af[mi], bfm[ni], acc[mi][ni]);
    __syncthreads();
  }
#pragma unroll
  for (int mi = 0; mi < 4; ++mi) {
    int gmb = m0 + wr * 64 + mi * 16 + lhi * 4;
#pragma unroll
    for (int ni = 0; ni < 4; ++ni) {
      int gn = n0 + wc * 64 + ni * 16 + llo;
      float bv = bias[gn];
#pragma unroll
      for (int r = 0; r < 4; ++r)
        outB[(long)(gmb + r) * 3072 + gn] = f2bf(gelu_exact(acc[mi][ni][r] + bv));
    }
  }
}

// ---------------- 128x128 tile: generic NT fp32 out + resid + bias (wo, ffn2) ----------
__global__ __launch_bounds__(256) void gemm128(
    const short* __restrict__ A, const short* __restrict__ W, int K,
    const float* __restrict__ resid, const float* __restrict__ bias,
    float* __restrict__ outF) {
  __shared__ __align__(16) short As[128 * 40];
  __shared__ __align__(16) short Bs[128 * 40];
  int m0 = blockIdx.y * 128, n0 = blockIdx.x * 128;
  int tid = threadIdx.x;
  int wv = tid >> 6, lane = tid & 63;
  int wr = wv >> 1, wc = wv & 1;
  int lhi = lane >> 4, llo = lane & 15;
  int r4 = tid >> 2, c8 = (tid & 3) * 8;
  f32x4 acc[4][4] = {};
  for (int k0 = 0; k0 < K; k0 += 32) {
    *(bf8*)&As[r4 * 40 + c8] = *(const bf8*)(A + (long)(m0 + r4) * K + k0 + c8);
    *(bf8*)&As[(r4 + 64) * 40 + c8] =
        *(const bf8*)(A + (long)(m0 + r4 + 64) * K + k0 + c8);
    *(bf8*)&Bs[r4 * 40 + c8] = *(const bf8*)(W + (long)(n0 + r4) * K + k0 + c8);
    *(bf8*)&Bs[(r4 + 64) * 40 + c8] =
        *(const bf8*)(W + (long)(n0 + r4 + 64) * K + k0 + c8);
    __syncthreads();
    bf8 af[4], bfm[4];
#pragma unroll
    for (int mi = 0; mi < 4; ++mi)
      af[mi] = *(const bf8*)&As[(wr * 64 + mi * 16 + llo) * 40 + lhi * 8];
#pragma unroll
    for (int ni = 0; ni < 4; ++ni)
      bfm[ni] = *(const bf8*)&Bs[(wc * 64 + ni * 16 + llo) * 40 + lhi * 8];
#pragma unroll
    for (int mi = 0; mi < 4; ++mi)
#pragma unroll
      for (int ni = 0; ni < 4; ++ni)
        acc[mi][ni] = MFMA(af[mi], bfm[ni], acc[mi][ni]);
    __syncthreads();
  }
#pragma unroll
  for (int mi = 0; mi < 4; ++mi) {
    int gmb = m0 + wr * 64 + mi * 16 + lhi * 4;
#pragma unroll
    for (int ni = 0; ni < 4; ++ni) {
      int gn = n0 + wc * 64 + ni * 16 + llo;
      float bv = bias[gn];
#pragma unroll
      for (int r = 0; r < 4; ++r)
        outF[(long)(gmb + r) * 768 + gn] =
            acc[mi][ni][r] + bv + resid[(long)(gmb + r) * 768 + gn];
    }
  }
}

// ---------------- fused scores + softmax (flash-row, 16 rows/block) ----------------
__global__ __launch_bounds__(256) void attn_fused(
    const short* __restrict__ q_bf, const short* __restrict__ k_bf,
    const short* __restrict__ bias_bf, const float* __restrict__ mask,
    short* __restrict__ out_bf) {
  int it = blockIdx.x, h = blockIdx.y, b = blockIdx.z;
  int tid = threadIdx.x;
  int wv = tid >> 6, lane = tid & 63;
  int lhi = lane >> 4, llo = lane & 15;
  int i0 = it * 16;
  long qoff = ((long)(b * 512 + i0)) * 768 + h * 96;
  bf8 qf[3];
#pragma unroll
  for (int ks = 0; ks < 3; ++ks)
    qf[ks] = *(const bf8*)(q_bf + qoff + (long)llo * 768 + ks * 32 + lhi * 8);
  long koff = ((long)b * 512) * 768 + h * 96;
  long bioff = (long)(b * 8 + h) * NNe + (long)i0 * 512;
  long moff = (long)b * NNe + (long)i0 * 512;
  float sv[8][4];
  int jb0 = wv * 128;
#pragma unroll
  for (int jf = 0; jf < 8; ++jf) {
    int jb = jb0 + jf * 16;
    f32x4 acc = {0.f, 0.f, 0.f, 0.f};
#pragma unroll
    for (int ks = 0; ks < 3; ++ks) {
      bf8 kf = *(const bf8*)(k_bf + koff + (long)(jb + llo) * 768 + ks * 32 + lhi * 8);
      acc = MFMA(qf[ks], kf, acc);
    }
#pragma unroll
    for (int r = 0; r < 4; ++r) {
      int irow = lhi * 4 + r;
      int j = jb + llo;
      float bia = bf2f(bias_bf[bioff + (long)irow * 512 + j]);
      float mk = mask[moff + (long)irow * 512 + j];
      sv[jf][r] = acc[r] + bia + mk;
    }
  }
  __shared__ float redA[4][20];
  __shared__ float redB[4][20];
  float rmax[4];
#pragma unroll
  for (int r = 0; r < 4; ++r) {
    float m = sv[0][r];
#pragma unroll
    for (int jf = 1; jf < 8; ++jf) m = fmaxf(m, sv[jf][r]);
#pragma unroll
    for (int off = 1; off < 16; off <<= 1) m = fmaxf(m, __shfl_xor(m, off, 16));
    if (llo == 0) redA[wv][lhi * 4 + r] = m;
  }
  __syncthreads();
#pragma unroll
  for (int r = 0; r < 4; ++r) {
    int row = lhi * 4 + r;
    rmax[r] = fmaxf(fmaxf(redA[0][row], redA[1][row]),
                    fmaxf(redA[2][row], redA[3][row]));
  }
  float rsum[4] = {0.f, 0.f, 0.f, 0.f};
#pragma unroll
  for (int jf = 0; jf < 8; ++jf)
#pragma unroll
    for (int r = 0; r < 4; ++r) {
      float e = __expf(sv[jf][r] - rmax[r]);
      sv[jf][r] = e;
      rsum[r] += e;
    }
#pragma unroll
  for (int r = 0; r < 4; ++r) {
#pragma unroll
    for (int off = 1; off < 16; off <<= 1) rsum[r] += __shfl_xor(rsum[r], off, 16);
    if (llo == 0) redB[wv][lhi * 4 + r] = rsum[r];
  }
  __syncthreads();
#pragma unroll
  for (int r = 0; r < 4; ++r) {
    int row = lhi * 4 + r;
    float s = redB[0][row] + redB[1][row] + redB[2][row] + redB[3][row];
    float inv = 1.f / s;
#pragma unroll
    for (int jf = 0; jf < 8; ++jf) {
      int j = jb0 + jf * 16 + llo;
      out_bf[bioff + (long)row * 512 + j] = f2bf(sv[jf][r] * inv);
    }
  }
}

// ---------------- ab *= op_mask ; emit b-half bf16 ----------------
__global__ __launch_bounds__(256) void opmask_kernel(float* __restrict__ ab,
                                                     const float* __restrict__ mask,
                                                     short* __restrict__ bo_bf) {
  int idx = blockIdx.x * 256 + threadIdx.x;
  if (idx < 131072) {
    float v = ab[idx] * mask[idx >> 6];
    ab[idx] = v;
    int ch = idx & 63;
    if (ch >= 32) bo_bf[(idx >> 6) * 32 + ch - 32] = f2bf(v);
  }
}

// ---------------- T[row,p,e] (bf16) ----------------
__global__ __launch_bounds__(256) void opm_T_kernel(const float* __restrict__ ab,
                                                    const float* __restrict__ w,
                                                    short* __restrict__ T) {
  int p = blockIdx.y;
  int row = blockIdx.x * 8 + threadIdx.y;
  int e = threadIdx.x;
  const float* a = ab + (long)row * 64;
  const float* wp = w + p * 1024 + e;
  float acc = 0.f;
#pragma unroll
  for (int d = 0; d < 32; ++d) acc += a[d] * wp[d * 32];
  T[((long)row * 64 + p) * 32 + e] = f2bf(acc);
}

// ---------------- pair bias: register LN ----------------
__global__ __launch_bounds__(256) void pair_bias_mfma(
    const float* __restrict__ pair, const float* __restrict__ gam,
    const float* __restrict__ bet, const short* __restrict__ wb_a,
    const float* __restrict__ bbv, short* __restrict__ bias) {
  __shared__ __align__(16) short Zb[64 * 72];
  __shared__ __align__(16) short Wb[16 * 72];
  __shared__ float sp[4][2][72];
  int tid = threadIdx.x;
  long e0 = (long)blockIdx.x * 64;
  int b = (int)(e0 >> 18);
  long ein = e0 & (NNe - 1);
  const float* base = pair + e0 * 64;
  for (int l = tid; l < 1024; l += 256) {
    int h = l >> 6, c = l & 63;
    Wb[h * 72 + c] = (h < 8) ? wb_a[h * 64 + c] : (short)0;
  }
  int e = tid & 63, q = tid >> 6;
  f32x4 v4[4];
  float s = 0.f, ss = 0.f;
#pragma unroll
  for (int k = 0; k < 4; ++k) {
    v4[k] = *(const f32x4*)(base + (long)e * 64 + q * 16 + k * 4);
#pragma unroll
    for (int u = 0; u < 4; ++u) { float v = v4[k][u]; s += v; ss += v * v; }
  }
  sp[q][0][e] = s; sp[q][1][e] = ss;
  __syncthreads();
  float ts = sp[0][0][e] + sp[1][0][e] + sp[2][0][e] + sp[3][0][e];
  float tss = sp[0][1][e] + sp[1][1][e] + sp[2][1][e] + sp[3][1][e];
  float mu = ts * 0.015625f, var = tss * 0.015625f - mu * mu;
  float rs = rsqrtf(var + LNEPS);
#pragma unroll
  for (int k = 0; k < 4; ++k) {
    bf4 pk;
#pragma unroll
    for (int u = 0; u < 4; ++u) {
      int c = q * 16 + k * 4 + u;
      pk[u] = f2bf((v4[k][u] - mu) * rs * gam[c] + bet[c]);
    }
    *(bf4*)&Zb[e * 72 + q * 16 + k * 4] = pk;
  }
  __syncthreads();
  int wv = tid >> 6, lane = tid & 63;
  int lhi = lane >> 4, llo = lane & 15;
  int n0 = wv * 16;
  f32x4 acc = {0.f, 0.f, 0.f, 0.f};
#pragma unroll
  for (int ks = 0; ks < 2; ++ks) {
    bf8 a = *(const bf8*)&Wb[llo * 72 + ks * 32 + lhi * 8];
    bf8 bz = *(const bf8*)&Zb[(n0 + llo) * 72 + ks * 32 + lhi * 8];
    acc = MFMA(a, bz, acc);
  }
  int elem = n0 + llo;
#pragma unroll
  for (int r = 0; r < 4; ++r) {
    int h = lhi * 4 + r;
    if (h < 8) bias[(long)(b * 8 + h) * NNe + ein + elem] = f2bf(acc[r] + bbv[h]);
  }
}

// -------- opm + triangle ab (batched z=4, fp32 pair reads, LDS W) --------
__global__ __launch_bounds__(256) void opm_ab_fused(
    const float* __restrict__ pair_in, const short* __restrict__ Tb,
    const short* __restrict__ bo_bf, const float* __restrict__ b_out,
    const float* __restrict__ op_norm, const float* __restrict__ gam,
    const float* __restrict__ bet, const short* __restrict__ wp_a,
    const float* __restrict__ b_abp, const short* __restrict__ wg_a,
    const float* __restrict__ b_abg,
    short* __restrict__ aN4, short* __restrict__ bN4) {
  int jt = blockIdx.x;   // 0..7
  int i = blockIdx.y;    // 0..511
  int bb = blockIdx.z;   // 0..3
  int tid = threadIdx.x;
  __shared__ __align__(16) short Zb[64 * 72];
  __shared__ __align__(16) short Wp[64 * 72];
  __shared__ __align__(16) short Wg[64 * 72];
  __shared__ float spS[64][9];
  __shared__ float spQ[64][9];
  int wv = tid >> 6, lane = tid & 63;
  int wr = wv >> 1, wc = wv & 1;
  int lhi = lane >> 4, llo = lane & 15;
  int chb = wr * 32 + lhi * 4;
  int fc = lhi * 8;
  for (int l = tid; l < 512; l += 256) {
    int r = l >> 3, c8 = (l & 7) * 8;
    *(bf8*)&Wp[r * 72 + c8] = *(const bf8*)(wp_a + r * 64 + c8);
    *(bf8*)&Wg[r * 72 + c8] = *(const bf8*)(wg_a + r * 64 + c8);
  }
  long grow = (long)bb * 512 + i;
  long ebase = (long)i * 512 + jt * 64;
  const float* pbase = pair_in + ((long)bb * NNe + ebase) * 64;
  short* aN = aN4 + (long)bb * 8388608;
  short* bN = bN4 + (long)bb * 8388608;
  f32x4 x[2][2];
#pragma unroll
  for (int mi = 0; mi < 2; ++mi)
#pragma unroll
    for (int ni = 0; ni < 2; ++ni)
      x[mi][ni] = *(const f32x4*)(pbase + (long)(wc * 32 + ni * 16 + llo) * 64 +
                                  chb + mi * 16);
  {
    f32x4 acc[2][2] = {};
    bf8 a0 = *(const bf8*)(Tb + grow * 2048 + (long)(wr * 32 + llo) * 32 + fc);
    bf8 a1 = *(const bf8*)(Tb + grow * 2048 + (long)(wr * 32 + 16 + llo) * 32 + fc);
    bf8 b0 = *(const bf8*)(bo_bf + ((long)bb * 512 + jt * 64 + wc * 32 + llo) * 32 + fc);
    bf8 b1 = *(const bf8*)(bo_bf +
                           ((long)bb * 512 + jt * 64 + wc * 32 + 16 + llo) * 32 + fc);
    acc[0][0] = MFMA(a0, b0, acc[0][0]);
    acc[0][1] = MFMA(a0, b1, acc[0][1]);
    acc[1][0] = MFMA(a1, b0, acc[1][0]);
    acc[1][1] = MFMA(a1, b1, acc[1][1]);
    float nrm = op_norm[0];
#pragma unroll
    for (int mi = 0; mi < 2; ++mi) {
      f32x4 bo4 = *(const f32x4*)(b_out + chb + mi * 16);
#pragma unroll
      for (int ni = 0; ni < 2; ++ni)
#pragma unroll
        for (int r = 0; r < 4; ++r)
          x[mi][ni][r] += (acc[mi][ni][r] + bo4[r]) * nrm;
    }
  }
#pragma unroll
  for (int ni = 0; ni < 2; ++ni) {
    float s = 0.f, ss = 0.f;
#pragma unroll
    for (int mi = 0; mi < 2; ++mi)
#pragma unroll
      for (int r = 0; r < 4; ++r) { float v = x[mi][ni][r]; s += v; ss += v * v; }
    int e = wc * 32 + ni * 16 + llo;
    spS[e][wr * 4 + lhi] = s;
    spQ[e][wr * 4 + lhi] = ss;
  }
  __syncthreads();   // (1)
  float mu1[2], rs1[2];
#pragma unroll
  for (int ni = 0; ni < 2; ++ni) {
    int e = wc * 32 + ni * 16 + llo;
    float s = 0.f, q2 = 0.f;
#pragma unroll
    for (int k = 0; k < 8; ++k) { s += spS[e][k]; q2 += spQ[e][k]; }
    float mu = s * 0.015625f, var = q2 * 0.015625f - mu * mu;
    mu1[ni] = mu; rs1[ni] = rsqrtf(var + LNEPS);
  }
#pragma unroll
  for (int mi = 0; mi < 2; ++mi) {
    f32x4 gv = *(const f32x4*)(gam + chb + mi * 16);
    f32x4 bv = *(const f32x4*)(bet + chb + mi * 16);
#pragma unroll
    for (int ni = 0; ni < 2; ++ni) {
      int e = wc * 32 + ni * 16 + llo;
      bf4 pk;
#pragma unroll
      for (int r = 0; r < 4; ++r)
        pk[r] = f2bf((x[mi][ni][r] - mu1[ni]) * rs1[ni] * gv[r] + bv[r]);
      *(bf4*)&Zb[e * 72 + chb + mi * 16] = pk;
    }
  }
  __syncthreads();   // (2)
  f32x4 ap[2][2] = {};
  f32x4 ag[2][2] = {};
#pragma unroll
  for (int ks = 0; ks < 2; ++ks) {
    bf8 z0 = *(const bf8*)&Zb[(wr * 32 + llo) * 72 + ks * 32 + fc];
    bf8 z1 = *(const bf8*)&Zb[(wr * 32 + 16 + llo) * 72 + ks * 32 + fc];
    bf8 p0 = *(const bf8*)&Wp[(wc * 32 + llo) * 72 + ks * 32 + fc];
    bf8 p1 = *(const bf8*)&Wp[(wc * 32 + 16 + llo) * 72 + ks * 32 + fc];
    bf8 g0 = *(const bf8*)&Wg[(wc * 32 + llo) * 72 + ks * 32 + fc];
    bf8 g1 = *(const bf8*)&Wg[(wc * 32 + 16 + llo) * 72 + ks * 32 + fc];
    ap[0][0] = MFMA(z0, p0, ap[0][0]);
    ap[0][1] = MFMA(z0, p1, ap[0][1]);
    ap[1][0] = MFMA(z1, p0, ap[1][0]);
    ap[1][1] = MFMA(z1, p1, ap[1][1]);
    ag[0][0] = MFMA(z0, g0, ag[0][0]);
    ag[0][1] = MFMA(z0, g1, ag[0][1]);
    ag[1][0] = MFMA(z1, g0, ag[1][0]);
    ag[1][1] = MFMA(z1, g1, ag[1][1]);
  }
#pragma unroll
  for (int mi = 0; mi < 2; ++mi) {
    int elemb = wr * 32 + mi * 16 + lhi * 4;
#pragma unroll
    for (int ni = 0; ni < 2; ++ni) {
      int ch = wc * 32 + ni * 16 + llo;
      float bp = b_abp[ch], bg = b_abg[ch];
      bf4 pack;
#pragma unroll
      for (int r = 0; r < 4; ++r)
        pack[r] = f2bf((ap[mi][ni][r] + bp) * sigmoidf_(ag[mi][ni][r] + bg));
      short* dst = (ch < 32) ? (aN + (long)ch * NNe) : (bN + (long)(ch - 32) * NNe);
      *(bf4*)(dst + ebase + elemb) = pack;
    }
  }
}

// ---------------- triangle einsum -> t bf16 (128x128 tile, batched, XCD swizzle) --------
__global__ __launch_bounds__(512) void tm_tri_mfma(const short* __restrict__ aN4,
                                                   const short* __restrict__ bN4,
                                                   short* __restrict__ t4) {
  int lin = blockIdx.z * 16 + blockIdx.y * 4 + blockIdx.x;   // 0..2047
  int vid = (lin & 7) * 256 + (lin >> 3);                    // bijective
  int hh = vid >> 4;        // 0..127
  int b = hh >> 5, h = hh & 31;
  int rem = vid & 15;
  int i0 = (rem >> 2) * 128, k0 = (rem & 3) * 128;
  const short* A = aN4 + (long)b * 8388608 + (long)h * NNe;
  const short* B = bN4 + (long)b * 8388608 + (long)h * NNe;
  __shared__ __align__(16) short A1[128 * 40];
  __shared__ __align__(16) short B1[128 * 40];
  __shared__ __align__(16) short A2[128 * 40];
  __shared__ __align__(16) short B2[128 * 40];
  int tid = threadIdx.x;
  int wv = tid >> 6, lane = tid & 63;
  int wr = wv >> 2, wc = wv & 3;
  int lhi = lane >> 4, llo = lane & 15;
  int r1 = tid >> 2, cp = (tid & 3) * 8;
  int s2 = tid >> 5, cg = (tid & 31) * 4;
  f32x4 acc[4][2] = {};
  for (int j0 = 0; j0 < 512; j0 += 32) {
    *(bf8*)&A1[r1 * 40 + cp] = *(const bf8*)(A + (long)(i0 + r1) * 512 + j0 + cp);
    *(bf8*)&B1[r1 * 40 + cp] = *(const bf8*)(B + (long)(k0 + r1) * 512 + j0 + cp);
    bf4 va0 = *(const bf4*)(A + (long)(j0 + 2 * s2) * 512 + i0 + cg);
    bf4 va1 = *(const bf4*)(A + (long)(j0 + 2 * s2 + 1) * 512 + i0 + cg);
    bf4 vb0 = *(const bf4*)(B + (long)(j0 + 2 * s2) * 512 + k0 + cg);
    bf4 vb1 = *(const bf4*)(B + (long)(j0 + 2 * s2 + 1) * 512 + k0 + cg);
#pragma unroll
    for (int q = 0; q < 4; ++q) {
      unsigned pa = (unsigned)(unsigned short)va0[q] |
                    ((unsigned)(unsigned short)va1[q] << 16);
      unsigned pb = (unsigned)(unsigned short)vb0[q] |
                    ((unsigned)(unsigned short)vb1[q] << 16);
      *(unsigned*)&A2[(cg + q) * 40 + 2 * s2] = pa;
      *(unsigned*)&B2[(cg + q) * 40 + 2 * s2] = pb;
    }
    __syncthreads();
    bf8 bfr[2], dfr[2];
#pragma unroll
    for (int ni = 0; ni < 2; ++ni) {
      bfr[ni] = *(const bf8*)&B1[(wc * 32 + ni * 16 + llo) * 40 + lhi * 8];
      dfr[ni] = *(const bf8*)&B2[(wc * 32 + ni * 16 + llo) * 40 + lhi * 8];
    }
#pragma unroll
    for (int mi = 0; mi < 4; ++mi) {
      bf8 a = *(const bf8*)&A1[(wr * 64 + mi * 16 + llo) * 40 + lhi * 8];
      acc[mi][0] = MFMA(a, bfr[0], acc[mi][0]);
      acc[mi][1] = MFMA(a, bfr[1], acc[mi][1]);
    }
#pragma unroll
    for (int mi = 0; mi < 4; ++mi) {
      bf8 c = *(const bf8*)&A2[(wr * 64 + mi * 16 + llo) * 40 + lhi * 8];
      acc[mi][0] = MFMA(c, dfr[0], acc[mi][0]);
      acc[mi][1] = MFMA(c, dfr[1], acc[mi][1]);
    }
    __syncthreads();
  }
  short* tp = t4 + (long)b * 8388608 + (long)h * NNe;
#pragma unroll
  for (int mi = 0; mi < 4; ++mi)
#pragma unroll
    for (int ni = 0; ni < 2; ++ni) {
      int row = i0 + wr * 64 + mi * 16 + lhi * 4;
      int col = k0 + wc * 32 + ni * 16 + llo;
#pragma unroll
      for (int r = 0; r < 4; ++r) tp[(long)(row + r) * 512 + col] = f2bf(acc[mi][ni][r]);
    }
}

// --- fused OPM-recompute + triangle update + pair FFN (batched, fp32 in/out) ---
__global__ __launch_bounds__(256) void upd_pffn_fused(
    const float* __restrict__ pin, float* __restrict__ pout,
    const short* __restrict__ t4,
    const short* __restrict__ Tb, const short* __restrict__ bo_bf,
    const float* __restrict__ b_out, const float* __restrict__ op_norm,
    const float* __restrict__ g_tm, const float* __restrict__ b_tm,
    const short* __restrict__ wg_a, const float* __restrict__ b_g,
    const short* __restrict__ wz_a, const float* __restrict__ b_z,
    const float* __restrict__ g_tmo, const float* __restrict__ b_tmo,
    const float* __restrict__ g_pf, const float* __restrict__ b_pf,
    const short* __restrict__ w1_a, const float* __restrict__ b1,
    const short* __restrict__ w2_a, const float* __restrict__ b2) {
  __shared__ __align__(16) short Zb[64 * 72];
  __shared__ __align__(16) short Tlb[64 * 40];
  __shared__ __align__(16) short Wbuf[64 * 72];
  __shared__ __align__(16) short Wzb[64 * 36];
  __shared__ float spS[64][9];
  __shared__ float spQ[64][9];
  __shared__ float spB[4][2][72];
  int tid = threadIdx.x;
  long e0 = (long)blockIdx.x * 64;
  int bbt = (int)(e0 >> 18);
  long el = e0 & (NNe - 1);
  long growT = e0 >> 9;
  int jt = (int)((e0 >> 6) & 7);
  int wv = tid >> 6, lane = tid & 63;
  int wr = wv >> 1, wc = wv & 1;
  int lhi = lane >> 4, llo = lane & 15;
  int chb = wr * 32 + lhi * 4;
  int fc = lhi * 8;
  int fr0 = wr * 32 + llo, fr1 = fr0 + 16;
  int br0 = wc * 32 + llo, br1 = br0 + 16;
  int r0 = tid >> 3, c0 = (tid & 7) * 8;
  int r1 = (tid + 256) >> 3, c1 = ((tid + 256) & 7) * 8;
  bf8 w1r0, w1r1, w2r0, w2r1;
  {
    *(bf8*)&Wbuf[r0 * 72 + c0] = *(const bf8*)(wg_a + r0 * 64 + c0);
    *(bf8*)&Wbuf[r1 * 72 + c1] = *(const bf8*)(wg_a + r1 * 64 + c1);
    w1r0 = *(const bf8*)(w1_a + r0 * 64 + c0);
    w1r1 = *(const bf8*)(w1_a + r1 * 64 + c1);
    w2r0 = *(const bf8*)(w2_a + r0 * 64 + c0);
    w2r1 = *(const bf8*)(w2_a + r1 * 64 + c1);
    int rz = tid >> 2, cz = (tid & 3) * 8;
    *(bf8*)&Wzb[rz * 36 + cz] = *(const bf8*)(wz_a + rz * 32 + cz);
  }
  f32x4 x[2][2];
#pragma unroll
  for (int mi = 0; mi < 2; ++mi)
#pragma unroll
    for (int ni = 0; ni < 2; ++ni)
      x[mi][ni] = *(const f32x4*)(pin + (e0 + wc * 32 + ni * 16 + llo) * 64 +
                                  chb + mi * 16);
  {
    f32x4 acc[2][2] = {};
    bf8 a0 = *(const bf8*)(Tb + growT * 2048 + (long)fr0 * 32 + fc);
    bf8 a1 = *(const bf8*)(Tb + growT * 2048 + (long)fr1 * 32 + fc);
    bf8 b0 = *(const bf8*)(bo_bf + ((long)bbt * 512 + jt * 64 + br0) * 32 + fc);
    bf8 b1 = *(const bf8*)(bo_bf + ((long)bbt * 512 + jt * 64 + br1) * 32 + fc);
    acc[0][0] = MFMA(a0, b0, acc[0][0]);
    acc[0][1] = MFMA(a0, b1, acc[0][1]);
    acc[1][0] = MFMA(a1, b0, acc[1][0]);
    acc[1][1] = MFMA(a1, b1, acc[1][1]);
    float nrm = op_norm[0];
#pragma unroll
    for (int mi = 0; mi < 2; ++mi) {
      f32x4 bo4 = *(const f32x4*)(b_out + chb + mi * 16);
#pragma unroll
      for (int ni = 0; ni < 2; ++ni)
#pragma unroll
        for (int r = 0; r < 4; ++r)
          x[mi][ni][r] += (acc[mi][ni][r] + bo4[r]) * nrm;
    }
  }
#pragma unroll
  for (int ni = 0; ni < 2; ++ni) {
    float s = 0.f, ss = 0.f;
#pragma unroll
    for (int mi = 0; mi < 2; ++mi)
#pragma unroll
      for (int r = 0; r < 4; ++r) { float v = x[mi][ni][r]; s += v; ss += v * v; }
    int e = wc * 32 + ni * 16 + llo;
    spS[e][wr * 4 + lhi] = s;
    spQ[e][wr * 4 + lhi] = ss;
  }
  const short* t_in = t4 + (long)bbt * 8388608;
  int te = tid & 63, tq = tid >> 6;
  float tt[8];
  {
    float sB = 0.f, ssB = 0.f;
#pragma unroll
    for (int k = 0; k < 8; ++k) {
      float v = bf2f(t_in[(long)(tq * 8 + k) * NNe + el + te]);
      tt[k] = v; sB += v; ssB += v * v;
    }
    spB[tq][0][te] = sB; spB[tq][1][te] = ssB;
  }
  __syncthreads();   // (1)
  {
    float ts = spB[0][0][te] + spB[1][0][te] + spB[2][0][te] + spB[3][0][te];
    float tss = spB[0][1][te] + spB[1][1][te] + spB[2][1][te] + spB[3][1][te];
    float mu = ts * 0.03125f, var = tss * 0.03125f - mu * mu;
    float rs = rsqrtf(var + LNEPS);
    bf8 pk;
#pragma unroll
    for (int k = 0; k < 8; ++k) {
      int c = tq * 8 + k;
      pk[k] = f2bf((tt[k] - mu) * rs * g_tmo[c] + b_tmo[c]);
    }
    *(bf8*)&Tlb[te * 40 + tq * 8] = pk;
  }
  float mu1[2], rs1[2];
#pragma unroll
  for (int ni = 0; ni < 2; ++ni) {
    int e = wc * 32 + ni * 16 + llo;
    float s = 0.f, q2 = 0.f;
#pragma unroll
    for (int k = 0; k < 8; ++k) { s += spS[e][k]; q2 += spQ[e][k]; }
    float mu = s * 0.015625f, var = q2 * 0.015625f - mu * mu;
    mu1[ni] = mu; rs1[ni] = rsqrtf(var + LNEPS);
  }
#pragma unroll
  for (int mi = 0; mi < 2; ++mi) {
    f32x4 gv = *(const f32x4*)(g_tm + chb + mi * 16);
    f32x4 bv = *(const f32x4*)(b_tm + chb + mi * 16);
#pragma unroll
    for (int ni = 0; ni < 2; ++ni) {
      int e = wc * 32 + ni * 16 + llo;
      bf4 pk;
#pragma unroll
      for (int r = 0; r < 4; ++r)
        pk[r] = f2bf((x[mi][ni][r] - mu1[ni]) * rs1[ni] * gv[r] + bv[r]);
      *(bf4*)&Zb[e * 72 + chb + mi * 16] = pk;
    }
  }
  __syncthreads();   // (2)
  f32x4 accg[2][2] = {};
  f32x4 accz[2][2] = {};
#pragma unroll
  for (int ks = 0; ks < 2; ++ks) {
    bf8 a0 = *(const bf8*)&Wbuf[fr0 * 72 + ks * 32 + fc];
    bf8 a1 = *(const bf8*)&Wbuf[fr1 * 72 + ks * 32 + fc];
    bf8 z0 = *(const bf8*)&Zb[br0 * 72 + ks * 32 + fc];
    bf8 z1 = *(const bf8*)&Zb[br1 * 72 + ks * 32 + fc];
    accg[0][0] = MFMA(a0, z0, accg[0][0]);
    accg[0][1] = MFMA(a0, z1, accg[0][1]);
    accg[1][0] = MFMA(a1, z0, accg[1][0]);
    accg[1][1] = MFMA(a1, z1, accg[1][1]);
  }
  {
    bf8 a0 = *(const bf8*)&Wzb[fr0 * 36 + fc];
    bf8 a1 = *(const bf8*)&Wzb[fr1 * 36 + fc];
    bf8 t0 = *(const bf8*)&Tlb[br0 * 40 + fc];
    bf8 t1 = *(const bf8*)&Tlb[br1 * 40 + fc];
    accz[0][0] = MFMA(a0, t0, accz[0][0]);
    accz[0][1] = MFMA(a0, t1, accz[0][1]);
    accz[1][0] = MFMA(a1, t0, accz[1][0]);
    accz[1][1] = MFMA(a1, t1, accz[1][1]);
  }
#pragma unroll
  for (int mi = 0; mi < 2; ++mi) {
    f32x4 bgv = *(const f32x4*)(b_g + chb + mi * 16);
    f32x4 bzv = *(const f32x4*)(b_z + chb + mi * 16);
#pragma unroll
    for (int ni = 0; ni < 2; ++ni)
#pragma unroll
      for (int r = 0; r < 4; ++r)
        x[mi][ni][r] += (accg[mi][ni][r] + bgv[r]) * (accz[mi][ni][r] + bzv[r]);
  }
#pragma unroll
  for (int ni = 0; ni < 2; ++ni) {
    float s = 0.f, ss = 0.f;
#pragma unroll
    for (int mi = 0; mi < 2; ++mi)
#pragma unroll
      for (int r = 0; r < 4; ++r) { float v = x[mi][ni][r]; s += v; ss += v * v; }
    int e = wc * 32 + ni * 16 + llo;
    spS[e][wr * 4 + lhi] = s;
    spQ[e][wr * 4 + lhi] = ss;
  }
  __syncthreads();   // (3)
  *(bf8*)&Wbuf[r0 * 72 + c0] = w1r0;
  *(bf8*)&Wbuf[r1 * 72 + c1] = w1r1;
#pragma unroll
  for (int ni = 0; ni < 2; ++ni) {
    int e = wc * 32 + ni * 16 + llo;
    float s = 0.f, q2 = 0.f;
#pragma unroll
    for (int k = 0; k < 8; ++k) { s += spS[e][k]; q2 += spQ[e][k]; }
    float mu = s * 0.015625f, var = q2 * 0.015625f - mu * mu;
    mu1[ni] = mu; rs1[ni] = rsqrtf(var + LNEPS);
  }
#pragma unroll
  for (int mi = 0; mi < 2; ++mi) {
    f32x4 gv = *(const f32x4*)(g_pf + chb + mi * 16);
    f32x4 bv = *(const f32x4*)(b_pf + chb + mi * 16);
#pragma unroll
    for (int ni = 0; ni < 2; ++ni) {
      int e = wc * 32 + ni * 16 + llo;
      bf4 pk;
#pragma unroll
      for (int r = 0; r < 4; ++r)
        pk[r] = f2bf((x[mi][ni][r] - mu1[ni]) * rs1[ni] * gv[r] + bv[r]);
      *(bf4*)&Zb[e * 72 + chb + mi * 16] = pk;
    }
  }
  __syncthreads();   // (4)
  f32x4 acc1[2][2] = {};
#pragma unroll
  for (int ks = 0; ks < 2; ++ks) {
    bf8 a0 = *(const bf8*)&Wbuf[fr0 * 72 + ks * 32 + fc];
    bf8 a1 = *(const bf8*)&Wbuf[fr1 * 72 + ks * 32 + fc];
    bf8 z0 = *(const bf8*)&Zb[br0 * 72 + ks * 32 + fc];
    bf8 z1 = *(const bf8*)&Zb[br1 * 72 + ks * 32 + fc];
    acc1[0][0] = MFMA(a0, z0, acc1[0][0]);
    acc1[0][1] = MFMA(a0, z1, acc1[0][1]);
    acc1[1][0] = MFMA(a1, z0, acc1[1][0]);
    acc1[1][1] = MFMA(a1, z1, acc1[1][1]);
  }
  __syncthreads();   // (5)
  *(bf8*)&Wbuf[r0 * 72 + c0] = w2r0;
  *(bf8*)&Wbuf[r1 * 72 + c1] = w2r1;
#pragma unroll
  for (int mi = 0; mi < 2; ++mi) {
    f32x4 bv = *(const f32x4*)(b1 + chb + mi * 16);
#pragma unroll
    for (int ni = 0; ni < 2; ++ni) {
      int e = wc * 32 + ni * 16 + llo;
      bf4 pk;
#pragma unroll
      for (int r = 0; r < 4; ++r) pk[r] = f2bf(gelu_fast(acc1[mi][ni][r] + bv[r]));
      *(bf4*)&Zb[e * 72 + chb + mi * 16] = pk;
    }
  }
  __syncthreads();   // (6)
  f32x4 acc2[2][2] = {};
#pragma unroll
  for (int ks = 0; ks < 2; ++ks) {
    bf8 a0 = *(const bf8*)&Wbuf[fr0 * 72 + ks * 32 + fc];
    bf8 a1 = *(const bf8*)&Wbuf[fr1 * 72 + ks * 32 + fc];
    bf8 z0 = *(const bf8*)&Zb[br0 * 72 + ks * 32 + fc];
    bf8 z1 = *(const bf8*)&Zb[br1 * 72 + ks * 32 + fc];
    acc2[0][0] = MFMA(a0, z0, acc2[0][0]);
    acc2[0][1] = MFMA(a0, z1, acc2[0][1]);
    acc2[1][0] = MFMA(a1, z0, acc2[1][0]);
    acc2[1][1] = MFMA(a1, z1, acc2[1][1]);
  }
#pragma unroll
  for (int mi = 0; mi < 2; ++mi) {
    f32x4 bv = *(const f32x4*)(b2 + chb + mi * 16);
#pragma unroll
    for (int ni = 0; ni < 2; ++ni) {
#pragma unroll
      for (int r = 0; r < 4; ++r) x[mi][ni][r] += acc2[mi][ni][r] + bv[r];
      *(f32x4*)(pout + (e0 + wc * 32 + ni * 16 + llo) * 64 + chb + mi * 16) =
          x[mi][ni];
    }
  }
}

extern "C" void kernel_launch(void* const* d_in, const int* in_sizes, int n_in,
                              void* d_out, int out_size, void* d_ws, size_t ws_size,
                              hipStream_t stream) {
  const float* x = (const float*)d_in[0];
  const float* pair = (const float*)d_in[1];
  const float* attn_mask = (const float*)d_in[2];
  const float* op_mask = (const float*)d_in[3];
  const float* op_norm = (const float*)d_in[4];
  const float* wq = (const float*)d_in[6];
  const float* wk = (const float*)d_in[7];
  const float* wv_ = (const float*)d_in[8];
  const float* wg = (const float*)d_in[9];
  const float* bg = (const float*)d_in[10];
  const float* wo = (const float*)d_in[11];
  const float* bo = (const float*)d_in[12];
  const float* ln_pair_g = (const float*)d_in[13];
  const float* ln_pair_b = (const float*)d_in[14];
  const float* wb = (const float*)d_in[15];
  const float* bb = (const float*)d_in[16];
  const float* ln_attn_g = (const float*)d_in[17];
  const float* ln_attn_b = (const float*)d_in[18];
  const float* ln_ffn_g = (const float*)d_in[19];
  const float* ln_ffn_b = (const float*)d_in[20];
  const float* w_ffn1 = (const float*)d_in[21];
  const float* b_ffn1 = (const float*)d_in[22];
  const float* w_ffn2 = (const float*)d_in[23];
  const float* b_ffn2 = (const float*)d_in[24];
  const float* ln_opm_g = (const float*)d_in[25];
  const float* ln_opm_b = (const float*)d_in[26];
  const float* w_opm_in = (const float*)d_in[27];
  const float* b_opm_in = (const float*)d_in[28];
  const float* w_opm_out = (const float*)d_in[29];
  const float* b_opm_out = (const float*)d_in[30];
  const float* ln_tm_g = (const float*)d_in[31];
  const float* ln_tm_b = (const float*)d_in[32];
  const float* w_tm_abp = (const float*)d_in[33];
  const float* b_tm_abp = (const float*)d_in[34];
  const float* w_tm_abg = (const float*)d_in[35];
  const float* b_tm_abg = (const float*)d_in[36];
  const float* w_tm_g = (const float*)d_in[37];
  const float* b_tm_g = (const float*)d_in[38];
  const float* w_tm_z = (const float*)d_in[39];
  const float* b_tm_z = (const float*)d_in[40];
  const float* ln_tmo_g = (const float*)d_in[41];
  const float* ln_tmo_b = (const float*)d_in[42];
  const float* ln_pffn_g = (const float*)d_in[43];
  const float* ln_pffn_b = (const float*)d_in[44];
  const float* w_pffn1 = (const float*)d_in[45];
  const float* b_pffn1 = (const float*)d_in[46];
  const float* w_pffn2 = (const float*)d_in[47];
  const float* b_pffn2 = (const float*)d_in[48];

  float* ws = (float*)d_ws;
  short* wbf = (short*)ws;
  short* wq_bf = wbf + 0;            // contiguous [3072][768] qkvg block
  short* wo_bf = wbf + 2359296;
  short* wf1_bf = wbf + 2949120;
  short* wf2_bf = wbf + 5308416;
  short* wop_bf = wbf + 7667712;
  short* wb_a = wbf + 7716864;
  short* wabp_a = wbf + 7717376;
  short* wabg_a = wbf + 7721472;
  short* wtg_a = wbf + 7725568;
  short* wtz_a = wbf + 7729664;
  short* wp1_a = wbf + 7731712;
  short* wp2_a = wbf + 7735808;

  short* h_bf = (short*)(ws + 3869952);
  short* q_bf = (short*)(ws + 4656384);
  short* k_bf = (short*)(ws + 5442816);
  short* vT_bf = (short*)(ws + 6229248);
  float* gb = ws + 7015680;
  short* gb_bf = (short*)(ws + 10161408);
  float* x1b = ws + 10947840;
  short* biasb_bf = (short*)(ws + 12520704);   // 8388608 bf16
  short* attn_bf = (short*)(ws + 16715008);    // 8388608 bf16
  short* mffn_bf = (short*)(ws + 20909312);    // 6291456 bf16
  float* abb = ws + 24055040;                  // 131072 f32
  short* abb_bf = (short*)(ws + 24186112);     // 65536 bf16 (bo, all batches)
  short* Tb_bf = (short*)(ws + 24218880);      // 4194304 bf16 (all batches)
  short* aN4 = (short*)(ws + 59870464);        // 4 x 8388608 bf16
  short* bN4 = (short*)(ws + 76647680);
  short* t4 = (short*)(ws + 93424896);

  float* xo = (float*)d_out;
  float* pair1 = xo + 1572864;

  const float qscale = 0.1020620726159658f;  // 96^-0.5

  // --- weight casts ---
  castw_kernel<<<30144, 256, 0, stream>>>(wq, wk, wv_, wg, wo, w_ffn1, w_ffn2, w_opm_in,
                                          wbf, qscale);
  castw2_kernel<<<90, 256, 0, stream>>>(wb, w_tm_abp, w_tm_abg, w_tm_g, w_tm_z,
                                        w_pffn1, w_pffn2, wb_a);
  // --- attention ---
  ln_bf_kernel<<<2048, 256, 0, stream>>>(x, h_bf, ln_attn_g, ln_attn_b, 768);
  gemm_qkvg<<<dim3(24, 16, 1), 256, 0, stream>>>(h_bf, wq_bf, q_bf, k_bf, vT_bf, gb, bg);
  pair_bias_mfma<<<16384, 256, 0, stream>>>(pair, ln_pair_g, ln_pair_b, wb_a, bb, biasb_bf);
  attn_fused<<<dim3(32, 8, 4), 256, 0, stream>>>(q_bf, k_bf, biasb_bf, attn_mask, attn_bf);
  // AV with fused output gate
  gemm_bf<<<dim3(2, 8, 32), 256, 0, stream>>>(attn_bf, 512, 2097152, 262144,
                                              vT_bf, 512, 393216, 49152,
                                              nullptr, 0, 393216, 96, gb_bf, 768,
                                              gb, 768, 393216, 96, nullptr,
                                              512, 96, 512, 2, 0, 8);
  gemm128<<<dim3(6, 16, 1), 256, 0, stream>>>(gb_bf, wo_bf, 768, x, bo, x1b);
  // --- FFN ---
  ln_bf_kernel<<<2048, 256, 0, stream>>>(x1b, h_bf, ln_ffn_g, ln_ffn_b, 768);
  gemm_ffn1<<<dim3(24, 16, 1), 256, 0, stream>>>(h_bf, wf1_bf, mffn_bf, b_ffn1);
  gemm128<<<dim3(6, 16, 1), 256, 0, stream>>>(mffn_bf, wf2_bf, 3072, x1b, b_ffn2, xo);
  // --- outer product mean prep ---
  ln_bf_kernel<<<2048, 256, 0, stream>>>(xo, h_bf, ln_opm_g, ln_opm_b, 768);
  gemm_bf<<<dim3(1, 32, 1), 256, 0, stream>>>(h_bf, 768, 0, 0, wop_bf, 768, 0, 0,
                                              abb, 64, 0, 0, nullptr, 0,
                                              nullptr, 0, 0, 0, b_opm_in,
                                              2048, 64, 768, 0, 0, 1);
  opmask_kernel<<<512, 256, 0, stream>>>(abb, op_mask, abb_bf);
  opm_T_kernel<<<dim3(256, 64, 1), dim3(32, 8, 1), 0, stream>>>(abb, w_opm_out, Tb_bf);
  // --- pair stack (batched over all 4 batches) ---
  opm_ab_fused<<<dim3(8, 512, 4), 256, 0, stream>>>(
      pair, Tb_bf, abb_bf, b_opm_out, op_norm,
      ln_tm_g, ln_tm_b, wabp_a, b_tm_abp, wabg_a, b_tm_abg, aN4, bN4);
  tm_tri_mfma<<<dim3(4, 4, 128), 512, 0, stream>>>(aN4, bN4, t4);
  upd_pffn_fused<<<16384, 256, 0, stream>>>(
      pair, pair1, t4, Tb_bf, abb_bf, b_opm_out, op_norm,
      ln_tm_g, ln_tm_b, wtg_a, b_tm_g, wtz_a, b_tm_z,
      ln_tmo_g, ln_tmo_b, ln_pffn_g, ln_pffn_b, wp1_a, b_pffn1, wp2_a, b_pffn2);
}

// Round 14
// 883.055 us; speedup vs baseline: 1.0412x; 1.0412x over previous
//
#include <hip/hip_runtime.h>
#include <hip/hip_bf16.h>
#include <math.h>

#define Nn 512
#define Ee 768
#define Pp 64
#define PHh 32
#define Hh 8
#define Dd 96
#define NNe 262144      // N*N
#define LNEPS 1e-5f

typedef __attribute__((ext_vector_type(8))) short bf8;
typedef __attribute__((ext_vector_type(4))) short bf4;
typedef __attribute__((ext_vector_type(4))) float f32x4;
#define MFMA(a,b,c) __builtin_amdgcn_mfma_f32_16x16x32_bf16(a,b,c,0,0,0)

__device__ __forceinline__ short f2bf(float f) {
  __bf16 h = (__bf16)f;
  return __builtin_bit_cast(short, h);
}
__device__ __forceinline__ float bf2f(short s) {
  unsigned u = ((unsigned)(unsigned short)s) << 16;
  return __builtin_bit_cast(float, u);
}

__device__ __forceinline__ float wave_red_sum(float v) {
#pragma unroll
  for (int off = 32; off > 0; off >>= 1) v += __shfl_xor(v, off);
  return v;
}
__device__ __forceinline__ float gelu_exact(float v) {
  return 0.5f * v * (1.f + erff(v * 0.70710678118654752f));
}
__device__ __forceinline__ float sigmoidf_(float v) {
  return 1.f / (1.f + __expf(-v));
}
__device__ __forceinline__ float gelu_fast(float v) {
  return v / (1.f + __expf(-1.702f * v));
}

// ---------------- weight casts to bf16 arena ----------------
__global__ __launch_bounds__(256) void castw_kernel(
    const float* __restrict__ wq, const float* __restrict__ wk,
    const float* __restrict__ wv, const float* __restrict__ wg,
    const float* __restrict__ wo, const float* __restrict__ f1,
    const float* __restrict__ f2, const float* __restrict__ wop,
    short* __restrict__ dst, float qs) {
  long i = (long)blockIdx.x * 256 + threadIdx.x;
  float v;
  if (i < 589824) v = wq[i] * qs;
  else if (i < 1179648) v = wk[i - 589824];
  else if (i < 1769472) v = wv[i - 1179648];
  else if (i < 2359296) v = wg[i - 1769472];
  else if (i < 2949120) v = wo[i - 2359296];
  else if (i < 5308416) v = f1[i - 2949120];
  else if (i < 7667712) v = f2[i - 5308416];
  else if (i < 7716864) v = wop[i - 7667712];
  else return;
  dst[i] = f2bf(v);
}

__global__ __launch_bounds__(256) void castw2_kernel(
    const float* __restrict__ wb, const float* __restrict__ abp,
    const float* __restrict__ abg, const float* __restrict__ wtg,
    const float* __restrict__ wtz, const float* __restrict__ p1,
    const float* __restrict__ p2, short* __restrict__ dst) {
  int i = blockIdx.x * 256 + threadIdx.x;
  float v;
  if (i < 512) v = wb[i];
  else if (i < 4608) v = abp[i - 512];
  else if (i < 8704) v = abg[i - 4608];
  else if (i < 12800) v = wtg[i - 8704];
  else if (i < 14848) v = wtz[i - 12800];
  else if (i < 18944) v = p1[i - 14848];
  else if (i < 23040) v = p2[i - 18944];
  else return;
  dst[i] = f2bf(v);
}

// ---------------- LayerNorm over last dim C -> bf16 out ----------------
__global__ __launch_bounds__(256) void ln_bf_kernel(const float* __restrict__ in,
                                                    short* __restrict__ out,
                                                    const float* __restrict__ gam,
                                                    const float* __restrict__ bet, int C) {
  int row = blockIdx.x;
  const float* xr = in + (long)row * C;
  short* yr = out + (long)row * C;
  float s = 0.f, ss = 0.f;
  for (int c = threadIdx.x; c < C; c += 256) { float v = xr[c]; s += v; ss += v * v; }
  s = wave_red_sum(s); ss = wave_red_sum(ss);
  __shared__ float sm[4][2];
  int wv = threadIdx.x >> 6, lane = threadIdx.x & 63;
  if (lane == 0) { sm[wv][0] = s; sm[wv][1] = ss; }
  __syncthreads();
  float ts = sm[0][0] + sm[1][0] + sm[2][0] + sm[3][0];
  float tss = sm[0][1] + sm[1][1] + sm[2][1] + sm[3][1];
  float mu = ts / C;
  float var = tss / C - mu * mu;
  float rs = rsqrtf(var + LNEPS);
  for (int c = threadIdx.x; c < C; c += 256) {
    float v = xr[c];
    yr[c] = f2bf((v - mu) * rs * gam[c] + bet[c]);
  }
}

// ---------------- bf16 MFMA NT GEMM, 64x64, BK=64 ----------------
__global__ __launch_bounds__(256) void gemm_bf(
    const short* __restrict__ A, int lda, long asB, long asH,
    const short* __restrict__ Bm, int ldb, long bsB, long bsH,
    float* __restrict__ outF, int ldf, long fsB, long fsH,
    short* __restrict__ outB, int ldob,
    const float* __restrict__ resid, int ldr, long rsB, long rsH,
    const float* __restrict__ bias,
    int M, int N, int K, int act, int vtrans, int Hdim) {
  int bz = blockIdx.z, bb = bz / Hdim, hh = bz % Hdim;
  A += bb * asB + hh * asH;
  Bm += bb * bsB + hh * bsH;
  if (outF) outF += bb * fsB + hh * fsH;
  if (outB) outB += bb * fsB + hh * fsH;
  if (resid) resid += bb * rsB + hh * rsH;
  __shared__ __align__(16) short As[64 * 72];
  __shared__ __align__(16) short Bs[64 * 72];
  int m0 = blockIdx.y * 64, n0 = blockIdx.x * 64;
  int tid = threadIdx.x;
  int wv = tid >> 6, lane = tid & 63;
  int wr = wv >> 1, wc = wv & 1;
  int lhi = lane >> 4, llo = lane & 15;
  int r4 = tid >> 2, c8 = (tid & 3) * 8;
  f32x4 acc[2][2] = {};
  for (int k0 = 0; k0 < K; k0 += 64) {
    *(bf8*)&As[r4 * 72 + c8] = *(const bf8*)(A + (long)(m0 + r4) * lda + k0 + c8);
    *(bf8*)&As[r4 * 72 + 32 + c8] =
        *(const bf8*)(A + (long)(m0 + r4) * lda + k0 + 32 + c8);
    bf8 bv0 = {}, bv1 = {};
    if (n0 + r4 < N) {
      bv0 = *(const bf8*)(Bm + (long)(n0 + r4) * ldb + k0 + c8);
      bv1 = *(const bf8*)(Bm + (long)(n0 + r4) * ldb + k0 + 32 + c8);
    }
    *(bf8*)&Bs[r4 * 72 + c8] = bv0;
    *(bf8*)&Bs[r4 * 72 + 32 + c8] = bv1;
    __syncthreads();
#pragma unroll
    for (int ks = 0; ks < 2; ++ks) {
      bf8 a0 = *(const bf8*)&As[(wr * 32 + llo) * 72 + ks * 32 + lhi * 8];
      bf8 a1 = *(const bf8*)&As[(wr * 32 + 16 + llo) * 72 + ks * 32 + lhi * 8];
      bf8 b0 = *(const bf8*)&Bs[(wc * 32 + llo) * 72 + ks * 32 + lhi * 8];
      bf8 b1 = *(const bf8*)&Bs[(wc * 32 + 16 + llo) * 72 + ks * 32 + lhi * 8];
      acc[0][0] = MFMA(a0, b0, acc[0][0]);
      acc[0][1] = MFMA(a0, b1, acc[0][1]);
      acc[1][0] = MFMA(a1, b0, acc[1][0]);
      acc[1][1] = MFMA(a1, b1, acc[1][1]);
    }
    __syncthreads();
  }
#pragma unroll
  for (int mi = 0; mi < 2; ++mi) {
    int gmb = m0 + wr * 32 + mi * 16 + lhi * 4;
#pragma unroll
    for (int ni = 0; ni < 2; ++ni) {
      int gn = n0 + wc * 32 + ni * 16 + llo;
      if (gn >= N) continue;
      float bv = bias ? bias[gn] : 0.f;
      float vr[4];
#pragma unroll
      for (int r = 0; r < 4; ++r) {
        float v = acc[mi][ni][r] + bv;
        if (resid) {
          float rv = resid[(long)(gmb + r) * ldr + gn];
          if (act == 2) v = sigmoidf_(rv) * acc[mi][ni][r];
          else v += rv;
        }
        if (act == 1) v = gelu_exact(v);
        vr[r] = v;
      }
      if (outF) {
#pragma unroll
        for (int r = 0; r < 4; ++r) outF[(long)(gmb + r) * ldf + gn] = vr[r];
      }
      if (outB) {
        if (vtrans) {
          bf4 pk;
#pragma unroll
          for (int r = 0; r < 4; ++r) pk[r] = f2bf(vr[r]);
          *(bf4*)(outB + ((long)((gmb >> 9) * 768 + gn) * 512 + (gmb & 511))) = pk;
        } else {
#pragma unroll
          for (int r = 0; r < 4; ++r) outB[(long)(gmb + r) * ldob + gn] = f2bf(vr[r]);
        }
      }
    }
  }
}

// ---------------- 128x128 tile: QKVG projection ----------------
__global__ __launch_bounds__(256) void gemm_qkvg(
    const short* __restrict__ A, const short* __restrict__ W,
    short* __restrict__ q_bf, short* __restrict__ k_bf,
    short* __restrict__ vT_bf, float* __restrict__ gb,
    const float* __restrict__ bg) {
  __shared__ __align__(16) short As[128 * 40];
  __shared__ __align__(16) short Bs[128 * 40];
  int m0 = blockIdx.y * 128, n0 = blockIdx.x * 128;
  int sec = n0 / 768;
  int cbase = n0 - sec * 768;
  int tid = threadIdx.x;
  int wv = tid >> 6, lane = tid & 63;
  int wr = wv >> 1, wc = wv & 1;
  int lhi = lane >> 4, llo = lane & 15;
  int r4 = tid >> 2, c8 = (tid & 3) * 8;
  f32x4 acc[4][4] = {};
  for (int k0 = 0; k0 < 768; k0 += 32) {
    *(bf8*)&As[r4 * 40 + c8] = *(const bf8*)(A + (long)(m0 + r4) * 768 + k0 + c8);
    *(bf8*)&As[(r4 + 64) * 40 + c8] =
        *(const bf8*)(A + (long)(m0 + r4 + 64) * 768 + k0 + c8);
    *(bf8*)&Bs[r4 * 40 + c8] = *(const bf8*)(W + (long)(n0 + r4) * 768 + k0 + c8);
    *(bf8*)&Bs[(r4 + 64) * 40 + c8] =
        *(const bf8*)(W + (long)(n0 + r4 + 64) * 768 + k0 + c8);
    __syncthreads();
    bf8 af[4], bfm[4];
#pragma unroll
    for (int mi = 0; mi < 4; ++mi)
      af[mi] = *(const bf8*)&As[(wr * 64 + mi * 16 + llo) * 40 + lhi * 8];
#pragma unroll
    for (int ni = 0; ni < 4; ++ni)
      bfm[ni] = *(const bf8*)&Bs[(wc * 64 + ni * 16 + llo) * 40 + lhi * 8];
#pragma unroll
    for (int mi = 0; mi < 4; ++mi)
#pragma unroll
      for (int ni = 0; ni < 4; ++ni)
        acc[mi][ni] = MFMA(af[mi], bfm[ni], acc[mi][ni]);
    __syncthreads();
  }
#pragma unroll
  for (int mi = 0; mi < 4; ++mi) {
    int gmb = m0 + wr * 64 + mi * 16 + lhi * 4;
#pragma unroll
    for (int ni = 0; ni < 4; ++ni) {
      int cn = cbase + wc * 64 + ni * 16 + llo;
      if (sec == 0) {
#pragma unroll
        for (int r = 0; r < 4; ++r) q_bf[(long)(gmb + r) * 768 + cn] = f2bf(acc[mi][ni][r]);
      } else if (sec == 1) {
#pragma unroll
        for (int r = 0; r < 4; ++r) k_bf[(long)(gmb + r) * 768 + cn] = f2bf(acc[mi][ni][r]);
      } else if (sec == 2) {
        bf4 pk;
#pragma unroll
        for (int r = 0; r < 4; ++r) pk[r] = f2bf(acc[mi][ni][r]);
        *(bf4*)(vT_bf + ((long)((gmb >> 9) * 768 + cn) * 512 + (gmb & 511))) = pk;
      } else {
        float bv = bg[cn];
#pragma unroll
        for (int r = 0; r < 4; ++r) gb[(long)(gmb + r) * 768 + cn] = acc[mi][ni][r] + bv;
      }
    }
  }
}

// ---------------- 128x128 tile: FFN1 (gelu exact, bf16 out) ----------------
__global__ __launch_bounds__(256) void gemm_ffn1(
    const short* __restrict__ A, const short* __restrict__ W,
    short* __restrict__ outB, const float* __restrict__ bias) {
  __shared__ __align__(16) short As[128 * 40];
  __shared__ __align__(16) short Bs[128 * 40];
  int m0 = blockIdx.y * 128, n0 = blockIdx.x * 128;
  int tid = threadIdx.x;
  int wv = tid >> 6, lane = tid & 63;
  int wr = wv >> 1, wc = wv & 1;
  int lhi = lane >> 4, llo = lane & 15;
  int r4 = tid >> 2, c8 = (tid & 3) * 8;
  f32x4 acc[4][4] = {};
  for (int k0 = 0; k0 < 768; k0 += 32) {
    *(bf8*)&As[r4 * 40 + c8] = *(const bf8*)(A + (long)(m0 + r4) * 768 + k0 + c8);
    *(bf8*)&As[(r4 + 64) * 40 + c8] =
        *(const bf8*)(A + (long)(m0 + r4 + 64) * 768 + k0 + c8);
    *(bf8*)&Bs[r4 * 40 + c8] = *(const bf8*)(W + (long)(n0 + r4) * 768 + k0 + c8);
    *(bf8*)&Bs[(r4 + 64) * 40 + c8] =
        *(const bf8*)(W + (long)(n0 + r4 + 64) * 768 + k0 + c8);
    __syncthreads();
    bf8 af[4], bfm[4];
#pragma unroll
    for (int mi = 0; mi < 4; ++mi)
      af[mi] = *(const bf8*)&As[(wr * 64 + mi * 16 + llo) * 40 + lhi * 8];
#pragma unroll
    for (int ni = 0; ni < 4; ++ni)
      bfm[ni] = *(const bf8*)&Bs[(wc * 64 + ni * 16 + llo) * 40 + lhi * 8];
#pragma unroll
    for (int mi = 0; mi < 4; ++mi)
#pragma unroll
      for (int ni = 0; ni < 4; ++ni)
        acc[mi][ni] = MFMA(af[mi], bfm[ni], acc[mi][ni]);
    __syncthreads();
  }
#pragma unroll
  for (int mi = 0; mi < 4; ++mi) {
    int gmb = m0 + wr * 64 + mi * 16 + lhi * 4;
#pragma unroll
    for (int ni = 0; ni < 4; ++ni) {
      int gn = n0 + wc * 64 + ni * 16 + llo;
      float bv = bias[gn];
#pragma unroll
      for (int r = 0; r < 4; ++r)
        outB[(long)(gmb + r) * 3072 + gn] = f2bf(gelu_exact(acc[mi][ni][r] + bv));
    }
  }
}

// ---------------- 128x128 tile: generic NT fp32 out + resid + bias (wo, ffn2) ----------
__global__ __launch_bounds__(256) void gemm128(
    const short* __restrict__ A, const short* __restrict__ W, int K,
    const float* __restrict__ resid, const float* __restrict__ bias,
    float* __restrict__ outF) {
  __shared__ __align__(16) short As[128 * 40];
  __shared__ __align__(16) short Bs[128 * 40];
  int m0 = blockIdx.y * 128, n0 = blockIdx.x * 128;
  int tid = threadIdx.x;
  int wv = tid >> 6, lane = tid & 63;
  int wr = wv >> 1, wc = wv & 1;
  int lhi = lane >> 4, llo = lane & 15;
  int r4 = tid >> 2, c8 = (tid & 3) * 8;
  f32x4 acc[4][4] = {};
  for (int k0 = 0; k0 < K; k0 += 32) {
    *(bf8*)&As[r4 * 40 + c8] = *(const bf8*)(A + (long)(m0 + r4) * K + k0 + c8);
    *(bf8*)&As[(r4 + 64) * 40 + c8] =
        *(const bf8*)(A + (long)(m0 + r4 + 64) * K + k0 + c8);
    *(bf8*)&Bs[r4 * 40 + c8] = *(const bf8*)(W + (long)(n0 + r4) * K + k0 + c8);
    *(bf8*)&Bs[(r4 + 64) * 40 + c8] =
        *(const bf8*)(W + (long)(n0 + r4 + 64) * K + k0 + c8);
    __syncthreads();
    bf8 af[4], bfm[4];
#pragma unroll
    for (int mi = 0; mi < 4; ++mi)
      af[mi] = *(const bf8*)&As[(wr * 64 + mi * 16 + llo) * 40 + lhi * 8];
#pragma unroll
    for (int ni = 0; ni < 4; ++ni)
      bfm[ni] = *(const bf8*)&Bs[(wc * 64 + ni * 16 + llo) * 40 + lhi * 8];
#pragma unroll
    for (int mi = 0; mi < 4; ++mi)
#pragma unroll
      for (int ni = 0; ni < 4; ++ni)
        acc[mi][ni] = MFMA(af[mi], bfm[ni], acc[mi][ni]);
    __syncthreads();
  }
#pragma unroll
  for (int mi = 0; mi < 4; ++mi) {
    int gmb = m0 + wr * 64 + mi * 16 + lhi * 4;
#pragma unroll
    for (int ni = 0; ni < 4; ++ni) {
      int gn = n0 + wc * 64 + ni * 16 + llo;
      float bv = bias[gn];
#pragma unroll
      for (int r = 0; r < 4; ++r)
        outF[(long)(gmb + r) * 768 + gn] =
            acc[mi][ni][r] + bv + resid[(long)(gmb + r) * 768 + gn];
    }
  }
}

// ---------------- fused scores + softmax (flash-row, 16 rows/block) ----------------
__global__ __launch_bounds__(256) void attn_fused(
    const short* __restrict__ q_bf, const short* __restrict__ k_bf,
    const short* __restrict__ bias_bf, const float* __restrict__ mask,
    short* __restrict__ out_bf) {
  int it = blockIdx.x, h = blockIdx.y, b = blockIdx.z;
  int tid = threadIdx.x;
  int wv = tid >> 6, lane = tid & 63;
  int lhi = lane >> 4, llo = lane & 15;
  int i0 = it * 16;
  long qoff = ((long)(b * 512 + i0)) * 768 + h * 96;
  bf8 qf[3];
#pragma unroll
  for (int ks = 0; ks < 3; ++ks)
    qf[ks] = *(const bf8*)(q_bf + qoff + (long)llo * 768 + ks * 32 + lhi * 8);
  long koff = ((long)b * 512) * 768 + h * 96;
  long bioff = (long)(b * 8 + h) * NNe + (long)i0 * 512;
  long moff = (long)b * NNe + (long)i0 * 512;
  float sv[8][4];
  int jb0 = wv * 128;
#pragma unroll
  for (int jf = 0; jf < 8; ++jf) {
    int jb = jb0 + jf * 16;
    f32x4 acc = {0.f, 0.f, 0.f, 0.f};
#pragma unroll
    for (int ks = 0; ks < 3; ++ks) {
      bf8 kf = *(const bf8*)(k_bf + koff + (long)(jb + llo) * 768 + ks * 32 + lhi * 8);
      acc = MFMA(qf[ks], kf, acc);
    }
#pragma unroll
    for (int r = 0; r < 4; ++r) {
      int irow = lhi * 4 + r;
      int j = jb + llo;
      float bia = bf2f(bias_bf[bioff + (long)irow * 512 + j]);
      float mk = mask[moff + (long)irow * 512 + j];
      sv[jf][r] = acc[r] + bia + mk;
    }
  }
  __shared__ float redA[4][20];
  __shared__ float redB[4][20];
  float rmax[4];
#pragma unroll
  for (int r = 0; r < 4; ++r) {
    float m = sv[0][r];
#pragma unroll
    for (int jf = 1; jf < 8; ++jf) m = fmaxf(m, sv[jf][r]);
#pragma unroll
    for (int off = 1; off < 16; off <<= 1) m = fmaxf(m, __shfl_xor(m, off, 16));
    if (llo == 0) redA[wv][lhi * 4 + r] = m;
  }
  __syncthreads();
#pragma unroll
  for (int r = 0; r < 4; ++r) {
    int row = lhi * 4 + r;
    rmax[r] = fmaxf(fmaxf(redA[0][row], redA[1][row]),
                    fmaxf(redA[2][row], redA[3][row]));
  }
  float rsum[4] = {0.f, 0.f, 0.f, 0.f};
#pragma unroll
  for (int jf = 0; jf < 8; ++jf)
#pragma unroll
    for (int r = 0; r < 4; ++r) {
      float e = __expf(sv[jf][r] - rmax[r]);
      sv[jf][r] = e;
      rsum[r] += e;
    }
#pragma unroll
  for (int r = 0; r < 4; ++r) {
#pragma unroll
    for (int off = 1; off < 16; off <<= 1) rsum[r] += __shfl_xor(rsum[r], off, 16);
    if (llo == 0) redB[wv][lhi * 4 + r] = rsum[r];
  }
  __syncthreads();
#pragma unroll
  for (int r = 0; r < 4; ++r) {
    int row = lhi * 4 + r;
    float s = redB[0][row] + redB[1][row] + redB[2][row] + redB[3][row];
    float inv = 1.f / s;
#pragma unroll
    for (int jf = 0; jf < 8; ++jf) {
      int j = jb0 + jf * 16 + llo;
      out_bf[bioff + (long)row * 512 + j] = f2bf(sv[jf][r] * inv);
    }
  }
}

// ---------------- ab *= op_mask ; emit b-half bf16 ----------------
__global__ __launch_bounds__(256) void opmask_kernel(float* __restrict__ ab,
                                                     const float* __restrict__ mask,
                                                     short* __restrict__ bo_bf) {
  int idx = blockIdx.x * 256 + threadIdx.x;
  if (idx < 131072) {
    float v = ab[idx] * mask[idx >> 6];
    ab[idx] = v;
    int ch = idx & 63;
    if (ch >= 32) bo_bf[(idx >> 6) * 32 + ch - 32] = f2bf(v);
  }
}

// ---------------- T[row,p,e] (bf16) ----------------
__global__ __launch_bounds__(256) void opm_T_kernel(const float* __restrict__ ab,
                                                    const float* __restrict__ w,
                                                    short* __restrict__ T) {
  int p = blockIdx.y;
  int row = blockIdx.x * 8 + threadIdx.y;
  int e = threadIdx.x;
  const float* a = ab + (long)row * 64;
  const float* wp = w + p * 1024 + e;
  float acc = 0.f;
#pragma unroll
  for (int d = 0; d < 32; ++d) acc += a[d] * wp[d * 32];
  T[((long)row * 64 + p) * 32 + e] = f2bf(acc);
}

// ---------------- pair bias: register LN ----------------
__global__ __launch_bounds__(256) void pair_bias_mfma(
    const float* __restrict__ pair, const float* __restrict__ gam,
    const float* __restrict__ bet, const short* __restrict__ wb_a,
    const float* __restrict__ bbv, short* __restrict__ bias) {
  __shared__ __align__(16) short Zb[64 * 72];
  __shared__ __align__(16) short Wb[16 * 72];
  __shared__ float sp[4][2][72];
  int tid = threadIdx.x;
  long e0 = (long)blockIdx.x * 64;
  int b = (int)(e0 >> 18);
  long ein = e0 & (NNe - 1);
  const float* base = pair + e0 * 64;
  for (int l = tid; l < 1024; l += 256) {
    int h = l >> 6, c = l & 63;
    Wb[h * 72 + c] = (h < 8) ? wb_a[h * 64 + c] : (short)0;
  }
  int e = tid & 63, q = tid >> 6;
  f32x4 v4[4];
  float s = 0.f, ss = 0.f;
#pragma unroll
  for (int k = 0; k < 4; ++k) {
    v4[k] = *(const f32x4*)(base + (long)e * 64 + q * 16 + k * 4);
#pragma unroll
    for (int u = 0; u < 4; ++u) { float v = v4[k][u]; s += v; ss += v * v; }
  }
  sp[q][0][e] = s; sp[q][1][e] = ss;
  __syncthreads();
  float ts = sp[0][0][e] + sp[1][0][e] + sp[2][0][e] + sp[3][0][e];
  float tss = sp[0][1][e] + sp[1][1][e] + sp[2][1][e] + sp[3][1][e];
  float mu = ts * 0.015625f, var = tss * 0.015625f - mu * mu;
  float rs = rsqrtf(var + LNEPS);
#pragma unroll
  for (int k = 0; k < 4; ++k) {
    bf4 pk;
#pragma unroll
    for (int u = 0; u < 4; ++u) {
      int c = q * 16 + k * 4 + u;
      pk[u] = f2bf((v4[k][u] - mu) * rs * gam[c] + bet[c]);
    }
    *(bf4*)&Zb[e * 72 + q * 16 + k * 4] = pk;
  }
  __syncthreads();
  int wv = tid >> 6, lane = tid & 63;
  int lhi = lane >> 4, llo = lane & 15;
  int n0 = wv * 16;
  f32x4 acc = {0.f, 0.f, 0.f, 0.f};
#pragma unroll
  for (int ks = 0; ks < 2; ++ks) {
    bf8 a = *(const bf8*)&Wb[llo * 72 + ks * 32 + lhi * 8];
    bf8 bz = *(const bf8*)&Zb[(n0 + llo) * 72 + ks * 32 + lhi * 8];
    acc = MFMA(a, bz, acc);
  }
  int elem = n0 + llo;
#pragma unroll
  for (int r = 0; r < 4; ++r) {
    int h = lhi * 4 + r;
    if (h < 8) bias[(long)(b * 8 + h) * NNe + ein + elem] = f2bf(acc[r] + bbv[h]);
  }
}

// -------- opm + triangle ab (batched z=4, fp32 pair reads, LDS W) --------
__global__ __launch_bounds__(256) void opm_ab_fused(
    const float* __restrict__ pair_in, const short* __restrict__ Tb,
    const short* __restrict__ bo_bf, const float* __restrict__ b_out,
    const float* __restrict__ op_norm, const float* __restrict__ gam,
    const float* __restrict__ bet, const short* __restrict__ wp_a,
    const float* __restrict__ b_abp, const short* __restrict__ wg_a,
    const float* __restrict__ b_abg,
    short* __restrict__ aN4, short* __restrict__ bN4) {
  int jt = blockIdx.x;   // 0..7
  int i = blockIdx.y;    // 0..511
  int bb = blockIdx.z;   // 0..3
  int tid = threadIdx.x;
  __shared__ __align__(16) short Zb[64 * 72];
  __shared__ __align__(16) short Wp[64 * 72];
  __shared__ __align__(16) short Wg[64 * 72];
  __shared__ float spS[64][9];
  __shared__ float spQ[64][9];
  int wv = tid >> 6, lane = tid & 63;
  int wr = wv >> 1, wc = wv & 1;
  int lhi = lane >> 4, llo = lane & 15;
  int chb = wr * 32 + lhi * 4;
  int fc = lhi * 8;
  for (int l = tid; l < 512; l += 256) {
    int r = l >> 3, c8 = (l & 7) * 8;
    *(bf8*)&Wp[r * 72 + c8] = *(const bf8*)(wp_a + r * 64 + c8);
    *(bf8*)&Wg[r * 72 + c8] = *(const bf8*)(wg_a + r * 64 + c8);
  }
  long grow = (long)bb * 512 + i;
  long ebase = (long)i * 512 + jt * 64;
  const float* pbase = pair_in + ((long)bb * NNe + ebase) * 64;
  short* aN = aN4 + (long)bb * 8388608;
  short* bN = bN4 + (long)bb * 8388608;
  f32x4 x[2][2];
#pragma unroll
  for (int mi = 0; mi < 2; ++mi)
#pragma unroll
    for (int ni = 0; ni < 2; ++ni)
      x[mi][ni] = *(const f32x4*)(pbase + (long)(wc * 32 + ni * 16 + llo) * 64 +
                                  chb + mi * 16);
  {
    f32x4 acc[2][2] = {};
    bf8 a0 = *(const bf8*)(Tb + grow * 2048 + (long)(wr * 32 + llo) * 32 + fc);
    bf8 a1 = *(const bf8*)(Tb + grow * 2048 + (long)(wr * 32 + 16 + llo) * 32 + fc);
    bf8 b0 = *(const bf8*)(bo_bf + ((long)bb * 512 + jt * 64 + wc * 32 + llo) * 32 + fc);
    bf8 b1 = *(const bf8*)(bo_bf +
                           ((long)bb * 512 + jt * 64 + wc * 32 + 16 + llo) * 32 + fc);
    acc[0][0] = MFMA(a0, b0, acc[0][0]);
    acc[0][1] = MFMA(a0, b1, acc[0][1]);
    acc[1][0] = MFMA(a1, b0, acc[1][0]);
    acc[1][1] = MFMA(a1, b1, acc[1][1]);
    float nrm = op_norm[0];
#pragma unroll
    for (int mi = 0; mi < 2; ++mi) {
      f32x4 bo4 = *(const f32x4*)(b_out + chb + mi * 16);
#pragma unroll
      for (int ni = 0; ni < 2; ++ni)
#pragma unroll
        for (int r = 0; r < 4; ++r)
          x[mi][ni][r] += (acc[mi][ni][r] + bo4[r]) * nrm;
    }
  }
#pragma unroll
  for (int ni = 0; ni < 2; ++ni) {
    float s = 0.f, ss = 0.f;
#pragma unroll
    for (int mi = 0; mi < 2; ++mi)
#pragma unroll
      for (int r = 0; r < 4; ++r) { float v = x[mi][ni][r]; s += v; ss += v * v; }
    int e = wc * 32 + ni * 16 + llo;
    spS[e][wr * 4 + lhi] = s;
    spQ[e][wr * 4 + lhi] = ss;
  }
  __syncthreads();   // (1)
  float mu1[2], rs1[2];
#pragma unroll
  for (int ni = 0; ni < 2; ++ni) {
    int e = wc * 32 + ni * 16 + llo;
    float s = 0.f, q2 = 0.f;
#pragma unroll
    for (int k = 0; k < 8; ++k) { s += spS[e][k]; q2 += spQ[e][k]; }
    float mu = s * 0.015625f, var = q2 * 0.015625f - mu * mu;
    mu1[ni] = mu; rs1[ni] = rsqrtf(var + LNEPS);
  }
#pragma unroll
  for (int mi = 0; mi < 2; ++mi) {
    f32x4 gv = *(const f32x4*)(gam + chb + mi * 16);
    f32x4 bv = *(const f32x4*)(bet + chb + mi * 16);
#pragma unroll
    for (int ni = 0; ni < 2; ++ni) {
      int e = wc * 32 + ni * 16 + llo;
      bf4 pk;
#pragma unroll
      for (int r = 0; r < 4; ++r)
        pk[r] = f2bf((x[mi][ni][r] - mu1[ni]) * rs1[ni] * gv[r] + bv[r]);
      *(bf4*)&Zb[e * 72 + chb + mi * 16] = pk;
    }
  }
  __syncthreads();   // (2)
  f32x4 ap[2][2] = {};
  f32x4 ag[2][2] = {};
#pragma unroll
  for (int ks = 0; ks < 2; ++ks) {
    bf8 z0 = *(const bf8*)&Zb[(wr * 32 + llo) * 72 + ks * 32 + fc];
    bf8 z1 = *(const bf8*)&Zb[(wr * 32 + 16 + llo) * 72 + ks * 32 + fc];
    bf8 p0 = *(const bf8*)&Wp[(wc * 32 + llo) * 72 + ks * 32 + fc];
    bf8 p1 = *(const bf8*)&Wp[(wc * 32 + 16 + llo) * 72 + ks * 32 + fc];
    bf8 g0 = *(const bf8*)&Wg[(wc * 32 + llo) * 72 + ks * 32 + fc];
    bf8 g1 = *(const bf8*)&Wg[(wc * 32 + 16 + llo) * 72 + ks * 32 + fc];
    ap[0][0] = MFMA(z0, p0, ap[0][0]);
    ap[0][1] = MFMA(z0, p1, ap[0][1]);
    ap[1][0] = MFMA(z1, p0, ap[1][0]);
    ap[1][1] = MFMA(z1, p1, ap[1][1]);
    ag[0][0] = MFMA(z0, g0, ag[0][0]);
    ag[0][1] = MFMA(z0, g1, ag[0][1]);
    ag[1][0] = MFMA(z1, g0, ag[1][0]);
    ag[1][1] = MFMA(z1, g1, ag[1][1]);
  }
#pragma unroll
  for (int mi = 0; mi < 2; ++mi) {
    int elemb = wr * 32 + mi * 16 + lhi * 4;
#pragma unroll
    for (int ni = 0; ni < 2; ++ni) {
      int ch = wc * 32 + ni * 16 + llo;
      float bp = b_abp[ch], bg = b_abg[ch];
      bf4 pack;
#pragma unroll
      for (int r = 0; r < 4; ++r)
        pack[r] = f2bf((ap[mi][ni][r] + bp) * sigmoidf_(ag[mi][ni][r] + bg));
      short* dst = (ch < 32) ? (aN + (long)ch * NNe) : (bN + (long)(ch - 32) * NNe);
      *(bf4*)(dst + ebase + elemb) = pack;
    }
  }
}

// ---------------- triangle einsum -> t bf16 (128x128 tile, batched, XCD swizzle) --------
__global__ __launch_bounds__(512) void tm_tri_mfma(const short* __restrict__ aN4,
                                                   const short* __restrict__ bN4,
                                                   short* __restrict__ t4) {
  int lin = blockIdx.z * 16 + blockIdx.y * 4 + blockIdx.x;   // 0..2047
  int vid = (lin & 7) * 256 + (lin >> 3);                    // bijective
  int hh = vid >> 4;        // 0..127
  int b = hh >> 5, h = hh & 31;
  int rem = vid & 15;
  int i0 = (rem >> 2) * 128, k0 = (rem & 3) * 128;
  const short* A = aN4 + (long)b * 8388608 + (long)h * NNe;
  const short* B = bN4 + (long)b * 8388608 + (long)h * NNe;
  __shared__ __align__(16) short A1[128 * 40];
  __shared__ __align__(16) short B1[128 * 40];
  __shared__ __align__(16) short A2[128 * 40];
  __shared__ __align__(16) short B2[128 * 40];
  int tid = threadIdx.x;
  int wv = tid >> 6, lane = tid & 63;
  int wr = wv >> 2, wc = wv & 3;
  int lhi = lane >> 4, llo = lane & 15;
  int r1 = tid >> 2, cp = (tid & 3) * 8;
  int s2 = tid >> 5, cg = (tid & 31) * 4;
  f32x4 acc[4][2] = {};
  for (int j0 = 0; j0 < 512; j0 += 32) {
    *(bf8*)&A1[r1 * 40 + cp] = *(const bf8*)(A + (long)(i0 + r1) * 512 + j0 + cp);
    *(bf8*)&B1[r1 * 40 + cp] = *(const bf8*)(B + (long)(k0 + r1) * 512 + j0 + cp);
    bf4 va0 = *(const bf4*)(A + (long)(j0 + 2 * s2) * 512 + i0 + cg);
    bf4 va1 = *(const bf4*)(A + (long)(j0 + 2 * s2 + 1) * 512 + i0 + cg);
    bf4 vb0 = *(const bf4*)(B + (long)(j0 + 2 * s2) * 512 + k0 + cg);
    bf4 vb1 = *(const bf4*)(B + (long)(j0 + 2 * s2 + 1) * 512 + k0 + cg);
#pragma unroll
    for (int q = 0; q < 4; ++q) {
      unsigned pa = (unsigned)(unsigned short)va0[q] |
                    ((unsigned)(unsigned short)va1[q] << 16);
      unsigned pb = (unsigned)(unsigned short)vb0[q] |
                    ((unsigned)(unsigned short)vb1[q] << 16);
      *(unsigned*)&A2[(cg + q) * 40 + 2 * s2] = pa;
      *(unsigned*)&B2[(cg + q) * 40 + 2 * s2] = pb;
    }
    __syncthreads();
    bf8 bfr[2], dfr[2];
#pragma unroll
    for (int ni = 0; ni < 2; ++ni) {
      bfr[ni] = *(const bf8*)&B1[(wc * 32 + ni * 16 + llo) * 40 + lhi * 8];
      dfr[ni] = *(const bf8*)&B2[(wc * 32 + ni * 16 + llo) * 40 + lhi * 8];
    }
#pragma unroll
    for (int mi = 0; mi < 4; ++mi) {
      bf8 a = *(const bf8*)&A1[(wr * 64 + mi * 16 + llo) * 40 + lhi * 8];
      acc[mi][0] = MFMA(a, bfr[0], acc[mi][0]);
      acc[mi][1] = MFMA(a, bfr[1], acc[mi][1]);
    }
#pragma unroll
    for (int mi = 0; mi < 4; ++mi) {
      bf8 c = *(const bf8*)&A2[(wr * 64 + mi * 16 + llo) * 40 + lhi * 8];
      acc[mi][0] = MFMA(c, dfr[0], acc[mi][0]);
      acc[mi][1] = MFMA(c, dfr[1], acc[mi][1]);
    }
    __syncthreads();
  }
  short* tp = t4 + (long)b * 8388608 + (long)h * NNe;
#pragma unroll
  for (int mi = 0; mi < 4; ++mi)
#pragma unroll
    for (int ni = 0; ni < 2; ++ni) {
      int row = i0 + wr * 64 + mi * 16 + lhi * 4;
      int col = k0 + wc * 32 + ni * 16 + llo;
#pragma unroll
      for (int r = 0; r < 4; ++r) tp[(long)(row + r) * 512 + col] = f2bf(acc[mi][ni][r]);
    }
}

// --- fused OPM-recompute + triangle update + pair FFN (128 elems / 512 thr) ---
__global__ __launch_bounds__(512) void upd_pffn_fused(
    const float* __restrict__ pin, float* __restrict__ pout,
    const short* __restrict__ t4,
    const short* __restrict__ Tb, const short* __restrict__ bo_bf,
    const float* __restrict__ b_out, const float* __restrict__ op_norm,
    const float* __restrict__ g_tm, const float* __restrict__ b_tm,
    const short* __restrict__ wg_a, const float* __restrict__ b_g,
    const short* __restrict__ wz_a, const float* __restrict__ b_z,
    const float* __restrict__ g_tmo, const float* __restrict__ b_tmo,
    const float* __restrict__ g_pf, const float* __restrict__ b_pf,
    const short* __restrict__ w1_a, const float* __restrict__ b1,
    const short* __restrict__ w2_a, const float* __restrict__ b2) {
  __shared__ __align__(16) short Zb[2][64 * 72];
  __shared__ __align__(16) short Tlb[2][64 * 40];
  __shared__ __align__(16) short Wbuf[64 * 72];
  __shared__ __align__(16) short Wzb[64 * 36];
  __shared__ float spS[2][64][9];
  __shared__ float spQ[2][64][9];
  __shared__ float spB[2][4][2][72];
  int tid = threadIdx.x;
  int grp = tid >> 8;          // 0/1: element group
  int t = tid & 255;
  long e0 = (long)blockIdx.x * 128 + grp * 64;
  int bbt = (int)(e0 >> 18);
  long el = e0 & (NNe - 1);
  long growT = e0 >> 9;
  int jt = (int)((e0 >> 6) & 7);
  int wv = t >> 6, lane = t & 63;
  int wr = wv >> 1, wc = wv & 1;
  int lhi = lane >> 4, llo = lane & 15;
  int chb = wr * 32 + lhi * 4;
  int fc = lhi * 8;
  int fr0 = wr * 32 + llo, fr1 = fr0 + 16;
  int br0 = wc * 32 + llo, br1 = br0 + 16;
  // weight staging: 1 bf8/thread covers 64x64
  int r0 = tid >> 3, c0 = (tid & 7) * 8;
  bf8 w1r, w2r;
  {
    *(bf8*)&Wbuf[r0 * 72 + c0] = *(const bf8*)(wg_a + r0 * 64 + c0);
    w1r = *(const bf8*)(w1_a + r0 * 64 + c0);
    w2r = *(const bf8*)(w2_a + r0 * 64 + c0);
    int rz = tid >> 3, cz = (tid & 7) * 4;
    *(bf4*)&Wzb[rz * 36 + cz] = *(const bf4*)(wz_a + rz * 32 + cz);
  }
  // X registers from fp32 pair input
  f32x4 x[2][2];
#pragma unroll
  for (int mi = 0; mi < 2; ++mi)
#pragma unroll
    for (int ni = 0; ni < 2; ++ni)
      x[mi][ni] = *(const f32x4*)(pin + (e0 + wc * 32 + ni * 16 + llo) * 64 +
                                  chb + mi * 16);
  // OPM recompute: direct global fragments
  {
    f32x4 acc[2][2] = {};
    bf8 a0 = *(const bf8*)(Tb + growT * 2048 + (long)fr0 * 32 + fc);
    bf8 a1 = *(const bf8*)(Tb + growT * 2048 + (long)fr1 * 32 + fc);
    bf8 b0 = *(const bf8*)(bo_bf + ((long)bbt * 512 + jt * 64 + br0) * 32 + fc);
    bf8 b1 = *(const bf8*)(bo_bf + ((long)bbt * 512 + jt * 64 + br1) * 32 + fc);
    acc[0][0] = MFMA(a0, b0, acc[0][0]);
    acc[0][1] = MFMA(a0, b1, acc[0][1]);
    acc[1][0] = MFMA(a1, b0, acc[1][0]);
    acc[1][1] = MFMA(a1, b1, acc[1][1]);
    float nrm = op_norm[0];
#pragma unroll
    for (int mi = 0; mi < 2; ++mi) {
      f32x4 bo4 = *(const f32x4*)(b_out + chb + mi * 16);
#pragma unroll
      for (int ni = 0; ni < 2; ++ni)
#pragma unroll
        for (int r = 0; r < 4; ++r)
          x[mi][ni][r] += (acc[mi][ni][r] + bo4[r]) * nrm;
    }
  }
  // LN1 partials
#pragma unroll
  for (int ni = 0; ni < 2; ++ni) {
    float s = 0.f, ss = 0.f;
#pragma unroll
    for (int mi = 0; mi < 2; ++mi)
#pragma unroll
      for (int r = 0; r < 4; ++r) { float v = x[mi][ni][r]; s += v; ss += v * v; }
    int e = wc * 32 + ni * 16 + llo;
    spS[grp][e][wr * 4 + lhi] = s;
    spQ[grp][e][wr * 4 + lhi] = ss;
  }
  // t loads + LN32 partials
  const short* t_in = t4 + (long)bbt * 8388608;
  int te = t & 63, tq = t >> 6;
  float tt[8];
  {
    float sB = 0.f, ssB = 0.f;
#pragma unroll
    for (int k = 0; k < 8; ++k) {
      float v = bf2f(t_in[(long)(tq * 8 + k) * NNe + el + te]);
      tt[k] = v; sB += v; ssB += v * v;
    }
    spB[grp][tq][0][te] = sB; spB[grp][tq][1][te] = ssB;
  }
  __syncthreads();   // (1)
  {
    float ts = spB[grp][0][0][te] + spB[grp][1][0][te] + spB[grp][2][0][te] +
               spB[grp][3][0][te];
    float tss = spB[grp][0][1][te] + spB[grp][1][1][te] + spB[grp][2][1][te] +
                spB[grp][3][1][te];
    float mu = ts * 0.03125f, var = tss * 0.03125f - mu * mu;
    float rs = rsqrtf(var + LNEPS);
    bf8 pk;
#pragma unroll
    for (int k = 0; k < 8; ++k) {
      int c = tq * 8 + k;
      pk[k] = f2bf((tt[k] - mu) * rs * g_tmo[c] + b_tmo[c]);
    }
    *(bf8*)&Tlb[grp][te * 40 + tq * 8] = pk;
  }
  float mu1[2], rs1[2];
#pragma unroll
  for (int ni = 0; ni < 2; ++ni) {
    int e = wc * 32 + ni * 16 + llo;
    float s = 0.f, q2 = 0.f;
#pragma unroll
    for (int k = 0; k < 8; ++k) { s += spS[grp][e][k]; q2 += spQ[grp][e][k]; }
    float mu = s * 0.015625f, var = q2 * 0.015625f - mu * mu;
    mu1[ni] = mu; rs1[ni] = rsqrtf(var + LNEPS);
  }
#pragma unroll
  for (int mi = 0; mi < 2; ++mi) {
    f32x4 gv = *(const f32x4*)(g_tm + chb + mi * 16);
    f32x4 bv = *(const f32x4*)(b_tm + chb + mi * 16);
#pragma unroll
    for (int ni = 0; ni < 2; ++ni) {
      int e = wc * 32 + ni * 16 + llo;
      bf4 pk;
#pragma unroll
      for (int r = 0; r < 4; ++r)
        pk[r] = f2bf((x[mi][ni][r] - mu1[ni]) * rs1[ni] * gv[r] + bv[r]);
      *(bf4*)&Zb[grp][e * 72 + chb + mi * 16] = pk;
    }
  }
  __syncthreads();   // (2)
  f32x4 accg[2][2] = {};
  f32x4 accz[2][2] = {};
#pragma unroll
  for (int ks = 0; ks < 2; ++ks) {
    bf8 a0 = *(const bf8*)&Wbuf[fr0 * 72 + ks * 32 + fc];
    bf8 a1 = *(const bf8*)&Wbuf[fr1 * 72 + ks * 32 + fc];
    bf8 z0 = *(const bf8*)&Zb[grp][br0 * 72 + ks * 32 + fc];
    bf8 z1 = *(const bf8*)&Zb[grp][br1 * 72 + ks * 32 + fc];
    accg[0][0] = MFMA(a0, z0, accg[0][0]);
    accg[0][1] = MFMA(a0, z1, accg[0][1]);
    accg[1][0] = MFMA(a1, z0, accg[1][0]);
    accg[1][1] = MFMA(a1, z1, accg[1][1]);
  }
  {
    bf8 a0 = *(const bf8*)&Wzb[fr0 * 36 + fc];
    bf8 a1 = *(const bf8*)&Wzb[fr1 * 36 + fc];
    bf8 t0 = *(const bf8*)&Tlb[grp][br0 * 40 + fc];
    bf8 t1 = *(const bf8*)&Tlb[grp][br1 * 40 + fc];
    accz[0][0] = MFMA(a0, t0, accz[0][0]);
    accz[0][1] = MFMA(a0, t1, accz[0][1]);
    accz[1][0] = MFMA(a1, t0, accz[1][0]);
    accz[1][1] = MFMA(a1, t1, accz[1][1]);
  }
#pragma unroll
  for (int mi = 0; mi < 2; ++mi) {
    f32x4 bgv = *(const f32x4*)(b_g + chb + mi * 16);
    f32x4 bzv = *(const f32x4*)(b_z + chb + mi * 16);
#pragma unroll
    for (int ni = 0; ni < 2; ++ni)
#pragma unroll
      for (int r = 0; r < 4; ++r)
        x[mi][ni][r] += (accg[mi][ni][r] + bgv[r]) * (accz[mi][ni][r] + bzv[r]);
  }
  // LN2 partials
#pragma unroll
  for (int ni = 0; ni < 2; ++ni) {
    float s = 0.f, ss = 0.f;
#pragma unroll
    for (int mi = 0; mi < 2; ++mi)
#pragma unroll
      for (int r = 0; r < 4; ++r) { float v = x[mi][ni][r]; s += v; ss += v * v; }
    int e = wc * 32 + ni * 16 + llo;
    spS[grp][e][wr * 4 + lhi] = s;
    spQ[grp][e][wr * 4 + lhi] = ss;
  }
  __syncthreads();   // (3)
  *(bf8*)&Wbuf[r0 * 72 + c0] = w1r;
#pragma unroll
  for (int ni = 0; ni < 2; ++ni) {
    int e = wc * 32 + ni * 16 + llo;
    float s = 0.f, q2 = 0.f;
#pragma unroll
    for (int k = 0; k < 8; ++k) { s += spS[grp][e][k]; q2 += spQ[grp][e][k]; }
    float mu = s * 0.015625f, var = q2 * 0.015625f - mu * mu;
    mu1[ni] = mu; rs1[ni] = rsqrtf(var + LNEPS);
  }
#pragma unroll
  for (int mi = 0; mi < 2; ++mi) {
    f32x4 gv = *(const f32x4*)(g_pf + chb + mi * 16);
    f32x4 bv = *(const f32x4*)(b_pf + chb + mi * 16);
#pragma unroll
    for (int ni = 0; ni < 2; ++ni) {
      int e = wc * 32 + ni * 16 + llo;
      bf4 pk;
#pragma unroll
      for (int r = 0; r < 4; ++r)
        pk[r] = f2bf((x[mi][ni][r] - mu1[ni]) * rs1[ni] * gv[r] + bv[r]);
      *(bf4*)&Zb[grp][e * 72 + chb + mi * 16] = pk;
    }
  }
  __syncthreads();   // (4)
  f32x4 acc1[2][2] = {};
#pragma unroll
  for (int ks = 0; ks < 2; ++ks) {
    bf8 a0 = *(const bf8*)&Wbuf[fr0 * 72 + ks * 32 + fc];
    bf8 a1 = *(const bf8*)&Wbuf[fr1 * 72 + ks * 32 + fc];
    bf8 z0 = *(const bf8*)&Zb[grp][br0 * 72 + ks * 32 + fc];
    bf8 z1 = *(const bf8*)&Zb[grp][br1 * 72 + ks * 32 + fc];
    acc1[0][0] = MFMA(a0, z0, acc1[0][0]);
    acc1[0][1] = MFMA(a0, z1, acc1[0][1]);
    acc1[1][0] = MFMA(a1, z0, acc1[1][0]);
    acc1[1][1] = MFMA(a1, z1, acc1[1][1]);
  }
  __syncthreads();   // (5)
  *(bf8*)&Wbuf[r0 * 72 + c0] = w2r;
#pragma unroll
  for (int mi = 0; mi < 2; ++mi) {
    f32x4 bv = *(const f32x4*)(b1 + chb + mi * 16);
#pragma unroll
    for (int ni = 0; ni < 2; ++ni) {
      int e = wc * 32 + ni * 16 + llo;
      bf4 pk;
#pragma unroll
      for (int r = 0; r < 4; ++r) pk[r] = f2bf(gelu_fast(acc1[mi][ni][r] + bv[r]));
      *(bf4*)&Zb[grp][e * 72 + chb + mi * 16] = pk;
    }
  }
  __syncthreads();   // (6)
  f32x4 acc2[2][2] = {};
#pragma unroll
  for (int ks = 0; ks < 2; ++ks) {
    bf8 a0 = *(const bf8*)&Wbuf[fr0 * 72 + ks * 32 + fc];
    bf8 a1 = *(const bf8*)&Wbuf[fr1 * 72 + ks * 32 + fc];
    bf8 z0 = *(const bf8*)&Zb[grp][br0 * 72 + ks * 32 + fc];
    bf8 z1 = *(const bf8*)&Zb[grp][br1 * 72 + ks * 32 + fc];
    acc2[0][0] = MFMA(a0, z0, acc2[0][0]);
    acc2[0][1] = MFMA(a0, z1, acc2[0][1]);
    acc2[1][0] = MFMA(a1, z0, acc2[1][0]);
    acc2[1][1] = MFMA(a1, z1, acc2[1][1]);
  }
#pragma unroll
  for (int mi = 0; mi < 2; ++mi) {
    f32x4 bv = *(const f32x4*)(b2 + chb + mi * 16);
#pragma unroll
    for (int ni = 0; ni < 2; ++ni) {
#pragma unroll
      for (int r = 0; r < 4; ++r) x[mi][ni][r] += acc2[mi][ni][r] + bv[r];
      *(f32x4*)(pout + (e0 + wc * 32 + ni * 16 + llo) * 64 + chb + mi * 16) =
          x[mi][ni];
    }
  }
}

extern "C" void kernel_launch(void* const* d_in, const int* in_sizes, int n_in,
                              void* d_out, int out_size, void* d_ws, size_t ws_size,
                              hipStream_t stream) {
  const float* x = (const float*)d_in[0];
  const float* pair = (const float*)d_in[1];
  const float* attn_mask = (const float*)d_in[2];
  const float* op_mask = (const float*)d_in[3];
  const float* op_norm = (const float*)d_in[4];
  const float* wq = (const float*)d_in[6];
  const float* wk = (const float*)d_in[7];
  const float* wv_ = (const float*)d_in[8];
  const float* wg = (const float*)d_in[9];
  const float* bg = (const float*)d_in[10];
  const float* wo = (const float*)d_in[11];
  const float* bo = (const float*)d_in[12];
  const float* ln_pair_g = (const float*)d_in[13];
  const float* ln_pair_b = (const float*)d_in[14];
  const float* wb = (const float*)d_in[15];
  const float* bb = (const float*)d_in[16];
  const float* ln_attn_g = (const float*)d_in[17];
  const float* ln_attn_b = (const float*)d_in[18];
  const float* ln_ffn_g = (const float*)d_in[19];
  const float* ln_ffn_b = (const float*)d_in[20];
  const float* w_ffn1 = (const float*)d_in[21];
  const float* b_ffn1 = (const float*)d_in[22];
  const float* w_ffn2 = (const float*)d_in[23];
  const float* b_ffn2 = (const float*)d_in[24];
  const float* ln_opm_g = (const float*)d_in[25];
  const float* ln_opm_b = (const float*)d_in[26];
  const float* w_opm_in = (const float*)d_in[27];
  const float* b_opm_in = (const float*)d_in[28];
  const float* w_opm_out = (const float*)d_in[29];
  const float* b_opm_out = (const float*)d_in[30];
  const float* ln_tm_g = (const float*)d_in[31];
  const float* ln_tm_b = (const float*)d_in[32];
  const float* w_tm_abp = (const float*)d_in[33];
  const float* b_tm_abp = (const float*)d_in[34];
  const float* w_tm_abg = (const float*)d_in[35];
  const float* b_tm_abg = (const float*)d_in[36];
  const float* w_tm_g = (const float*)d_in[37];
  const float* b_tm_g = (const float*)d_in[38];
  const float* w_tm_z = (const float*)d_in[39];
  const float* b_tm_z = (const float*)d_in[40];
  const float* ln_tmo_g = (const float*)d_in[41];
  const float* ln_tmo_b = (const float*)d_in[42];
  const float* ln_pffn_g = (const float*)d_in[43];
  const float* ln_pffn_b = (const float*)d_in[44];
  const float* w_pffn1 = (const float*)d_in[45];
  const float* b_pffn1 = (const float*)d_in[46];
  const float* w_pffn2 = (const float*)d_in[47];
  const float* b_pffn2 = (const float*)d_in[48];

  float* ws = (float*)d_ws;
  short* wbf = (short*)ws;
  short* wq_bf = wbf + 0;            // contiguous [3072][768] qkvg block
  short* wo_bf = wbf + 2359296;
  short* wf1_bf = wbf + 2949120;
  short* wf2_bf = wbf + 5308416;
  short* wop_bf = wbf + 7667712;
  short* wb_a = wbf + 7716864;
  short* wabp_a = wbf + 7717376;
  short* wabg_a = wbf + 7721472;
  short* wtg_a = wbf + 7725568;
  short* wtz_a = wbf + 7729664;
  short* wp1_a = wbf + 7731712;
  short* wp2_a = wbf + 7735808;

  short* h_bf = (short*)(ws + 3869952);
  short* q_bf = (short*)(ws + 4656384);
  short* k_bf = (short*)(ws + 5442816);
  short* vT_bf = (short*)(ws + 6229248);
  float* gb = ws + 7015680;
  short* gb_bf = (short*)(ws + 10161408);
  float* x1b = ws + 10947840;
  short* biasb_bf = (short*)(ws + 12520704);   // 8388608 bf16
  short* attn_bf = (short*)(ws + 16715008);    // 8388608 bf16
  short* mffn_bf = (short*)(ws + 20909312);    // 6291456 bf16
  float* abb = ws + 24055040;                  // 131072 f32
  short* abb_bf = (short*)(ws + 24186112);     // 65536 bf16 (bo, all batches)
  short* Tb_bf = (short*)(ws + 24218880);      // 4194304 bf16 (all batches)
  short* aN4 = (short*)(ws + 59870464);        // 4 x 8388608 bf16
  short* bN4 = (short*)(ws + 76647680);
  short* t4 = (short*)(ws + 93424896);

  float* xo = (float*)d_out;
  float* pair1 = xo + 1572864;

  const float qscale = 0.1020620726159658f;  // 96^-0.5

  // --- weight casts ---
  castw_kernel<<<30144, 256, 0, stream>>>(wq, wk, wv_, wg, wo, w_ffn1, w_ffn2, w_opm_in,
                                          wbf, qscale);
  castw2_kernel<<<90, 256, 0, stream>>>(wb, w_tm_abp, w_tm_abg, w_tm_g, w_tm_z,
                                        w_pffn1, w_pffn2, wb_a);
  // --- attention ---
  ln_bf_kernel<<<2048, 256, 0, stream>>>(x, h_bf, ln_attn_g, ln_attn_b, 768);
  gemm_qkvg<<<dim3(24, 16, 1), 256, 0, stream>>>(h_bf, wq_bf, q_bf, k_bf, vT_bf, gb, bg);
  pair_bias_mfma<<<16384, 256, 0, stream>>>(pair, ln_pair_g, ln_pair_b, wb_a, bb, biasb_bf);
  attn_fused<<<dim3(32, 8, 4), 256, 0, stream>>>(q_bf, k_bf, biasb_bf, attn_mask, attn_bf);
  // AV with fused output gate
  gemm_bf<<<dim3(2, 8, 32), 256, 0, stream>>>(attn_bf, 512, 2097152, 262144,
                                              vT_bf, 512, 393216, 49152,
                                              nullptr, 0, 393216, 96, gb_bf, 768,
                                              gb, 768, 393216, 96, nullptr,
                                              512, 96, 512, 2, 0, 8);
  gemm128<<<dim3(6, 16, 1), 256, 0, stream>>>(gb_bf, wo_bf, 768, x, bo, x1b);
  // --- FFN ---
  ln_bf_kernel<<<2048, 256, 0, stream>>>(x1b, h_bf, ln_ffn_g, ln_ffn_b, 768);
  gemm_ffn1<<<dim3(24, 16, 1), 256, 0, stream>>>(h_bf, wf1_bf, mffn_bf, b_ffn1);
  gemm128<<<dim3(6, 16, 1), 256, 0, stream>>>(mffn_bf, wf2_bf, 3072, x1b, b_ffn2, xo);
  // --- outer product mean prep ---
  ln_bf_kernel<<<2048, 256, 0, stream>>>(xo, h_bf, ln_opm_g, ln_opm_b, 768);
  gemm_bf<<<dim3(1, 32, 1), 256, 0, stream>>>(h_bf, 768, 0, 0, wop_bf, 768, 0, 0,
                                              abb, 64, 0, 0, nullptr, 0,
                                              nullptr, 0, 0, 0, b_opm_in,
                                              2048, 64, 768, 0, 0, 1);
  opmask_kernel<<<512, 256, 0, stream>>>(abb, op_mask, abb_bf);
  opm_T_kernel<<<dim3(256, 64, 1), dim3(32, 8, 1), 0, stream>>>(abb, w_opm_out, Tb_bf);
  // --- pair stack (batched over all 4 batches) ---
  opm_ab_fused<<<dim3(8, 512, 4), 256, 0, stream>>>(
      pair, Tb_bf, abb_bf, b_opm_out, op_norm,
      ln_tm_g, ln_tm_b, wabp_a, b_tm_abp, wabg_a, b_tm_abg, aN4, bN4);
  tm_tri_mfma<<<dim3(4, 4, 128), 512, 0, stream>>>(aN4, bN4, t4);
  upd_pffn_fused<<<8192, 512, 0, stream>>>(
      pair, pair1, t4, Tb_bf, abb_bf, b_opm_out, op_norm,
      ln_tm_g, ln_tm_b, wtg_a, b_tm_g, wtz_a, b_tm_z,
      ln_tmo_g, ln_tmo_b, ln_pffn_g, ln_pffn_b, wp1_a, b_pffn1, wp2_a, b_pffn2);
}

// Round 15
// 867.409 us; speedup vs baseline: 1.0599x; 1.0180x over previous
//
#include <hip/hip_runtime.h>
#include <hip/hip_bf16.h>
#include <math.h>

#define Nn 512
#define Ee 768
#define Pp 64
#define PHh 32
#define Hh 8
#define Dd 96
#define NNe 262144      // N*N
#define LNEPS 1e-5f

typedef __attribute__((ext_vector_type(8))) short bf8;
typedef __attribute__((ext_vector_type(4))) short bf4;
typedef __attribute__((ext_vector_type(4))) float f32x4;
#define MFMA(a,b,c) __builtin_amdgcn_mfma_f32_16x16x32_bf16(a,b,c,0,0,0)

__device__ __forceinline__ short f2bf(float f) {
  __bf16 h = (__bf16)f;
  return __builtin_bit_cast(short, h);
}
__device__ __forceinline__ float bf2f(short s) {
  unsigned u = ((unsigned)(unsigned short)s) << 16;
  return __builtin_bit_cast(float, u);
}

__device__ __forceinline__ float wave_red_sum(float v) {
#pragma unroll
  for (int off = 32; off > 0; off >>= 1) v += __shfl_xor(v, off);
  return v;
}
__device__ __forceinline__ float gelu_exact(float v) {
  return 0.5f * v * (1.f + erff(v * 0.70710678118654752f));
}
__device__ __forceinline__ float sigmoidf_(float v) {
  return 1.f / (1.f + __expf(-v));
}
__device__ __forceinline__ float gelu_fast(float v) {
  return v / (1.f + __expf(-1.702f * v));
}

// ---------------- weight casts to bf16 arena ----------------
__global__ __launch_bounds__(256) void castw_kernel(
    const float* __restrict__ wq, const float* __restrict__ wk,
    const float* __restrict__ wv, const float* __restrict__ wg,
    const float* __restrict__ wo, const float* __restrict__ f1,
    const float* __restrict__ f2, const float* __restrict__ wop,
    short* __restrict__ dst, float qs) {
  long i = (long)blockIdx.x * 256 + threadIdx.x;
  float v;
  if (i < 589824) v = wq[i] * qs;
  else if (i < 1179648) v = wk[i - 589824];
  else if (i < 1769472) v = wv[i - 1179648];
  else if (i < 2359296) v = wg[i - 1769472];
  else if (i < 2949120) v = wo[i - 2359296];
  else if (i < 5308416) v = f1[i - 2949120];
  else if (i < 7667712) v = f2[i - 5308416];
  else if (i < 7716864) v = wop[i - 7667712];
  else return;
  dst[i] = f2bf(v);
}

__global__ __launch_bounds__(256) void castw2_kernel(
    const float* __restrict__ wb, const float* __restrict__ abp,
    const float* __restrict__ abg, const float* __restrict__ wtg,
    const float* __restrict__ wtz, const float* __restrict__ p1,
    const float* __restrict__ p2, short* __restrict__ dst) {
  int i = blockIdx.x * 256 + threadIdx.x;
  float v;
  if (i < 512) v = wb[i];
  else if (i < 4608) v = abp[i - 512];
  else if (i < 8704) v = abg[i - 4608];
  else if (i < 12800) v = wtg[i - 8704];
  else if (i < 14848) v = wtz[i - 12800];
  else if (i < 18944) v = p1[i - 14848];
  else if (i < 23040) v = p2[i - 18944];
  else return;
  dst[i] = f2bf(v);
}

// ---------------- LayerNorm over last dim C -> bf16 out ----------------
__global__ __launch_bounds__(256) void ln_bf_kernel(const float* __restrict__ in,
                                                    short* __restrict__ out,
                                                    const float* __restrict__ gam,
                                                    const float* __restrict__ bet, int C) {
  int row = blockIdx.x;
  const float* xr = in + (long)row * C;
  short* yr = out + (long)row * C;
  float s = 0.f, ss = 0.f;
  for (int c = threadIdx.x; c < C; c += 256) { float v = xr[c]; s += v; ss += v * v; }
  s = wave_red_sum(s); ss = wave_red_sum(ss);
  __shared__ float sm[4][2];
  int wv = threadIdx.x >> 6, lane = threadIdx.x & 63;
  if (lane == 0) { sm[wv][0] = s; sm[wv][1] = ss; }
  __syncthreads();
  float ts = sm[0][0] + sm[1][0] + sm[2][0] + sm[3][0];
  float tss = sm[0][1] + sm[1][1] + sm[2][1] + sm[3][1];
  float mu = ts / C;
  float var = tss / C - mu * mu;
  float rs = rsqrtf(var + LNEPS);
  for (int c = threadIdx.x; c < C; c += 256) {
    float v = xr[c];
    yr[c] = f2bf((v - mu) * rs * gam[c] + bet[c]);
  }
}

// ---------------- bf16 MFMA NT GEMM, 64x64, BK=64 ----------------
__global__ __launch_bounds__(256) void gemm_bf(
    const short* __restrict__ A, int lda, long asB, long asH,
    const short* __restrict__ Bm, int ldb, long bsB, long bsH,
    float* __restrict__ outF, int ldf, long fsB, long fsH,
    short* __restrict__ outB, int ldob,
    const float* __restrict__ resid, int ldr, long rsB, long rsH,
    const float* __restrict__ bias,
    int M, int N, int K, int act, int vtrans, int Hdim) {
  int bz = blockIdx.z, bb = bz / Hdim, hh = bz % Hdim;
  A += bb * asB + hh * asH;
  Bm += bb * bsB + hh * bsH;
  if (outF) outF += bb * fsB + hh * fsH;
  if (outB) outB += bb * fsB + hh * fsH;
  if (resid) resid += bb * rsB + hh * rsH;
  __shared__ __align__(16) short As[64 * 72];
  __shared__ __align__(16) short Bs[64 * 72];
  int m0 = blockIdx.y * 64, n0 = blockIdx.x * 64;
  int tid = threadIdx.x;
  int wv = tid >> 6, lane = tid & 63;
  int wr = wv >> 1, wc = wv & 1;
  int lhi = lane >> 4, llo = lane & 15;
  int r4 = tid >> 2, c8 = (tid & 3) * 8;
  f32x4 acc[2][2] = {};
  for (int k0 = 0; k0 < K; k0 += 64) {
    *(bf8*)&As[r4 * 72 + c8] = *(const bf8*)(A + (long)(m0 + r4) * lda + k0 + c8);
    *(bf8*)&As[r4 * 72 + 32 + c8] =
        *(const bf8*)(A + (long)(m0 + r4) * lda + k0 + 32 + c8);
    bf8 bv0 = {}, bv1 = {};
    if (n0 + r4 < N) {
      bv0 = *(const bf8*)(Bm + (long)(n0 + r4) * ldb + k0 + c8);
      bv1 = *(const bf8*)(Bm + (long)(n0 + r4) * ldb + k0 + 32 + c8);
    }
    *(bf8*)&Bs[r4 * 72 + c8] = bv0;
    *(bf8*)&Bs[r4 * 72 + 32 + c8] = bv1;
    __syncthreads();
#pragma unroll
    for (int ks = 0; ks < 2; ++ks) {
      bf8 a0 = *(const bf8*)&As[(wr * 32 + llo) * 72 + ks * 32 + lhi * 8];
      bf8 a1 = *(const bf8*)&As[(wr * 32 + 16 + llo) * 72 + ks * 32 + lhi * 8];
      bf8 b0 = *(const bf8*)&Bs[(wc * 32 + llo) * 72 + ks * 32 + lhi * 8];
      bf8 b1 = *(const bf8*)&Bs[(wc * 32 + 16 + llo) * 72 + ks * 32 + lhi * 8];
      acc[0][0] = MFMA(a0, b0, acc[0][0]);
      acc[0][1] = MFMA(a0, b1, acc[0][1]);
      acc[1][0] = MFMA(a1, b0, acc[1][0]);
      acc[1][1] = MFMA(a1, b1, acc[1][1]);
    }
    __syncthreads();
  }
#pragma unroll
  for (int mi = 0; mi < 2; ++mi) {
    int gmb = m0 + wr * 32 + mi * 16 + lhi * 4;
#pragma unroll
    for (int ni = 0; ni < 2; ++ni) {
      int gn = n0 + wc * 32 + ni * 16 + llo;
      if (gn >= N) continue;
      float bv = bias ? bias[gn] : 0.f;
      float vr[4];
#pragma unroll
      for (int r = 0; r < 4; ++r) {
        float v = acc[mi][ni][r] + bv;
        if (resid) {
          float rv = resid[(long)(gmb + r) * ldr + gn];
          if (act == 2) v = sigmoidf_(rv) * acc[mi][ni][r];
          else v += rv;
        }
        if (act == 1) v = gelu_exact(v);
        vr[r] = v;
      }
      if (outF) {
#pragma unroll
        for (int r = 0; r < 4; ++r) outF[(long)(gmb + r) * ldf + gn] = vr[r];
      }
      if (outB) {
        if (vtrans) {
          bf4 pk;
#pragma unroll
          for (int r = 0; r < 4; ++r) pk[r] = f2bf(vr[r]);
          *(bf4*)(outB + ((long)((gmb >> 9) * 768 + gn) * 512 + (gmb & 511))) = pk;
        } else {
#pragma unroll
          for (int r = 0; r < 4; ++r) outB[(long)(gmb + r) * ldob + gn] = f2bf(vr[r]);
        }
      }
    }
  }
}

// ---------------- 128x128 tile: QKVG projection ----------------
__global__ __launch_bounds__(256) void gemm_qkvg(
    const short* __restrict__ A, const short* __restrict__ W,
    short* __restrict__ q_bf, short* __restrict__ k_bf,
    short* __restrict__ vT_bf, float* __restrict__ gb,
    const float* __restrict__ bg) {
  __shared__ __align__(16) short As[128 * 40];
  __shared__ __align__(16) short Bs[128 * 40];
  int m0 = blockIdx.y * 128, n0 = blockIdx.x * 128;
  int sec = n0 / 768;
  int cbase = n0 - sec * 768;
  int tid = threadIdx.x;
  int wv = tid >> 6, lane = tid & 63;
  int wr = wv >> 1, wc = wv & 1;
  int lhi = lane >> 4, llo = lane & 15;
  int r4 = tid >> 2, c8 = (tid & 3) * 8;
  f32x4 acc[4][4] = {};
  for (int k0 = 0; k0 < 768; k0 += 32) {
    *(bf8*)&As[r4 * 40 + c8] = *(const bf8*)(A + (long)(m0 + r4) * 768 + k0 + c8);
    *(bf8*)&As[(r4 + 64) * 40 + c8] =
        *(const bf8*)(A + (long)(m0 + r4 + 64) * 768 + k0 + c8);
    *(bf8*)&Bs[r4 * 40 + c8] = *(const bf8*)(W + (long)(n0 + r4) * 768 + k0 + c8);
    *(bf8*)&Bs[(r4 + 64) * 40 + c8] =
        *(const bf8*)(W + (long)(n0 + r4 + 64) * 768 + k0 + c8);
    __syncthreads();
    bf8 af[4], bfm[4];
#pragma unroll
    for (int mi = 0; mi < 4; ++mi)
      af[mi] = *(const bf8*)&As[(wr * 64 + mi * 16 + llo) * 40 + lhi * 8];
#pragma unroll
    for (int ni = 0; ni < 4; ++ni)
      bfm[ni] = *(const bf8*)&Bs[(wc * 64 + ni * 16 + llo) * 40 + lhi * 8];
#pragma unroll
    for (int mi = 0; mi < 4; ++mi)
#pragma unroll
      for (int ni = 0; ni < 4; ++ni)
        acc[mi][ni] = MFMA(af[mi], bfm[ni], acc[mi][ni]);
    __syncthreads();
  }
#pragma unroll
  for (int mi = 0; mi < 4; ++mi) {
    int gmb = m0 + wr * 64 + mi * 16 + lhi * 4;
#pragma unroll
    for (int ni = 0; ni < 4; ++ni) {
      int cn = cbase + wc * 64 + ni * 16 + llo;
      if (sec == 0) {
#pragma unroll
        for (int r = 0; r < 4; ++r) q_bf[(long)(gmb + r) * 768 + cn] = f2bf(acc[mi][ni][r]);
      } else if (sec == 1) {
#pragma unroll
        for (int r = 0; r < 4; ++r) k_bf[(long)(gmb + r) * 768 + cn] = f2bf(acc[mi][ni][r]);
      } else if (sec == 2) {
        bf4 pk;
#pragma unroll
        for (int r = 0; r < 4; ++r) pk[r] = f2bf(acc[mi][ni][r]);
        *(bf4*)(vT_bf + ((long)((gmb >> 9) * 768 + cn) * 512 + (gmb & 511))) = pk;
      } else {
        float bv = bg[cn];
#pragma unroll
        for (int r = 0; r < 4; ++r) gb[(long)(gmb + r) * 768 + cn] = acc[mi][ni][r] + bv;
      }
    }
  }
}

// ---------------- 128x128 tile: FFN1 (gelu exact, bf16 out) ----------------
__global__ __launch_bounds__(256) void gemm_ffn1(
    const short* __restrict__ A, const short* __restrict__ W,
    short* __restrict__ outB, const float* __restrict__ bias) {
  __shared__ __align__(16) short As[128 * 40];
  __shared__ __align__(16) short Bs[128 * 40];
  int m0 = blockIdx.y * 128, n0 = blockIdx.x * 128;
  int tid = threadIdx.x;
  int wv = tid >> 6, lane = tid & 63;
  int wr = wv >> 1, wc = wv & 1;
  int lhi = lane >> 4, llo = lane & 15;
  int r4 = tid >> 2, c8 = (tid & 3) * 8;
  f32x4 acc[4][4] = {};
  for (int k0 = 0; k0 < 768; k0 += 32) {
    *(bf8*)&As[r4 * 40 + c8] = *(const bf8*)(A + (long)(m0 + r4) * 768 + k0 + c8);
    *(bf8*)&As[(r4 + 64) * 40 + c8] =
        *(const bf8*)(A + (long)(m0 + r4 + 64) * 768 + k0 + c8);
    *(bf8*)&Bs[r4 * 40 + c8] = *(const bf8*)(W + (long)(n0 + r4) * 768 + k0 + c8);
    *(bf8*)&Bs[(r4 + 64) * 40 + c8] =
        *(const bf8*)(W + (long)(n0 + r4 + 64) * 768 + k0 + c8);
    __syncthreads();
    bf8 af[4], bfm[4];
#pragma unroll
    for (int mi = 0; mi < 4; ++mi)
      af[mi] = *(const bf8*)&As[(wr * 64 + mi * 16 + llo) * 40 + lhi * 8];
#pragma unroll
    for (int ni = 0; ni < 4; ++ni)
      bfm[ni] = *(const bf8*)&Bs[(wc * 64 + ni * 16 + llo) * 40 + lhi * 8];
#pragma unroll
    for (int mi = 0; mi < 4; ++mi)
#pragma unroll
      for (int ni = 0; ni < 4; ++ni)
        acc[mi][ni] = MFMA(af[mi], bfm[ni], acc[mi][ni]);
    __syncthreads();
  }
#pragma unroll
  for (int mi = 0; mi < 4; ++mi) {
    int gmb = m0 + wr * 64 + mi * 16 + lhi * 4;
#pragma unroll
    for (int ni = 0; ni < 4; ++ni) {
      int gn = n0 + wc * 64 + ni * 16 + llo;
      float bv = bias[gn];
#pragma unroll
      for (int r = 0; r < 4; ++r)
        outB[(long)(gmb + r) * 3072 + gn] = f2bf(gelu_exact(acc[mi][ni][r] + bv));
    }
  }
}

// ---------------- 128x128 tile: generic NT fp32 out + resid + bias (wo, ffn2) ----------
__global__ __launch_bounds__(256) void gemm128(
    const short* __restrict__ A, const short* __restrict__ W, int K,
    const float* __restrict__ resid, const float* __restrict__ bias,
    float* __restrict__ outF) {
  __shared__ __align__(16) short As[128 * 40];
  __shared__ __align__(16) short Bs[128 * 40];
  int m0 = blockIdx.y * 128, n0 = blockIdx.x * 128;
  int tid = threadIdx.x;
  int wv = tid >> 6, lane = tid & 63;
  int wr = wv >> 1, wc = wv & 1;
  int lhi = lane >> 4, llo = lane & 15;
  int r4 = tid >> 2, c8 = (tid & 3) * 8;
  f32x4 acc[4][4] = {};
  for (int k0 = 0; k0 < K; k0 += 32) {
    *(bf8*)&As[r4 * 40 + c8] = *(const bf8*)(A + (long)(m0 + r4) * K + k0 + c8);
    *(bf8*)&As[(r4 + 64) * 40 + c8] =
        *(const bf8*)(A + (long)(m0 + r4 + 64) * K + k0 + c8);
    *(bf8*)&Bs[r4 * 40 + c8] = *(const bf8*)(W + (long)(n0 + r4) * K + k0 + c8);
    *(bf8*)&Bs[(r4 + 64) * 40 + c8] =
        *(const bf8*)(W + (long)(n0 + r4 + 64) * K + k0 + c8);
    __syncthreads();
    bf8 af[4], bfm[4];
#pragma unroll
    for (int mi = 0; mi < 4; ++mi)
      af[mi] = *(const bf8*)&As[(wr * 64 + mi * 16 + llo) * 40 + lhi * 8];
#pragma unroll
    for (int ni = 0; ni < 4; ++ni)
      bfm[ni] = *(const bf8*)&Bs[(wc * 64 + ni * 16 + llo) * 40 + lhi * 8];
#pragma unroll
    for (int mi = 0; mi < 4; ++mi)
#pragma unroll
      for (int ni = 0; ni < 4; ++ni)
        acc[mi][ni] = MFMA(af[mi], bfm[ni], acc[mi][ni]);
    __syncthreads();
  }
#pragma unroll
  for (int mi = 0; mi < 4; ++mi) {
    int gmb = m0 + wr * 64 + mi * 16 + lhi * 4;
#pragma unroll
    for (int ni = 0; ni < 4; ++ni) {
      int gn = n0 + wc * 64 + ni * 16 + llo;
      float bv = bias[gn];
#pragma unroll
      for (int r = 0; r < 4; ++r)
        outF[(long)(gmb + r) * 768 + gn] =
            acc[mi][ni][r] + bv + resid[(long)(gmb + r) * 768 + gn];
    }
  }
}

// ---------------- fused scores + softmax (flash-row, 16 rows/block) ----------------
__global__ __launch_bounds__(256) void attn_fused(
    const short* __restrict__ q_bf, const short* __restrict__ k_bf,
    const short* __restrict__ bias_bf, const float* __restrict__ mask,
    short* __restrict__ out_bf) {
  int it = blockIdx.x, h = blockIdx.y, b = blockIdx.z;
  int tid = threadIdx.x;
  int wv = tid >> 6, lane = tid & 63;
  int lhi = lane >> 4, llo = lane & 15;
  int i0 = it * 16;
  long qoff = ((long)(b * 512 + i0)) * 768 + h * 96;
  bf8 qf[3];
#pragma unroll
  for (int ks = 0; ks < 3; ++ks)
    qf[ks] = *(const bf8*)(q_bf + qoff + (long)llo * 768 + ks * 32 + lhi * 8);
  long koff = ((long)b * 512) * 768 + h * 96;
  long bioff = (long)(b * 8 + h) * NNe + (long)i0 * 512;
  long moff = (long)b * NNe + (long)i0 * 512;
  float sv[8][4];
  int jb0 = wv * 128;
#pragma unroll
  for (int jf = 0; jf < 8; ++jf) {
    int jb = jb0 + jf * 16;
    f32x4 acc = {0.f, 0.f, 0.f, 0.f};
#pragma unroll
    for (int ks = 0; ks < 3; ++ks) {
      bf8 kf = *(const bf8*)(k_bf + koff + (long)(jb + llo) * 768 + ks * 32 + lhi * 8);
      acc = MFMA(qf[ks], kf, acc);
    }
#pragma unroll
    for (int r = 0; r < 4; ++r) {
      int irow = lhi * 4 + r;
      int j = jb + llo;
      float bia = bf2f(bias_bf[bioff + (long)irow * 512 + j]);
      float mk = mask[moff + (long)irow * 512 + j];
      sv[jf][r] = acc[r] + bia + mk;
    }
  }
  __shared__ float redA[4][20];
  __shared__ float redB[4][20];
  float rmax[4];
#pragma unroll
  for (int r = 0; r < 4; ++r) {
    float m = sv[0][r];
#pragma unroll
    for (int jf = 1; jf < 8; ++jf) m = fmaxf(m, sv[jf][r]);
#pragma unroll
    for (int off = 1; off < 16; off <<= 1) m = fmaxf(m, __shfl_xor(m, off, 16));
    if (llo == 0) redA[wv][lhi * 4 + r] = m;
  }
  __syncthreads();
#pragma unroll
  for (int r = 0; r < 4; ++r) {
    int row = lhi * 4 + r;
    rmax[r] = fmaxf(fmaxf(redA[0][row], redA[1][row]),
                    fmaxf(redA[2][row], redA[3][row]));
  }
  float rsum[4] = {0.f, 0.f, 0.f, 0.f};
#pragma unroll
  for (int jf = 0; jf < 8; ++jf)
#pragma unroll
    for (int r = 0; r < 4; ++r) {
      float e = __expf(sv[jf][r] - rmax[r]);
      sv[jf][r] = e;
      rsum[r] += e;
    }
#pragma unroll
  for (int r = 0; r < 4; ++r) {
#pragma unroll
    for (int off = 1; off < 16; off <<= 1) rsum[r] += __shfl_xor(rsum[r], off, 16);
    if (llo == 0) redB[wv][lhi * 4 + r] = rsum[r];
  }
  __syncthreads();
#pragma unroll
  for (int r = 0; r < 4; ++r) {
    int row = lhi * 4 + r;
    float s = redB[0][row] + redB[1][row] + redB[2][row] + redB[3][row];
    float inv = 1.f / s;
#pragma unroll
    for (int jf = 0; jf < 8; ++jf) {
      int j = jb0 + jf * 16 + llo;
      out_bf[bioff + (long)row * 512 + j] = f2bf(sv[jf][r] * inv);
    }
  }
}

// ---------------- ab *= op_mask ; emit b-half bf16 ----------------
__global__ __launch_bounds__(256) void opmask_kernel(float* __restrict__ ab,
                                                     const float* __restrict__ mask,
                                                     short* __restrict__ bo_bf) {
  int idx = blockIdx.x * 256 + threadIdx.x;
  if (idx < 131072) {
    float v = ab[idx] * mask[idx >> 6];
    ab[idx] = v;
    int ch = idx & 63;
    if (ch >= 32) bo_bf[(idx >> 6) * 32 + ch - 32] = f2bf(v);
  }
}

// ---------------- T[row,p,e] (bf16) ----------------
__global__ __launch_bounds__(256) void opm_T_kernel(const float* __restrict__ ab,
                                                    const float* __restrict__ w,
                                                    short* __restrict__ T) {
  int p = blockIdx.y;
  int row = blockIdx.x * 8 + threadIdx.y;
  int e = threadIdx.x;
  const float* a = ab + (long)row * 64;
  const float* wp = w + p * 1024 + e;
  float acc = 0.f;
#pragma unroll
  for (int d = 0; d < 32; ++d) acc += a[d] * wp[d * 32];
  T[((long)row * 64 + p) * 32 + e] = f2bf(acc);
}

// ---------------- pair bias: register LN ----------------
__global__ __launch_bounds__(256) void pair_bias_mfma(
    const float* __restrict__ pair, const float* __restrict__ gam,
    const float* __restrict__ bet, const short* __restrict__ wb_a,
    const float* __restrict__ bbv, short* __restrict__ bias) {
  __shared__ __align__(16) short Zb[64 * 72];
  __shared__ __align__(16) short Wb[16 * 72];
  __shared__ float sp[4][2][72];
  int tid = threadIdx.x;
  long e0 = (long)blockIdx.x * 64;
  int b = (int)(e0 >> 18);
  long ein = e0 & (NNe - 1);
  const float* base = pair + e0 * 64;
  for (int l = tid; l < 1024; l += 256) {
    int h = l >> 6, c = l & 63;
    Wb[h * 72 + c] = (h < 8) ? wb_a[h * 64 + c] : (short)0;
  }
  int e = tid & 63, q = tid >> 6;
  f32x4 v4[4];
  float s = 0.f, ss = 0.f;
#pragma unroll
  for (int k = 0; k < 4; ++k) {
    v4[k] = *(const f32x4*)(base + (long)e * 64 + q * 16 + k * 4);
#pragma unroll
    for (int u = 0; u < 4; ++u) { float v = v4[k][u]; s += v; ss += v * v; }
  }
  sp[q][0][e] = s; sp[q][1][e] = ss;
  __syncthreads();
  float ts = sp[0][0][e] + sp[1][0][e] + sp[2][0][e] + sp[3][0][e];
  float tss = sp[0][1][e] + sp[1][1][e] + sp[2][1][e] + sp[3][1][e];
  float mu = ts * 0.015625f, var = tss * 0.015625f - mu * mu;
  float rs = rsqrtf(var + LNEPS);
#pragma unroll
  for (int k = 0; k < 4; ++k) {
    bf4 pk;
#pragma unroll
    for (int u = 0; u < 4; ++u) {
      int c = q * 16 + k * 4 + u;
      pk[u] = f2bf((v4[k][u] - mu) * rs * gam[c] + bet[c]);
    }
    *(bf4*)&Zb[e * 72 + q * 16 + k * 4] = pk;
  }
  __syncthreads();
  int wv = tid >> 6, lane = tid & 63;
  int lhi = lane >> 4, llo = lane & 15;
  int n0 = wv * 16;
  f32x4 acc = {0.f, 0.f, 0.f, 0.f};
#pragma unroll
  for (int ks = 0; ks < 2; ++ks) {
    bf8 a = *(const bf8*)&Wb[llo * 72 + ks * 32 + lhi * 8];
    bf8 bz = *(const bf8*)&Zb[(n0 + llo) * 72 + ks * 32 + lhi * 8];
    acc = MFMA(a, bz, acc);
  }
  int elem = n0 + llo;
#pragma unroll
  for (int r = 0; r < 4; ++r) {
    int h = lhi * 4 + r;
    if (h < 8) bias[(long)(b * 8 + h) * NNe + ein + elem] = f2bf(acc[r] + bbv[h]);
  }
}

// -------- opm + triangle ab (128 elems / 512 thr, batched z=4) --------
__global__ __launch_bounds__(512) void opm_ab_fused(
    const float* __restrict__ pair_in, const short* __restrict__ Tb,
    const short* __restrict__ bo_bf, const float* __restrict__ b_out,
    const float* __restrict__ op_norm, const float* __restrict__ gam,
    const float* __restrict__ bet, const short* __restrict__ wp_a,
    const float* __restrict__ b_abp, const short* __restrict__ wg_a,
    const float* __restrict__ b_abg,
    short* __restrict__ aN4, short* __restrict__ bN4) {
  int jp = blockIdx.x;   // 0..3 (jt pair)
  int i = blockIdx.y;    // 0..511
  int bb = blockIdx.z;   // 0..3
  int tid = threadIdx.x;
  __shared__ __align__(16) short Zb[2][64 * 72];
  __shared__ __align__(16) short Wp[64 * 72];
  __shared__ __align__(16) short Wg[64 * 72];
  __shared__ float spS[2][64][9];
  __shared__ float spQ[2][64][9];
  int grp = tid >> 8;
  int t = tid & 255;
  int jt = jp * 2 + grp;
  int wv = t >> 6, lane = t & 63;
  int wr = wv >> 1, wc = wv & 1;
  int lhi = lane >> 4, llo = lane & 15;
  int chb = wr * 32 + lhi * 4;
  int fc = lhi * 8;
  {
    int r = tid >> 3, c8 = (tid & 7) * 8;
    *(bf8*)&Wp[r * 72 + c8] = *(const bf8*)(wp_a + r * 64 + c8);
    *(bf8*)&Wg[r * 72 + c8] = *(const bf8*)(wg_a + r * 64 + c8);
  }
  long grow = (long)bb * 512 + i;
  long ebase = (long)i * 512 + jt * 64;
  const float* pbase = pair_in + ((long)bb * NNe + ebase) * 64;
  short* aN = aN4 + (long)bb * 8388608;
  short* bN = bN4 + (long)bb * 8388608;
  f32x4 x[2][2];
#pragma unroll
  for (int mi = 0; mi < 2; ++mi)
#pragma unroll
    for (int ni = 0; ni < 2; ++ni)
      x[mi][ni] = *(const f32x4*)(pbase + (long)(wc * 32 + ni * 16 + llo) * 64 +
                                  chb + mi * 16);
  {
    f32x4 acc[2][2] = {};
    bf8 a0 = *(const bf8*)(Tb + grow * 2048 + (long)(wr * 32 + llo) * 32 + fc);
    bf8 a1 = *(const bf8*)(Tb + grow * 2048 + (long)(wr * 32 + 16 + llo) * 32 + fc);
    bf8 b0 = *(const bf8*)(bo_bf + ((long)bb * 512 + jt * 64 + wc * 32 + llo) * 32 + fc);
    bf8 b1 = *(const bf8*)(bo_bf +
                           ((long)bb * 512 + jt * 64 + wc * 32 + 16 + llo) * 32 + fc);
    acc[0][0] = MFMA(a0, b0, acc[0][0]);
    acc[0][1] = MFMA(a0, b1, acc[0][1]);
    acc[1][0] = MFMA(a1, b0, acc[1][0]);
    acc[1][1] = MFMA(a1, b1, acc[1][1]);
    float nrm = op_norm[0];
#pragma unroll
    for (int mi = 0; mi < 2; ++mi) {
      f32x4 bo4 = *(const f32x4*)(b_out + chb + mi * 16);
#pragma unroll
      for (int ni = 0; ni < 2; ++ni)
#pragma unroll
        for (int r = 0; r < 4; ++r)
          x[mi][ni][r] += (acc[mi][ni][r] + bo4[r]) * nrm;
    }
  }
#pragma unroll
  for (int ni = 0; ni < 2; ++ni) {
    float s = 0.f, ss = 0.f;
#pragma unroll
    for (int mi = 0; mi < 2; ++mi)
#pragma unroll
      for (int r = 0; r < 4; ++r) { float v = x[mi][ni][r]; s += v; ss += v * v; }
    int e = wc * 32 + ni * 16 + llo;
    spS[grp][e][wr * 4 + lhi] = s;
    spQ[grp][e][wr * 4 + lhi] = ss;
  }
  __syncthreads();   // (1)
  float mu1[2], rs1[2];
#pragma unroll
  for (int ni = 0; ni < 2; ++ni) {
    int e = wc * 32 + ni * 16 + llo;
    float s = 0.f, q2 = 0.f;
#pragma unroll
    for (int k = 0; k < 8; ++k) { s += spS[grp][e][k]; q2 += spQ[grp][e][k]; }
    float mu = s * 0.015625f, var = q2 * 0.015625f - mu * mu;
    mu1[ni] = mu; rs1[ni] = rsqrtf(var + LNEPS);
  }
#pragma unroll
  for (int mi = 0; mi < 2; ++mi) {
    f32x4 gv = *(const f32x4*)(gam + chb + mi * 16);
    f32x4 bv = *(const f32x4*)(bet + chb + mi * 16);
#pragma unroll
    for (int ni = 0; ni < 2; ++ni) {
      int e = wc * 32 + ni * 16 + llo;
      bf4 pk;
#pragma unroll
      for (int r = 0; r < 4; ++r)
        pk[r] = f2bf((x[mi][ni][r] - mu1[ni]) * rs1[ni] * gv[r] + bv[r]);
      *(bf4*)&Zb[grp][e * 72 + chb + mi * 16] = pk;
    }
  }
  __syncthreads();   // (2)
  f32x4 ap[2][2] = {};
  f32x4 ag[2][2] = {};
#pragma unroll
  for (int ks = 0; ks < 2; ++ks) {
    bf8 z0 = *(const bf8*)&Zb[grp][(wr * 32 + llo) * 72 + ks * 32 + fc];
    bf8 z1 = *(const bf8*)&Zb[grp][(wr * 32 + 16 + llo) * 72 + ks * 32 + fc];
    bf8 p0 = *(const bf8*)&Wp[(wc * 32 + llo) * 72 + ks * 32 + fc];
    bf8 p1 = *(const bf8*)&Wp[(wc * 32 + 16 + llo) * 72 + ks * 32 + fc];
    bf8 g0 = *(const bf8*)&Wg[(wc * 32 + llo) * 72 + ks * 32 + fc];
    bf8 g1 = *(const bf8*)&Wg[(wc * 32 + 16 + llo) * 72 + ks * 32 + fc];
    ap[0][0] = MFMA(z0, p0, ap[0][0]);
    ap[0][1] = MFMA(z0, p1, ap[0][1]);
    ap[1][0] = MFMA(z1, p0, ap[1][0]);
    ap[1][1] = MFMA(z1, p1, ap[1][1]);
    ag[0][0] = MFMA(z0, g0, ag[0][0]);
    ag[0][1] = MFMA(z0, g1, ag[0][1]);
    ag[1][0] = MFMA(z1, g0, ag[1][0]);
    ag[1][1] = MFMA(z1, g1, ag[1][1]);
  }
#pragma unroll
  for (int mi = 0; mi < 2; ++mi) {
    int elemb = wr * 32 + mi * 16 + lhi * 4;
#pragma unroll
    for (int ni = 0; ni < 2; ++ni) {
      int ch = wc * 32 + ni * 16 + llo;
      float bp = b_abp[ch], bg = b_abg[ch];
      bf4 pack;
#pragma unroll
      for (int r = 0; r < 4; ++r)
        pack[r] = f2bf((ap[mi][ni][r] + bp) * sigmoidf_(ag[mi][ni][r] + bg));
      short* dst = (ch < 32) ? (aN + (long)ch * NNe) : (bN + (long)(ch - 32) * NNe);
      *(bf4*)(dst + ebase + elemb) = pack;
    }
  }
}

// ---------------- triangle einsum -> t bf16 (128x128 tile, batched, XCD swizzle) --------
__global__ __launch_bounds__(512) void tm_tri_mfma(const short* __restrict__ aN4,
                                                   const short* __restrict__ bN4,
                                                   short* __restrict__ t4) {
  int lin = blockIdx.z * 16 + blockIdx.y * 4 + blockIdx.x;   // 0..2047
  int vid = (lin & 7) * 256 + (lin >> 3);                    // bijective
  int hh = vid >> 4;        // 0..127
  int b = hh >> 5, h = hh & 31;
  int rem = vid & 15;
  int i0 = (rem >> 2) * 128, k0 = (rem & 3) * 128;
  const short* A = aN4 + (long)b * 8388608 + (long)h * NNe;
  const short* B = bN4 + (long)b * 8388608 + (long)h * NNe;
  __shared__ __align__(16) short A1[128 * 40];
  __shared__ __align__(16) short B1[128 * 40];
  __shared__ __align__(16) short A2[128 * 40];
  __shared__ __align__(16) short B2[128 * 40];
  int tid = threadIdx.x;
  int wv = tid >> 6, lane = tid & 63;
  int wr = wv >> 2, wc = wv & 3;
  int lhi = lane >> 4, llo = lane & 15;
  int r1 = tid >> 2, cp = (tid & 3) * 8;
  int s2 = tid >> 5, cg = (tid & 31) * 4;
  f32x4 acc[4][2] = {};
  for (int j0 = 0; j0 < 512; j0 += 32) {
    *(bf8*)&A1[r1 * 40 + cp] = *(const bf8*)(A + (long)(i0 + r1) * 512 + j0 + cp);
    *(bf8*)&B1[r1 * 40 + cp] = *(const bf8*)(B + (long)(k0 + r1) * 512 + j0 + cp);
    bf4 va0 = *(const bf4*)(A + (long)(j0 + 2 * s2) * 512 + i0 + cg);
    bf4 va1 = *(const bf4*)(A + (long)(j0 + 2 * s2 + 1) * 512 + i0 + cg);
    bf4 vb0 = *(const bf4*)(B + (long)(j0 + 2 * s2) * 512 + k0 + cg);
    bf4 vb1 = *(const bf4*)(B + (long)(j0 + 2 * s2 + 1) * 512 + k0 + cg);
#pragma unroll
    for (int q = 0; q < 4; ++q) {
      unsigned pa = (unsigned)(unsigned short)va0[q] |
                    ((unsigned)(unsigned short)va1[q] << 16);
      unsigned pb = (unsigned)(unsigned short)vb0[q] |
                    ((unsigned)(unsigned short)vb1[q] << 16);
      *(unsigned*)&A2[(cg + q) * 40 + 2 * s2] = pa;
      *(unsigned*)&B2[(cg + q) * 40 + 2 * s2] = pb;
    }
    __syncthreads();
    bf8 bfr[2], dfr[2];
#pragma unroll
    for (int ni = 0; ni < 2; ++ni) {
      bfr[ni] = *(const bf8*)&B1[(wc * 32 + ni * 16 + llo) * 40 + lhi * 8];
      dfr[ni] = *(const bf8*)&B2[(wc * 32 + ni * 16 + llo) * 40 + lhi * 8];
    }
#pragma unroll
    for (int mi = 0; mi < 4; ++mi) {
      bf8 a = *(const bf8*)&A1[(wr * 64 + mi * 16 + llo) * 40 + lhi * 8];
      acc[mi][0] = MFMA(a, bfr[0], acc[mi][0]);
      acc[mi][1] = MFMA(a, bfr[1], acc[mi][1]);
    }
#pragma unroll
    for (int mi = 0; mi < 4; ++mi) {
      bf8 c = *(const bf8*)&A2[(wr * 64 + mi * 16 + llo) * 40 + lhi * 8];
      acc[mi][0] = MFMA(c, dfr[0], acc[mi][0]);
      acc[mi][1] = MFMA(c, dfr[1], acc[mi][1]);
    }
    __syncthreads();
  }
  short* tp = t4 + (long)b * 8388608 + (long)h * NNe;
#pragma unroll
  for (int mi = 0; mi < 4; ++mi)
#pragma unroll
    for (int ni = 0; ni < 2; ++ni) {
      int row = i0 + wr * 64 + mi * 16 + lhi * 4;
      int col = k0 + wc * 32 + ni * 16 + llo;
#pragma unroll
      for (int r = 0; r < 4; ++r) tp[(long)(row + r) * 512 + col] = f2bf(acc[mi][ni][r]);
    }
}

// --- fused OPM-recompute + triangle update + pair FFN (128 elems / 512 thr) ---
__global__ __launch_bounds__(512) void upd_pffn_fused(
    const float* __restrict__ pin, float* __restrict__ pout,
    const short* __restrict__ t4,
    const short* __restrict__ Tb, const short* __restrict__ bo_bf,
    const float* __restrict__ b_out, const float* __restrict__ op_norm,
    const float* __restrict__ g_tm, const float* __restrict__ b_tm,
    const short* __restrict__ wg_a, const float* __restrict__ b_g,
    const short* __restrict__ wz_a, const float* __restrict__ b_z,
    const float* __restrict__ g_tmo, const float* __restrict__ b_tmo,
    const float* __restrict__ g_pf, const float* __restrict__ b_pf,
    const short* __restrict__ w1_a, const float* __restrict__ b1,
    const short* __restrict__ w2_a, const float* __restrict__ b2) {
  __shared__ __align__(16) short Zb[2][64 * 72];
  __shared__ __align__(16) short Tlb[2][64 * 40];
  __shared__ __align__(16) short Wbuf[64 * 72];
  __shared__ __align__(16) short Wzb[64 * 36];
  __shared__ float spS[2][64][9];
  __shared__ float spQ[2][64][9];
  __shared__ float spB[2][4][2][72];
  int tid = threadIdx.x;
  int grp = tid >> 8;          // 0/1: element group
  int t = tid & 255;
  long e0 = (long)blockIdx.x * 128 + grp * 64;
  int bbt = (int)(e0 >> 18);
  long el = e0 & (NNe - 1);
  long growT = e0 >> 9;
  int jt = (int)((e0 >> 6) & 7);
  int wv = t >> 6, lane = t & 63;
  int wr = wv >> 1, wc = wv & 1;
  int lhi = lane >> 4, llo = lane & 15;
  int chb = wr * 32 + lhi * 4;
  int fc = lhi * 8;
  int fr0 = wr * 32 + llo, fr1 = fr0 + 16;
  int br0 = wc * 32 + llo, br1 = br0 + 16;
  int r0 = tid >> 3, c0 = (tid & 7) * 8;
  bf8 w1r, w2r;
  {
    *(bf8*)&Wbuf[r0 * 72 + c0] = *(const bf8*)(wg_a + r0 * 64 + c0);
    w1r = *(const bf8*)(w1_a + r0 * 64 + c0);
    w2r = *(const bf8*)(w2_a + r0 * 64 + c0);
    int rz = tid >> 3, cz = (tid & 7) * 4;
    *(bf4*)&Wzb[rz * 36 + cz] = *(const bf4*)(wz_a + rz * 32 + cz);
  }
  f32x4 x[2][2];
#pragma unroll
  for (int mi = 0; mi < 2; ++mi)
#pragma unroll
    for (int ni = 0; ni < 2; ++ni)
      x[mi][ni] = *(const f32x4*)(pin + (e0 + wc * 32 + ni * 16 + llo) * 64 +
                                  chb + mi * 16);
  {
    f32x4 acc[2][2] = {};
    bf8 a0 = *(const bf8*)(Tb + growT * 2048 + (long)fr0 * 32 + fc);
    bf8 a1 = *(const bf8*)(Tb + growT * 2048 + (long)fr1 * 32 + fc);
    bf8 b0 = *(const bf8*)(bo_bf + ((long)bbt * 512 + jt * 64 + br0) * 32 + fc);
    bf8 b1 = *(const bf8*)(bo_bf + ((long)bbt * 512 + jt * 64 + br1) * 32 + fc);
    acc[0][0] = MFMA(a0, b0, acc[0][0]);
    acc[0][1] = MFMA(a0, b1, acc[0][1]);
    acc[1][0] = MFMA(a1, b0, acc[1][0]);
    acc[1][1] = MFMA(a1, b1, acc[1][1]);
    float nrm = op_norm[0];
#pragma unroll
    for (int mi = 0; mi < 2; ++mi) {
      f32x4 bo4 = *(const f32x4*)(b_out + chb + mi * 16);
#pragma unroll
      for (int ni = 0; ni < 2; ++ni)
#pragma unroll
        for (int r = 0; r < 4; ++r)
          x[mi][ni][r] += (acc[mi][ni][r] + bo4[r]) * nrm;
    }
  }
#pragma unroll
  for (int ni = 0; ni < 2; ++ni) {
    float s = 0.f, ss = 0.f;
#pragma unroll
    for (int mi = 0; mi < 2; ++mi)
#pragma unroll
      for (int r = 0; r < 4; ++r) { float v = x[mi][ni][r]; s += v; ss += v * v; }
    int e = wc * 32 + ni * 16 + llo;
    spS[grp][e][wr * 4 + lhi] = s;
    spQ[grp][e][wr * 4 + lhi] = ss;
  }
  const short* t_in = t4 + (long)bbt * 8388608;
  int te = t & 63, tq = t >> 6;
  float tt[8];
  {
    float sB = 0.f, ssB = 0.f;
#pragma unroll
    for (int k = 0; k < 8; ++k) {
      float v = bf2f(t_in[(long)(tq * 8 + k) * NNe + el + te]);
      tt[k] = v; sB += v; ssB += v * v;
    }
    spB[grp][tq][0][te] = sB; spB[grp][tq][1][te] = ssB;
  }
  __syncthreads();   // (1)
  {
    float ts = spB[grp][0][0][te] + spB[grp][1][0][te] + spB[grp][2][0][te] +
               spB[grp][3][0][te];
    float tss = spB[grp][0][1][te] + spB[grp][1][1][te] + spB[grp][2][1][te] +
                spB[grp][3][1][te];
    float mu = ts * 0.03125f, var = tss * 0.03125f - mu * mu;
    float rs = rsqrtf(var + LNEPS);
    bf8 pk;
#pragma unroll
    for (int k = 0; k < 8; ++k) {
      int c = tq * 8 + k;
      pk[k] = f2bf((tt[k] - mu) * rs * g_tmo[c] + b_tmo[c]);
    }
    *(bf8*)&Tlb[grp][te * 40 + tq * 8] = pk;
  }
  float mu1[2], rs1[2];
#pragma unroll
  for (int ni = 0; ni < 2; ++ni) {
    int e = wc * 32 + ni * 16 + llo;
    float s = 0.f, q2 = 0.f;
#pragma unroll
    for (int k = 0; k < 8; ++k) { s += spS[grp][e][k]; q2 += spQ[grp][e][k]; }
    float mu = s * 0.015625f, var = q2 * 0.015625f - mu * mu;
    mu1[ni] = mu; rs1[ni] = rsqrtf(var + LNEPS);
  }
#pragma unroll
  for (int mi = 0; mi < 2; ++mi) {
    f32x4 gv = *(const f32x4*)(g_tm + chb + mi * 16);
    f32x4 bv = *(const f32x4*)(b_tm + chb + mi * 16);
#pragma unroll
    for (int ni = 0; ni < 2; ++ni) {
      int e = wc * 32 + ni * 16 + llo;
      bf4 pk;
#pragma unroll
      for (int r = 0; r < 4; ++r)
        pk[r] = f2bf((x[mi][ni][r] - mu1[ni]) * rs1[ni] * gv[r] + bv[r]);
      *(bf4*)&Zb[grp][e * 72 + chb + mi * 16] = pk;
    }
  }
  __syncthreads();   // (2)
  f32x4 accg[2][2] = {};
  f32x4 accz[2][2] = {};
#pragma unroll
  for (int ks = 0; ks < 2; ++ks) {
    bf8 a0 = *(const bf8*)&Wbuf[fr0 * 72 + ks * 32 + fc];
    bf8 a1 = *(const bf8*)&Wbuf[fr1 * 72 + ks * 32 + fc];
    bf8 z0 = *(const bf8*)&Zb[grp][br0 * 72 + ks * 32 + fc];
    bf8 z1 = *(const bf8*)&Zb[grp][br1 * 72 + ks * 32 + fc];
    accg[0][0] = MFMA(a0, z0, accg[0][0]);
    accg[0][1] = MFMA(a0, z1, accg[0][1]);
    accg[1][0] = MFMA(a1, z0, accg[1][0]);
    accg[1][1] = MFMA(a1, z1, accg[1][1]);
  }
  {
    bf8 a0 = *(const bf8*)&Wzb[fr0 * 36 + fc];
    bf8 a1 = *(const bf8*)&Wzb[fr1 * 36 + fc];
    bf8 t0 = *(const bf8*)&Tlb[grp][br0 * 40 + fc];
    bf8 t1 = *(const bf8*)&Tlb[grp][br1 * 40 + fc];
    accz[0][0] = MFMA(a0, t0, accz[0][0]);
    accz[0][1] = MFMA(a0, t1, accz[0][1]);
    accz[1][0] = MFMA(a1, t0, accz[1][0]);
    accz[1][1] = MFMA(a1, t1, accz[1][1]);
  }
#pragma unroll
  for (int mi = 0; mi < 2; ++mi) {
    f32x4 bgv = *(const f32x4*)(b_g + chb + mi * 16);
    f32x4 bzv = *(const f32x4*)(b_z + chb + mi * 16);
#pragma unroll
    for (int ni = 0; ni < 2; ++ni)
#pragma unroll
      for (int r = 0; r < 4; ++r)
        x[mi][ni][r] += (accg[mi][ni][r] + bgv[r]) * (accz[mi][ni][r] + bzv[r]);
  }
#pragma unroll
  for (int ni = 0; ni < 2; ++ni) {
    float s = 0.f, ss = 0.f;
#pragma unroll
    for (int mi = 0; mi < 2; ++mi)
#pragma unroll
      for (int r = 0; r < 4; ++r) { float v = x[mi][ni][r]; s += v; ss += v * v; }
    int e = wc * 32 + ni * 16 + llo;
    spS[grp][e][wr * 4 + lhi] = s;
    spQ[grp][e][wr * 4 + lhi] = ss;
  }
  __syncthreads();   // (3)
  *(bf8*)&Wbuf[r0 * 72 + c0] = w1r;
#pragma unroll
  for (int ni = 0; ni < 2; ++ni) {
    int e = wc * 32 + ni * 16 + llo;
    float s = 0.f, q2 = 0.f;
#pragma unroll
    for (int k = 0; k < 8; ++k) { s += spS[grp][e][k]; q2 += spQ[grp][e][k]; }
    float mu = s * 0.015625f, var = q2 * 0.015625f - mu * mu;
    mu1[ni] = mu; rs1[ni] = rsqrtf(var + LNEPS);
  }
#pragma unroll
  for (int mi = 0; mi < 2; ++mi) {
    f32x4 gv = *(const f32x4*)(g_pf + chb + mi * 16);
    f32x4 bv = *(const f32x4*)(b_pf + chb + mi * 16);
#pragma unroll
    for (int ni = 0; ni < 2; ++ni) {
      int e = wc * 32 + ni * 16 + llo;
      bf4 pk;
#pragma unroll
      for (int r = 0; r < 4; ++r)
        pk[r] = f2bf((x[mi][ni][r] - mu1[ni]) * rs1[ni] * gv[r] + bv[r]);
      *(bf4*)&Zb[grp][e * 72 + chb + mi * 16] = pk;
    }
  }
  __syncthreads();   // (4)
  f32x4 acc1[2][2] = {};
#pragma unroll
  for (int ks = 0; ks < 2; ++ks) {
    bf8 a0 = *(const bf8*)&Wbuf[fr0 * 72 + ks * 32 + fc];
    bf8 a1 = *(const bf8*)&Wbuf[fr1 * 72 + ks * 32 + fc];
    bf8 z0 = *(const bf8*)&Zb[grp][br0 * 72 + ks * 32 + fc];
    bf8 z1 = *(const bf8*)&Zb[grp][br1 * 72 + ks * 32 + fc];
    acc1[0][0] = MFMA(a0, z0, acc1[0][0]);
    acc1[0][1] = MFMA(a0, z1, acc1[0][1]);
    acc1[1][0] = MFMA(a1, z0, acc1[1][0]);
    acc1[1][1] = MFMA(a1, z1, acc1[1][1]);
  }
  __syncthreads();   // (5)
  *(bf8*)&Wbuf[r0 * 72 + c0] = w2r;
#pragma unroll
  for (int mi = 0; mi < 2; ++mi) {
    f32x4 bv = *(const f32x4*)(b1 + chb + mi * 16);
#pragma unroll
    for (int ni = 0; ni < 2; ++ni) {
      int e = wc * 32 + ni * 16 + llo;
      bf4 pk;
#pragma unroll
      for (int r = 0; r < 4; ++r) pk[r] = f2bf(gelu_fast(acc1[mi][ni][r] + bv[r]));
      *(bf4*)&Zb[grp][e * 72 + chb + mi * 16] = pk;
    }
  }
  __syncthreads();   // (6)
  f32x4 acc2[2][2] = {};
#pragma unroll
  for (int ks = 0; ks < 2; ++ks) {
    bf8 a0 = *(const bf8*)&Wbuf[fr0 * 72 + ks * 32 + fc];
    bf8 a1 = *(const bf8*)&Wbuf[fr1 * 72 + ks * 32 + fc];
    bf8 z0 = *(const bf8*)&Zb[grp][br0 * 72 + ks * 32 + fc];
    bf8 z1 = *(const bf8*)&Zb[grp][br1 * 72 + ks * 32 + fc];
    acc2[0][0] = MFMA(a0, z0, acc2[0][0]);
    acc2[0][1] = MFMA(a0, z1, acc2[0][1]);
    acc2[1][0] = MFMA(a1, z0, acc2[1][0]);
    acc2[1][1] = MFMA(a1, z1, acc2[1][1]);
  }
#pragma unroll
  for (int mi = 0; mi < 2; ++mi) {
    f32x4 bv = *(const f32x4*)(b2 + chb + mi * 16);
#pragma unroll
    for (int ni = 0; ni < 2; ++ni) {
#pragma unroll
      for (int r = 0; r < 4; ++r) x[mi][ni][r] += acc2[mi][ni][r] + bv[r];
      *(f32x4*)(pout + (e0 + wc * 32 + ni * 16 + llo) * 64 + chb + mi * 16) =
          x[mi][ni];
    }
  }
}

extern "C" void kernel_launch(void* const* d_in, const int* in_sizes, int n_in,
                              void* d_out, int out_size, void* d_ws, size_t ws_size,
                              hipStream_t stream) {
  const float* x = (const float*)d_in[0];
  const float* pair = (const float*)d_in[1];
  const float* attn_mask = (const float*)d_in[2];
  const float* op_mask = (const float*)d_in[3];
  const float* op_norm = (const float*)d_in[4];
  const float* wq = (const float*)d_in[6];
  const float* wk = (const float*)d_in[7];
  const float* wv_ = (const float*)d_in[8];
  const float* wg = (const float*)d_in[9];
  const float* bg = (const float*)d_in[10];
  const float* wo = (const float*)d_in[11];
  const float* bo = (const float*)d_in[12];
  const float* ln_pair_g = (const float*)d_in[13];
  const float* ln_pair_b = (const float*)d_in[14];
  const float* wb = (const float*)d_in[15];
  const float* bb = (const float*)d_in[16];
  const float* ln_attn_g = (const float*)d_in[17];
  const float* ln_attn_b = (const float*)d_in[18];
  const float* ln_ffn_g = (const float*)d_in[19];
  const float* ln_ffn_b = (const float*)d_in[20];
  const float* w_ffn1 = (const float*)d_in[21];
  const float* b_ffn1 = (const float*)d_in[22];
  const float* w_ffn2 = (const float*)d_in[23];
  const float* b_ffn2 = (const float*)d_in[24];
  const float* ln_opm_g = (const float*)d_in[25];
  const float* ln_opm_b = (const float*)d_in[26];
  const float* w_opm_in = (const float*)d_in[27];
  const float* b_opm_in = (const float*)d_in[28];
  const float* w_opm_out = (const float*)d_in[29];
  const float* b_opm_out = (const float*)d_in[30];
  const float* ln_tm_g = (const float*)d_in[31];
  const float* ln_tm_b = (const float*)d_in[32];
  const float* w_tm_abp = (const float*)d_in[33];
  const float* b_tm_abp = (const float*)d_in[34];
  const float* w_tm_abg = (const float*)d_in[35];
  const float* b_tm_abg = (const float*)d_in[36];
  const float* w_tm_g = (const float*)d_in[37];
  const float* b_tm_g = (const float*)d_in[38];
  const float* w_tm_z = (const float*)d_in[39];
  const float* b_tm_z = (const float*)d_in[40];
  const float* ln_tmo_g = (const float*)d_in[41];
  const float* ln_tmo_b = (const float*)d_in[42];
  const float* ln_pffn_g = (const float*)d_in[43];
  const float* ln_pffn_b = (const float*)d_in[44];
  const float* w_pffn1 = (const float*)d_in[45];
  const float* b_pffn1 = (const float*)d_in[46];
  const float* w_pffn2 = (const float*)d_in[47];
  const float* b_pffn2 = (const float*)d_in[48];

  float* ws = (float*)d_ws;
  short* wbf = (short*)ws;
  short* wq_bf = wbf + 0;            // contiguous [3072][768] qkvg block
  short* wo_bf = wbf + 2359296;
  short* wf1_bf = wbf + 2949120;
  short* wf2_bf = wbf + 5308416;
  short* wop_bf = wbf + 7667712;
  short* wb_a = wbf + 7716864;
  short* wabp_a = wbf + 7717376;
  short* wabg_a = wbf + 7721472;
  short* wtg_a = wbf + 7725568;
  short* wtz_a = wbf + 7729664;
  short* wp1_a = wbf + 7731712;
  short* wp2_a = wbf + 7735808;

  short* h_bf = (short*)(ws + 3869952);
  short* q_bf = (short*)(ws + 4656384);
  short* k_bf = (short*)(ws + 5442816);
  short* vT_bf = (short*)(ws + 6229248);
  float* gb = ws + 7015680;
  short* gb_bf = (short*)(ws + 10161408);
  float* x1b = ws + 10947840;
  short* biasb_bf = (short*)(ws + 12520704);   // 8388608 bf16
  short* attn_bf = (short*)(ws + 16715008);    // 8388608 bf16
  short* mffn_bf = (short*)(ws + 20909312);    // 6291456 bf16
  float* abb = ws + 24055040;                  // 131072 f32
  short* abb_bf = (short*)(ws + 24186112);     // 65536 bf16 (bo, all batches)
  short* Tb_bf = (short*)(ws + 24218880);      // 4194304 bf16 (all batches)
  short* aN4 = (short*)(ws + 59870464);        // 4 x 8388608 bf16
  short* bN4 = (short*)(ws + 76647680);
  short* t4 = (short*)(ws + 93424896);

  float* xo = (float*)d_out;
  float* pair1 = xo + 1572864;

  const float qscale = 0.1020620726159658f;  // 96^-0.5

  // --- weight casts ---
  castw_kernel<<<30144, 256, 0, stream>>>(wq, wk, wv_, wg, wo, w_ffn1, w_ffn2, w_opm_in,
                                          wbf, qscale);
  castw2_kernel<<<90, 256, 0, stream>>>(wb, w_tm_abp, w_tm_abg, w_tm_g, w_tm_z,
                                        w_pffn1, w_pffn2, wb_a);
  // --- attention ---
  ln_bf_kernel<<<2048, 256, 0, stream>>>(x, h_bf, ln_attn_g, ln_attn_b, 768);
  gemm_qkvg<<<dim3(24, 16, 1), 256, 0, stream>>>(h_bf, wq_bf, q_bf, k_bf, vT_bf, gb, bg);
  pair_bias_mfma<<<16384, 256, 0, stream>>>(pair, ln_pair_g, ln_pair_b, wb_a, bb, biasb_bf);
  attn_fused<<<dim3(32, 8, 4), 256, 0, stream>>>(q_bf, k_bf, biasb_bf, attn_mask, attn_bf);
  // AV with fused output gate
  gemm_bf<<<dim3(2, 8, 32), 256, 0, stream>>>(attn_bf, 512, 2097152, 262144,
                                              vT_bf, 512, 393216, 49152,
                                              nullptr, 0, 393216, 96, gb_bf, 768,
                                              gb, 768, 393216, 96, nullptr,
                                              512, 96, 512, 2, 0, 8);
  gemm128<<<dim3(6, 16, 1), 256, 0, stream>>>(gb_bf, wo_bf, 768, x, bo, x1b);
  // --- FFN ---
  ln_bf_kernel<<<2048, 256, 0, stream>>>(x1b, h_bf, ln_ffn_g, ln_ffn_b, 768);
  gemm_ffn1<<<dim3(24, 16, 1), 256, 0, stream>>>(h_bf, wf1_bf, mffn_bf, b_ffn1);
  gemm128<<<dim3(6, 16, 1), 256, 0, stream>>>(mffn_bf, wf2_bf, 3072, x1b, b_ffn2, xo);
  // --- outer product mean prep ---
  ln_bf_kernel<<<2048, 256, 0, stream>>>(xo, h_bf, ln_opm_g, ln_opm_b, 768);
  gemm_bf<<<dim3(1, 32, 1), 256, 0, stream>>>(h_bf, 768, 0, 0, wop_bf, 768, 0, 0,
                                              abb, 64, 0, 0, nullptr, 0,
                                              nullptr, 0, 0, 0, b_opm_in,
                                              2048, 64, 768, 0, 0, 1);
  opmask_kernel<<<512, 256, 0, stream>>>(abb, op_mask, abb_bf);
  opm_T_kernel<<<dim3(256, 64, 1), dim3(32, 8, 1), 0, stream>>>(abb, w_opm_out, Tb_bf);
  // --- pair stack (batched over all 4 batches) ---
  opm_ab_fused<<<dim3(4, 512, 4), 512, 0, stream>>>(
      pair, Tb_bf, abb_bf, b_opm_out, op_norm,
      ln_tm_g, ln_tm_b, wabp_a, b_tm_abp, wabg_a, b_tm_abg, aN4, bN4);
  tm_tri_mfma<<<dim3(4, 4, 128), 512, 0, stream>>>(aN4, bN4, t4);
  upd_pffn_fused<<<8192, 512, 0, stream>>>(
      pair, pair1, t4, Tb_bf, abb_bf, b_opm_out, op_norm,
      ln_tm_g, ln_tm_b, wtg_a, b_tm_g, wtz_a, b_tm_z,
      ln_tmo_g, ln_tmo_b, ln_pffn_g, ln_pffn_b, wp1_a, b_pffn1, wp2_a, b_pffn2);
}

// Round 16
// 867.036 us; speedup vs baseline: 1.0604x; 1.0004x over previous
//
#include <hip/hip_runtime.h>
#include <hip/hip_bf16.h>
#include <math.h>

#define Nn 512
#define Ee 768
#define Pp 64
#define PHh 32
#define Hh 8
#define Dd 96
#define NNe 262144      // N*N
#define LNEPS 1e-5f

typedef __attribute__((ext_vector_type(8))) short bf8;
typedef __attribute__((ext_vector_type(4))) short bf4;
typedef __attribute__((ext_vector_type(4))) float f32x4;
#define MFMA(a,b,c) __builtin_amdgcn_mfma_f32_16x16x32_bf16(a,b,c,0,0,0)

__device__ __forceinline__ short f2bf(float f) {
  __bf16 h = (__bf16)f;
  return __builtin_bit_cast(short, h);
}
__device__ __forceinline__ float bf2f(short s) {
  unsigned u = ((unsigned)(unsigned short)s) << 16;
  return __builtin_bit_cast(float, u);
}

__device__ __forceinline__ float wave_red_sum(float v) {
#pragma unroll
  for (int off = 32; off > 0; off >>= 1) v += __shfl_xor(v, off);
  return v;
}
__device__ __forceinline__ float gelu_exact(float v) {
  return 0.5f * v * (1.f + erff(v * 0.70710678118654752f));
}
__device__ __forceinline__ float sigmoidf_(float v) {
  return 1.f / (1.f + __expf(-v));
}
__device__ __forceinline__ float gelu_fast(float v) {
  return v / (1.f + __expf(-1.702f * v));
}

// ---------------- all weight casts to bf16 arena (merged) ----------------
__global__ __launch_bounds__(256) void castw_kernel(
    const float* __restrict__ wq, const float* __restrict__ wk,
    const float* __restrict__ wv, const float* __restrict__ wg,
    const float* __restrict__ wo, const float* __restrict__ f1,
    const float* __restrict__ f2, const float* __restrict__ wop,
    const float* __restrict__ wb, const float* __restrict__ abp,
    const float* __restrict__ abg, const float* __restrict__ wtg,
    const float* __restrict__ wtz, const float* __restrict__ p1,
    const float* __restrict__ p2,
    short* __restrict__ dst, float qs) {
  long i = (long)blockIdx.x * 256 + threadIdx.x;
  float v;
  if (i < 589824) v = wq[i] * qs;
  else if (i < 1179648) v = wk[i - 589824];
  else if (i < 1769472) v = wv[i - 1179648];
  else if (i < 2359296) v = wg[i - 1769472];
  else if (i < 2949120) v = wo[i - 2359296];
  else if (i < 5308416) v = f1[i - 2949120];
  else if (i < 7667712) v = f2[i - 5308416];
  else if (i < 7716864) v = wop[i - 7667712];
  else if (i < 7717376) v = wb[i - 7716864];
  else if (i < 7721472) v = abp[i - 7717376];
  else if (i < 7725568) v = abg[i - 7721472];
  else if (i < 7729664) v = wtg[i - 7725568];
  else if (i < 7731712) v = wtz[i - 7729664];
  else if (i < 7735808) v = p1[i - 7731712];
  else if (i < 7739904) v = p2[i - 7735808];
  else return;
  dst[i] = f2bf(v);
}

// ---------------- LayerNorm over last dim C -> bf16 out ----------------
__global__ __launch_bounds__(256) void ln_bf_kernel(const float* __restrict__ in,
                                                    short* __restrict__ out,
                                                    const float* __restrict__ gam,
                                                    const float* __restrict__ bet, int C) {
  int row = blockIdx.x;
  const float* xr = in + (long)row * C;
  short* yr = out + (long)row * C;
  float s = 0.f, ss = 0.f;
  for (int c = threadIdx.x; c < C; c += 256) { float v = xr[c]; s += v; ss += v * v; }
  s = wave_red_sum(s); ss = wave_red_sum(ss);
  __shared__ float sm[4][2];
  int wv = threadIdx.x >> 6, lane = threadIdx.x & 63;
  if (lane == 0) { sm[wv][0] = s; sm[wv][1] = ss; }
  __syncthreads();
  float ts = sm[0][0] + sm[1][0] + sm[2][0] + sm[3][0];
  float tss = sm[0][1] + sm[1][1] + sm[2][1] + sm[3][1];
  float mu = ts / C;
  float var = tss / C - mu * mu;
  float rs = rsqrtf(var + LNEPS);
  for (int c = threadIdx.x; c < C; c += 256) {
    float v = xr[c];
    yr[c] = f2bf((v - mu) * rs * gam[c] + bet[c]);
  }
}

// ---------------- bf16 MFMA NT GEMM, 64x64, BK=64 ----------------
__global__ __launch_bounds__(256) void gemm_bf(
    const short* __restrict__ A, int lda, long asB, long asH,
    const short* __restrict__ Bm, int ldb, long bsB, long bsH,
    float* __restrict__ outF, int ldf, long fsB, long fsH,
    short* __restrict__ outB, int ldob,
    const float* __restrict__ resid, int ldr, long rsB, long rsH,
    const float* __restrict__ bias,
    int M, int N, int K, int act, int vtrans, int Hdim) {
  int bz = blockIdx.z, bb = bz / Hdim, hh = bz % Hdim;
  A += bb * asB + hh * asH;
  Bm += bb * bsB + hh * bsH;
  if (outF) outF += bb * fsB + hh * fsH;
  if (outB) outB += bb * fsB + hh * fsH;
  if (resid) resid += bb * rsB + hh * rsH;
  __shared__ __align__(16) short As[64 * 72];
  __shared__ __align__(16) short Bs[64 * 72];
  int m0 = blockIdx.y * 64, n0 = blockIdx.x * 64;
  int tid = threadIdx.x;
  int wv = tid >> 6, lane = tid & 63;
  int wr = wv >> 1, wc = wv & 1;
  int lhi = lane >> 4, llo = lane & 15;
  int r4 = tid >> 2, c8 = (tid & 3) * 8;
  f32x4 acc[2][2] = {};
  for (int k0 = 0; k0 < K; k0 += 64) {
    *(bf8*)&As[r4 * 72 + c8] = *(const bf8*)(A + (long)(m0 + r4) * lda + k0 + c8);
    *(bf8*)&As[r4 * 72 + 32 + c8] =
        *(const bf8*)(A + (long)(m0 + r4) * lda + k0 + 32 + c8);
    bf8 bv0 = {}, bv1 = {};
    if (n0 + r4 < N) {
      bv0 = *(const bf8*)(Bm + (long)(n0 + r4) * ldb + k0 + c8);
      bv1 = *(const bf8*)(Bm + (long)(n0 + r4) * ldb + k0 + 32 + c8);
    }
    *(bf8*)&Bs[r4 * 72 + c8] = bv0;
    *(bf8*)&Bs[r4 * 72 + 32 + c8] = bv1;
    __syncthreads();
#pragma unroll
    for (int ks = 0; ks < 2; ++ks) {
      bf8 a0 = *(const bf8*)&As[(wr * 32 + llo) * 72 + ks * 32 + lhi * 8];
      bf8 a1 = *(const bf8*)&As[(wr * 32 + 16 + llo) * 72 + ks * 32 + lhi * 8];
      bf8 b0 = *(const bf8*)&Bs[(wc * 32 + llo) * 72 + ks * 32 + lhi * 8];
      bf8 b1 = *(const bf8*)&Bs[(wc * 32 + 16 + llo) * 72 + ks * 32 + lhi * 8];
      acc[0][0] = MFMA(a0, b0, acc[0][0]);
      acc[0][1] = MFMA(a0, b1, acc[0][1]);
      acc[1][0] = MFMA(a1, b0, acc[1][0]);
      acc[1][1] = MFMA(a1, b1, acc[1][1]);
    }
    __syncthreads();
  }
#pragma unroll
  for (int mi = 0; mi < 2; ++mi) {
    int gmb = m0 + wr * 32 + mi * 16 + lhi * 4;
#pragma unroll
    for (int ni = 0; ni < 2; ++ni) {
      int gn = n0 + wc * 32 + ni * 16 + llo;
      if (gn >= N) continue;
      float bv = bias ? bias[gn] : 0.f;
      float vr[4];
#pragma unroll
      for (int r = 0; r < 4; ++r) {
        float v = acc[mi][ni][r] + bv;
        if (resid) {
          float rv = resid[(long)(gmb + r) * ldr + gn];
          if (act == 2) v = sigmoidf_(rv) * acc[mi][ni][r];
          else v += rv;
        }
        if (act == 1) v = gelu_exact(v);
        vr[r] = v;
      }
      if (outF) {
#pragma unroll
        for (int r = 0; r < 4; ++r) outF[(long)(gmb + r) * ldf + gn] = vr[r];
      }
      if (outB) {
        if (vtrans) {
          bf4 pk;
#pragma unroll
          for (int r = 0; r < 4; ++r) pk[r] = f2bf(vr[r]);
          *(bf4*)(outB + ((long)((gmb >> 9) * 768 + gn) * 512 + (gmb & 511))) = pk;
        } else {
#pragma unroll
          for (int r = 0; r < 4; ++r) outB[(long)(gmb + r) * ldob + gn] = f2bf(vr[r]);
        }
      }
    }
  }
}

// ---------------- 128x128 tile: QKVG projection ----------------
__global__ __launch_bounds__(256) void gemm_qkvg(
    const short* __restrict__ A, const short* __restrict__ W,
    short* __restrict__ q_bf, short* __restrict__ k_bf,
    short* __restrict__ vT_bf, float* __restrict__ gb,
    const float* __restrict__ bg) {
  __shared__ __align__(16) short As[128 * 40];
  __shared__ __align__(16) short Bs[128 * 40];
  int m0 = blockIdx.y * 128, n0 = blockIdx.x * 128;
  int sec = n0 / 768;
  int cbase = n0 - sec * 768;
  int tid = threadIdx.x;
  int wv = tid >> 6, lane = tid & 63;
  int wr = wv >> 1, wc = wv & 1;
  int lhi = lane >> 4, llo = lane & 15;
  int r4 = tid >> 2, c8 = (tid & 3) * 8;
  f32x4 acc[4][4] = {};
  for (int k0 = 0; k0 < 768; k0 += 32) {
    *(bf8*)&As[r4 * 40 + c8] = *(const bf8*)(A + (long)(m0 + r4) * 768 + k0 + c8);
    *(bf8*)&As[(r4 + 64) * 40 + c8] =
        *(const bf8*)(A + (long)(m0 + r4 + 64) * 768 + k0 + c8);
    *(bf8*)&Bs[r4 * 40 + c8] = *(const bf8*)(W + (long)(n0 + r4) * 768 + k0 + c8);
    *(bf8*)&Bs[(r4 + 64) * 40 + c8] =
        *(const bf8*)(W + (long)(n0 + r4 + 64) * 768 + k0 + c8);
    __syncthreads();
    bf8 af[4], bfm[4];
#pragma unroll
    for (int mi = 0; mi < 4; ++mi)
      af[mi] = *(const bf8*)&As[(wr * 64 + mi * 16 + llo) * 40 + lhi * 8];
#pragma unroll
    for (int ni = 0; ni < 4; ++ni)
      bfm[ni] = *(const bf8*)&Bs[(wc * 64 + ni * 16 + llo) * 40 + lhi * 8];
#pragma unroll
    for (int mi = 0; mi < 4; ++mi)
#pragma unroll
      for (int ni = 0; ni < 4; ++ni)
        acc[mi][ni] = MFMA(af[mi], bfm[ni], acc[mi][ni]);
    __syncthreads();
  }
#pragma unroll
  for (int mi = 0; mi < 4; ++mi) {
    int gmb = m0 + wr * 64 + mi * 16 + lhi * 4;
#pragma unroll
    for (int ni = 0; ni < 4; ++ni) {
      int cn = cbase + wc * 64 + ni * 16 + llo;
      if (sec == 0) {
#pragma unroll
        for (int r = 0; r < 4; ++r) q_bf[(long)(gmb + r) * 768 + cn] = f2bf(acc[mi][ni][r]);
      } else if (sec == 1) {
#pragma unroll
        for (int r = 0; r < 4; ++r) k_bf[(long)(gmb + r) * 768 + cn] = f2bf(acc[mi][ni][r]);
      } else if (sec == 2) {
        bf4 pk;
#pragma unroll
        for (int r = 0; r < 4; ++r) pk[r] = f2bf(acc[mi][ni][r]);
        *(bf4*)(vT_bf + ((long)((gmb >> 9) * 768 + cn) * 512 + (gmb & 511))) = pk;
      } else {
        float bv = bg[cn];
#pragma unroll
        for (int r = 0; r < 4; ++r) gb[(long)(gmb + r) * 768 + cn] = acc[mi][ni][r] + bv;
      }
    }
  }
}

// ---------------- 128x128 tile: FFN1 (gelu exact, bf16 out) ----------------
__global__ __launch_bounds__(256) void gemm_ffn1(
    const short* __restrict__ A, const short* __restrict__ W,
    short* __restrict__ outB, const float* __restrict__ bias) {
  __shared__ __align__(16) short As[128 * 40];
  __shared__ __align__(16) short Bs[128 * 40];
  int m0 = blockIdx.y * 128, n0 = blockIdx.x * 128;
  int tid = threadIdx.x;
  int wv = tid >> 6, lane = tid & 63;
  int wr = wv >> 1, wc = wv & 1;
  int lhi = lane >> 4, llo = lane & 15;
  int r4 = tid >> 2, c8 = (tid & 3) * 8;
  f32x4 acc[4][4] = {};
  for (int k0 = 0; k0 < 768; k0 += 32) {
    *(bf8*)&As[r4 * 40 + c8] = *(const bf8*)(A + (long)(m0 + r4) * 768 + k0 + c8);
    *(bf8*)&As[(r4 + 64) * 40 + c8] =
        *(const bf8*)(A + (long)(m0 + r4 + 64) * 768 + k0 + c8);
    *(bf8*)&Bs[r4 * 40 + c8] = *(const bf8*)(W + (long)(n0 + r4) * 768 + k0 + c8);
    *(bf8*)&Bs[(r4 + 64) * 40 + c8] =
        *(const bf8*)(W + (long)(n0 + r4 + 64) * 768 + k0 + c8);
    __syncthreads();
    bf8 af[4], bfm[4];
#pragma unroll
    for (int mi = 0; mi < 4; ++mi)
      af[mi] = *(const bf8*)&As[(wr * 64 + mi * 16 + llo) * 40 + lhi * 8];
#pragma unroll
    for (int ni = 0; ni < 4; ++ni)
      bfm[ni] = *(const bf8*)&Bs[(wc * 64 + ni * 16 + llo) * 40 + lhi * 8];
#pragma unroll
    for (int mi = 0; mi < 4; ++mi)
#pragma unroll
      for (int ni = 0; ni < 4; ++ni)
        acc[mi][ni] = MFMA(af[mi], bfm[ni], acc[mi][ni]);
    __syncthreads();
  }
#pragma unroll
  for (int mi = 0; mi < 4; ++mi) {
    int gmb = m0 + wr * 64 + mi * 16 + lhi * 4;
#pragma unroll
    for (int ni = 0; ni < 4; ++ni) {
      int gn = n0 + wc * 64 + ni * 16 + llo;
      float bv = bias[gn];
#pragma unroll
      for (int r = 0; r < 4; ++r)
        outB[(long)(gmb + r) * 3072 + gn] = f2bf(gelu_exact(acc[mi][ni][r] + bv));
    }
  }
}

// ---------------- 128x128 tile: generic NT fp32 out + resid + bias (wo, ffn2) ----------
__global__ __launch_bounds__(256) void gemm128(
    const short* __restrict__ A, const short* __restrict__ W, int K,
    const float* __restrict__ resid, const float* __restrict__ bias,
    float* __restrict__ outF) {
  __shared__ __align__(16) short As[128 * 40];
  __shared__ __align__(16) short Bs[128 * 40];
  int m0 = blockIdx.y * 128, n0 = blockIdx.x * 128;
  int tid = threadIdx.x;
  int wv = tid >> 6, lane = tid & 63;
  int wr = wv >> 1, wc = wv & 1;
  int lhi = lane >> 4, llo = lane & 15;
  int r4 = tid >> 2, c8 = (tid & 3) * 8;
  f32x4 acc[4][4] = {};
  for (int k0 = 0; k0 < K; k0 += 32) {
    *(bf8*)&As[r4 * 40 + c8] = *(const bf8*)(A + (long)(m0 + r4) * K + k0 + c8);
    *(bf8*)&As[(r4 + 64) * 40 + c8] =
        *(const bf8*)(A + (long)(m0 + r4 + 64) * K + k0 + c8);
    *(bf8*)&Bs[r4 * 40 + c8] = *(const bf8*)(W + (long)(n0 + r4) * K + k0 + c8);
    *(bf8*)&Bs[(r4 + 64) * 40 + c8] =
        *(const bf8*)(W + (long)(n0 + r4 + 64) * K + k0 + c8);
    __syncthreads();
    bf8 af[4], bfm[4];
#pragma unroll
    for (int mi = 0; mi < 4; ++mi)
      af[mi] = *(const bf8*)&As[(wr * 64 + mi * 16 + llo) * 40 + lhi * 8];
#pragma unroll
    for (int ni = 0; ni < 4; ++ni)
      bfm[ni] = *(const bf8*)&Bs[(wc * 64 + ni * 16 + llo) * 40 + lhi * 8];
#pragma unroll
    for (int mi = 0; mi < 4; ++mi)
#pragma unroll
      for (int ni = 0; ni < 4; ++ni)
        acc[mi][ni] = MFMA(af[mi], bfm[ni], acc[mi][ni]);
    __syncthreads();
  }
#pragma unroll
  for (int mi = 0; mi < 4; ++mi) {
    int gmb = m0 + wr * 64 + mi * 16 + lhi * 4;
#pragma unroll
    for (int ni = 0; ni < 4; ++ni) {
      int gn = n0 + wc * 64 + ni * 16 + llo;
      float bv = bias[gn];
#pragma unroll
      for (int r = 0; r < 4; ++r)
        outF[(long)(gmb + r) * 768 + gn] =
            acc[mi][ni][r] + bv + resid[(long)(gmb + r) * 768 + gn];
    }
  }
}

// ---------------- fused scores + softmax (flash-row, 16 rows/block) ----------------
__global__ __launch_bounds__(256) void attn_fused(
    const short* __restrict__ q_bf, const short* __restrict__ k_bf,
    const short* __restrict__ bias_bf, const float* __restrict__ mask,
    short* __restrict__ out_bf) {
  int it = blockIdx.x, h = blockIdx.y, b = blockIdx.z;
  int tid = threadIdx.x;
  int wv = tid >> 6, lane = tid & 63;
  int lhi = lane >> 4, llo = lane & 15;
  int i0 = it * 16;
  long qoff = ((long)(b * 512 + i0)) * 768 + h * 96;
  bf8 qf[3];
#pragma unroll
  for (int ks = 0; ks < 3; ++ks)
    qf[ks] = *(const bf8*)(q_bf + qoff + (long)llo * 768 + ks * 32 + lhi * 8);
  long koff = ((long)b * 512) * 768 + h * 96;
  long bioff = (long)(b * 8 + h) * NNe + (long)i0 * 512;
  long moff = (long)b * NNe + (long)i0 * 512;
  float sv[8][4];
  int jb0 = wv * 128;
#pragma unroll
  for (int jf = 0; jf < 8; ++jf) {
    int jb = jb0 + jf * 16;
    f32x4 acc = {0.f, 0.f, 0.f, 0.f};
#pragma unroll
    for (int ks = 0; ks < 3; ++ks) {
      bf8 kf = *(const bf8*)(k_bf + koff + (long)(jb + llo) * 768 + ks * 32 + lhi * 8);
      acc = MFMA(qf[ks], kf, acc);
    }
#pragma unroll
    for (int r = 0; r < 4; ++r) {
      int irow = lhi * 4 + r;
      int j = jb + llo;
      float bia = bf2f(bias_bf[bioff + (long)irow * 512 + j]);
      float mk = mask[moff + (long)irow * 512 + j];
      sv[jf][r] = acc[r] + bia + mk;
    }
  }
  __shared__ float redA[4][20];
  __shared__ float redB[4][20];
  float rmax[4];
#pragma unroll
  for (int r = 0; r < 4; ++r) {
    float m = sv[0][r];
#pragma unroll
    for (int jf = 1; jf < 8; ++jf) m = fmaxf(m, sv[jf][r]);
#pragma unroll
    for (int off = 1; off < 16; off <<= 1) m = fmaxf(m, __shfl_xor(m, off, 16));
    if (llo == 0) redA[wv][lhi * 4 + r] = m;
  }
  __syncthreads();
#pragma unroll
  for (int r = 0; r < 4; ++r) {
    int row = lhi * 4 + r;
    rmax[r] = fmaxf(fmaxf(redA[0][row], redA[1][row]),
                    fmaxf(redA[2][row], redA[3][row]));
  }
  float rsum[4] = {0.f, 0.f, 0.f, 0.f};
#pragma unroll
  for (int jf = 0; jf < 8; ++jf)
#pragma unroll
    for (int r = 0; r < 4; ++r) {
      float e = __expf(sv[jf][r] - rmax[r]);
      sv[jf][r] = e;
      rsum[r] += e;
    }
#pragma unroll
  for (int r = 0; r < 4; ++r) {
#pragma unroll
    for (int off = 1; off < 16; off <<= 1) rsum[r] += __shfl_xor(rsum[r], off, 16);
    if (llo == 0) redB[wv][lhi * 4 + r] = rsum[r];
  }
  __syncthreads();
#pragma unroll
  for (int r = 0; r < 4; ++r) {
    int row = lhi * 4 + r;
    float s = redB[0][row] + redB[1][row] + redB[2][row] + redB[3][row];
    float inv = 1.f / s;
#pragma unroll
    for (int jf = 0; jf < 8; ++jf) {
      int j = jb0 + jf * 16 + llo;
      out_bf[bioff + (long)row * 512 + j] = f2bf(sv[jf][r] * inv);
    }
  }
}

// ---------------- ab *= op_mask ; emit b-half bf16 ----------------
__global__ __launch_bounds__(256) void opmask_kernel(float* __restrict__ ab,
                                                     const float* __restrict__ mask,
                                                     short* __restrict__ bo_bf) {
  int idx = blockIdx.x * 256 + threadIdx.x;
  if (idx < 131072) {
    float v = ab[idx] * mask[idx >> 6];
    ab[idx] = v;
    int ch = idx & 63;
    if (ch >= 32) bo_bf[(idx >> 6) * 32 + ch - 32] = f2bf(v);
  }
}

// ---------------- T[row,p,e] (bf16) ----------------
__global__ __launch_bounds__(256) void opm_T_kernel(const float* __restrict__ ab,
                                                    const float* __restrict__ w,
                                                    short* __restrict__ T) {
  int p = blockIdx.y;
  int row = blockIdx.x * 8 + threadIdx.y;
  int e = threadIdx.x;
  const float* a = ab + (long)row * 64;
  const float* wp = w + p * 1024 + e;
  float acc = 0.f;
#pragma unroll
  for (int d = 0; d < 32; ++d) acc += a[d] * wp[d * 32];
  T[((long)row * 64 + p) * 32 + e] = f2bf(acc);
}

// ---------------- pair bias (128 elems / 512 thr): register LN ----------------
__global__ __launch_bounds__(512) void pair_bias_mfma(
    const float* __restrict__ pair, const float* __restrict__ gam,
    const float* __restrict__ bet, const short* __restrict__ wb_a,
    const float* __restrict__ bbv, short* __restrict__ bias) {
  __shared__ __align__(16) short Zb[2][64 * 72];
  __shared__ __align__(16) short Wb[16 * 72];
  __shared__ float sp[2][4][2][72];
  int tid = threadIdx.x;
  int grp = tid >> 8, t = tid & 255;
  long e0 = (long)blockIdx.x * 128 + grp * 64;
  int b = (int)(e0 >> 18);
  long ein = e0 & (NNe - 1);
  const float* base = pair + e0 * 64;
  for (int l = tid; l < 1024; l += 512) {
    int h = l >> 6, c = l & 63;
    Wb[h * 72 + c] = (h < 8) ? wb_a[h * 64 + c] : (short)0;
  }
  int e = t & 63, q = t >> 6;
  f32x4 v4[4];
  float s = 0.f, ss = 0.f;
#pragma unroll
  for (int k = 0; k < 4; ++k) {
    v4[k] = *(const f32x4*)(base + (long)e * 64 + q * 16 + k * 4);
#pragma unroll
    for (int u = 0; u < 4; ++u) { float v = v4[k][u]; s += v; ss += v * v; }
  }
  sp[grp][q][0][e] = s; sp[grp][q][1][e] = ss;
  __syncthreads();
  float ts = sp[grp][0][0][e] + sp[grp][1][0][e] + sp[grp][2][0][e] + sp[grp][3][0][e];
  float tss = sp[grp][0][1][e] + sp[grp][1][1][e] + sp[grp][2][1][e] + sp[grp][3][1][e];
  float mu = ts * 0.015625f, var = tss * 0.015625f - mu * mu;
  float rs = rsqrtf(var + LNEPS);
#pragma unroll
  for (int k = 0; k < 4; ++k) {
    bf4 pk;
#pragma unroll
    for (int u = 0; u < 4; ++u) {
      int c = q * 16 + k * 4 + u;
      pk[u] = f2bf((v4[k][u] - mu) * rs * gam[c] + bet[c]);
    }
    *(bf4*)&Zb[grp][e * 72 + q * 16 + k * 4] = pk;
  }
  __syncthreads();
  int wv = t >> 6, lane = t & 63;
  int lhi = lane >> 4, llo = lane & 15;
  int n0 = wv * 16;
  f32x4 acc = {0.f, 0.f, 0.f, 0.f};
#pragma unroll
  for (int ks = 0; ks < 2; ++ks) {
    bf8 a = *(const bf8*)&Wb[llo * 72 + ks * 32 + lhi * 8];
    bf8 bz = *(const bf8*)&Zb[grp][(n0 + llo) * 72 + ks * 32 + lhi * 8];
    acc = MFMA(a, bz, acc);
  }
  int elem = n0 + llo;
#pragma unroll
  for (int r = 0; r < 4; ++r) {
    int h = lhi * 4 + r;
    if (h < 8) bias[(long)(b * 8 + h) * NNe + ein + elem] = f2bf(acc[r] + bbv[h]);
  }
}

// -------- opm + triangle ab (128 elems / 512 thr, batched z=4) --------
__global__ __launch_bounds__(512) void opm_ab_fused(
    const float* __restrict__ pair_in, const short* __restrict__ Tb,
    const short* __restrict__ bo_bf, const float* __restrict__ b_out,
    const float* __restrict__ op_norm, const float* __restrict__ gam,
    const float* __restrict__ bet, const short* __restrict__ wp_a,
    const float* __restrict__ b_abp, const short* __restrict__ wg_a,
    const float* __restrict__ b_abg,
    short* __restrict__ aN4, short* __restrict__ bN4) {
  int jp = blockIdx.x;   // 0..3 (jt pair)
  int i = blockIdx.y;    // 0..511
  int bb = blockIdx.z;   // 0..3
  int tid = threadIdx.x;
  __shared__ __align__(16) short Zb[2][64 * 72];
  __shared__ __align__(16) short Wp[64 * 72];
  __shared__ __align__(16) short Wg[64 * 72];
  __shared__ float spS[2][64][9];
  __shared__ float spQ[2][64][9];
  int grp = tid >> 8;
  int t = tid & 255;
  int jt = jp * 2 + grp;
  int wv = t >> 6, lane = t & 63;
  int wr = wv >> 1, wc = wv & 1;
  int lhi = lane >> 4, llo = lane & 15;
  int chb = wr * 32 + lhi * 4;
  int fc = lhi * 8;
  {
    int r = tid >> 3, c8 = (tid & 7) * 8;
    *(bf8*)&Wp[r * 72 + c8] = *(const bf8*)(wp_a + r * 64 + c8);
    *(bf8*)&Wg[r * 72 + c8] = *(const bf8*)(wg_a + r * 64 + c8);
  }
  long grow = (long)bb * 512 + i;
  long ebase = (long)i * 512 + jt * 64;
  const float* pbase = pair_in + ((long)bb * NNe + ebase) * 64;
  short* aN = aN4 + (long)bb * 8388608;
  short* bN = bN4 + (long)bb * 8388608;
  f32x4 x[2][2];
#pragma unroll
  for (int mi = 0; mi < 2; ++mi)
#pragma unroll
    for (int ni = 0; ni < 2; ++ni)
      x[mi][ni] = *(const f32x4*)(pbase + (long)(wc * 32 + ni * 16 + llo) * 64 +
                                  chb + mi * 16);
  {
    f32x4 acc[2][2] = {};
    bf8 a0 = *(const bf8*)(Tb + grow * 2048 + (long)(wr * 32 + llo) * 32 + fc);
    bf8 a1 = *(const bf8*)(Tb + grow * 2048 + (long)(wr * 32 + 16 + llo) * 32 + fc);
    bf8 b0 = *(const bf8*)(bo_bf + ((long)bb * 512 + jt * 64 + wc * 32 + llo) * 32 + fc);
    bf8 b1 = *(const bf8*)(bo_bf +
                           ((long)bb * 512 + jt * 64 + wc * 32 + 16 + llo) * 32 + fc);
    acc[0][0] = MFMA(a0, b0, acc[0][0]);
    acc[0][1] = MFMA(a0, b1, acc[0][1]);
    acc[1][0] = MFMA(a1, b0, acc[1][0]);
    acc[1][1] = MFMA(a1, b1, acc[1][1]);
    float nrm = op_norm[0];
#pragma unroll
    for (int mi = 0; mi < 2; ++mi) {
      f32x4 bo4 = *(const f32x4*)(b_out + chb + mi * 16);
#pragma unroll
      for (int ni = 0; ni < 2; ++ni)
#pragma unroll
        for (int r = 0; r < 4; ++r)
          x[mi][ni][r] += (acc[mi][ni][r] + bo4[r]) * nrm;
    }
  }
#pragma unroll
  for (int ni = 0; ni < 2; ++ni) {
    float s = 0.f, ss = 0.f;
#pragma unroll
    for (int mi = 0; mi < 2; ++mi)
#pragma unroll
      for (int r = 0; r < 4; ++r) { float v = x[mi][ni][r]; s += v; ss += v * v; }
    int e = wc * 32 + ni * 16 + llo;
    spS[grp][e][wr * 4 + lhi] = s;
    spQ[grp][e][wr * 4 + lhi] = ss;
  }
  __syncthreads();   // (1)
  float mu1[2], rs1[2];
#pragma unroll
  for (int ni = 0; ni < 2; ++ni) {
    int e = wc * 32 + ni * 16 + llo;
    float s = 0.f, q2 = 0.f;
#pragma unroll
    for (int k = 0; k < 8; ++k) { s += spS[grp][e][k]; q2 += spQ[grp][e][k]; }
    float mu = s * 0.015625f, var = q2 * 0.015625f - mu * mu;
    mu1[ni] = mu; rs1[ni] = rsqrtf(var + LNEPS);
  }
#pragma unroll
  for (int mi = 0; mi < 2; ++mi) {
    f32x4 gv = *(const f32x4*)(gam + chb + mi * 16);
    f32x4 bv = *(const f32x4*)(bet + chb + mi * 16);
#pragma unroll
    for (int ni = 0; ni < 2; ++ni) {
      int e = wc * 32 + ni * 16 + llo;
      bf4 pk;
#pragma unroll
      for (int r = 0; r < 4; ++r)
        pk[r] = f2bf((x[mi][ni][r] - mu1[ni]) * rs1[ni] * gv[r] + bv[r]);
      *(bf4*)&Zb[grp][e * 72 + chb + mi * 16] = pk;
    }
  }
  __syncthreads();   // (2)
  f32x4 ap[2][2] = {};
  f32x4 ag[2][2] = {};
#pragma unroll
  for (int ks = 0; ks < 2; ++ks) {
    bf8 z0 = *(const bf8*)&Zb[grp][(wr * 32 + llo) * 72 + ks * 32 + fc];
    bf8 z1 = *(const bf8*)&Zb[grp][(wr * 32 + 16 + llo) * 72 + ks * 32 + fc];
    bf8 p0 = *(const bf8*)&Wp[(wc * 32 + llo) * 72 + ks * 32 + fc];
    bf8 p1 = *(const bf8*)&Wp[(wc * 32 + 16 + llo) * 72 + ks * 32 + fc];
    bf8 g0 = *(const bf8*)&Wg[(wc * 32 + llo) * 72 + ks * 32 + fc];
    bf8 g1 = *(const bf8*)&Wg[(wc * 32 + 16 + llo) * 72 + ks * 32 + fc];
    ap[0][0] = MFMA(z0, p0, ap[0][0]);
    ap[0][1] = MFMA(z0, p1, ap[0][1]);
    ap[1][0] = MFMA(z1, p0, ap[1][0]);
    ap[1][1] = MFMA(z1, p1, ap[1][1]);
    ag[0][0] = MFMA(z0, g0, ag[0][0]);
    ag[0][1] = MFMA(z0, g1, ag[0][1]);
    ag[1][0] = MFMA(z1, g0, ag[1][0]);
    ag[1][1] = MFMA(z1, g1, ag[1][1]);
  }
#pragma unroll
  for (int mi = 0; mi < 2; ++mi) {
    int elemb = wr * 32 + mi * 16 + lhi * 4;
#pragma unroll
    for (int ni = 0; ni < 2; ++ni) {
      int ch = wc * 32 + ni * 16 + llo;
      float bp = b_abp[ch], bg = b_abg[ch];
      bf4 pack;
#pragma unroll
      for (int r = 0; r < 4; ++r)
        pack[r] = f2bf((ap[mi][ni][r] + bp) * sigmoidf_(ag[mi][ni][r] + bg));
      short* dst = (ch < 32) ? (aN + (long)ch * NNe) : (bN + (long)(ch - 32) * NNe);
      *(bf4*)(dst + ebase + elemb) = pack;
    }
  }
}

// ---------------- triangle einsum -> t bf16 (128x128 tile, batched, XCD swizzle) --------
__global__ __launch_bounds__(512) void tm_tri_mfma(const short* __restrict__ aN4,
                                                   const short* __restrict__ bN4,
                                                   short* __restrict__ t4) {
  int lin = blockIdx.z * 16 + blockIdx.y * 4 + blockIdx.x;   // 0..2047
  int vid = (lin & 7) * 256 + (lin >> 3);                    // bijective
  int hh = vid >> 4;        // 0..127
  int b = hh >> 5, h = hh & 31;
  int rem = vid & 15;
  int i0 = (rem >> 2) * 128, k0 = (rem & 3) * 128;
  const short* A = aN4 + (long)b * 8388608 + (long)h * NNe;
  const short* B = bN4 + (long)b * 8388608 + (long)h * NNe;
  __shared__ __align__(16) short A1[128 * 40];
  __shared__ __align__(16) short B1[128 * 40];
  __shared__ __align__(16) short A2[128 * 40];
  __shared__ __align__(16) short B2[128 * 40];
  int tid = threadIdx.x;
  int wv = tid >> 6, lane = tid & 63;
  int wr = wv >> 2, wc = wv & 3;
  int lhi = lane >> 4, llo = lane & 15;
  int r1 = tid >> 2, cp = (tid & 3) * 8;
  int s2 = tid >> 5, cg = (tid & 31) * 4;
  f32x4 acc[4][2] = {};
  for (int j0 = 0; j0 < 512; j0 += 32) {
    *(bf8*)&A1[r1 * 40 + cp] = *(const bf8*)(A + (long)(i0 + r1) * 512 + j0 + cp);
    *(bf8*)&B1[r1 * 40 + cp] = *(const bf8*)(B + (long)(k0 + r1) * 512 + j0 + cp);
    bf4 va0 = *(const bf4*)(A + (long)(j0 + 2 * s2) * 512 + i0 + cg);
    bf4 va1 = *(const bf4*)(A + (long)(j0 + 2 * s2 + 1) * 512 + i0 + cg);
    bf4 vb0 = *(const bf4*)(B + (long)(j0 + 2 * s2) * 512 + k0 + cg);
    bf4 vb1 = *(const bf4*)(B + (long)(j0 + 2 * s2 + 1) * 512 + k0 + cg);
#pragma unroll
    for (int q = 0; q < 4; ++q) {
      unsigned pa = (unsigned)(unsigned short)va0[q] |
                    ((unsigned)(unsigned short)va1[q] << 16);
      unsigned pb = (unsigned)(unsigned short)vb0[q] |
                    ((unsigned)(unsigned short)vb1[q] << 16);
      *(unsigned*)&A2[(cg + q) * 40 + 2 * s2] = pa;
      *(unsigned*)&B2[(cg + q) * 40 + 2 * s2] = pb;
    }
    __syncthreads();
    bf8 bfr[2], dfr[2];
#pragma unroll
    for (int ni = 0; ni < 2; ++ni) {
      bfr[ni] = *(const bf8*)&B1[(wc * 32 + ni * 16 + llo) * 40 + lhi * 8];
      dfr[ni] = *(const bf8*)&B2[(wc * 32 + ni * 16 + llo) * 40 + lhi * 8];
    }
#pragma unroll
    for (int mi = 0; mi < 4; ++mi) {
      bf8 a = *(const bf8*)&A1[(wr * 64 + mi * 16 + llo) * 40 + lhi * 8];
      acc[mi][0] = MFMA(a, bfr[0], acc[mi][0]);
      acc[mi][1] = MFMA(a, bfr[1], acc[mi][1]);
    }
#pragma unroll
    for (int mi = 0; mi < 4; ++mi) {
      bf8 c = *(const bf8*)&A2[(wr * 64 + mi * 16 + llo) * 40 + lhi * 8];
      acc[mi][0] = MFMA(c, dfr[0], acc[mi][0]);
      acc[mi][1] = MFMA(c, dfr[1], acc[mi][1]);
    }
    __syncthreads();
  }
  short* tp = t4 + (long)b * 8388608 + (long)h * NNe;
#pragma unroll
  for (int mi = 0; mi < 4; ++mi)
#pragma unroll
    for (int ni = 0; ni < 2; ++ni) {
      int row = i0 + wr * 64 + mi * 16 + lhi * 4;
      int col = k0 + wc * 32 + ni * 16 + llo;
#pragma unroll
      for (int r = 0; r < 4; ++r) tp[(long)(row + r) * 512 + col] = f2bf(acc[mi][ni][r]);
    }
}

// --- fused OPM-recompute + triangle update + pair FFN (128 elems / 512 thr) ---
__global__ __launch_bounds__(512) void upd_pffn_fused(
    const float* __restrict__ pin, float* __restrict__ pout,
    const short* __restrict__ t4,
    const short* __restrict__ Tb, const short* __restrict__ bo_bf,
    const float* __restrict__ b_out, const float* __restrict__ op_norm,
    const float* __restrict__ g_tm, const float* __restrict__ b_tm,
    const short* __restrict__ wg_a, const float* __restrict__ b_g,
    const short* __restrict__ wz_a, const float* __restrict__ b_z,
    const float* __restrict__ g_tmo, const float* __restrict__ b_tmo,
    const float* __restrict__ g_pf, const float* __restrict__ b_pf,
    const short* __restrict__ w1_a, const float* __restrict__ b1,
    const short* __restrict__ w2_a, const float* __restrict__ b2) {
  __shared__ __align__(16) short Zb[2][64 * 72];
  __shared__ __align__(16) short Tlb[2][64 * 40];
  __shared__ __align__(16) short Wbuf[64 * 72];
  __shared__ __align__(16) short Wzb[64 * 36];
  __shared__ float spS[2][64][9];
  __shared__ float spQ[2][64][9];
  __shared__ float spB[2][4][2][72];
  int tid = threadIdx.x;
  int grp = tid >> 8;          // 0/1: element group
  int t = tid & 255;
  long e0 = (long)blockIdx.x * 128 + grp * 64;
  int bbt = (int)(e0 >> 18);
  long el = e0 & (NNe - 1);
  long growT = e0 >> 9;
  int jt = (int)((e0 >> 6) & 7);
  int wv = t >> 6, lane = t & 63;
  int wr = wv >> 1, wc = wv & 1;
  int lhi = lane >> 4, llo = lane & 15;
  int chb = wr * 32 + lhi * 4;
  int fc = lhi * 8;
  int fr0 = wr * 32 + llo, fr1 = fr0 + 16;
  int br0 = wc * 32 + llo, br1 = br0 + 16;
  int r0 = tid >> 3, c0 = (tid & 7) * 8;
  bf8 w1r, w2r;
  {
    *(bf8*)&Wbuf[r0 * 72 + c0] = *(const bf8*)(wg_a + r0 * 64 + c0);
    w1r = *(const bf8*)(w1_a + r0 * 64 + c0);
    w2r = *(const bf8*)(w2_a + r0 * 64 + c0);
    int rz = tid >> 3, cz = (tid & 7) * 4;
    *(bf4*)&Wzb[rz * 36 + cz] = *(const bf4*)(wz_a + rz * 32 + cz);
  }
  f32x4 x[2][2];
#pragma unroll
  for (int mi = 0; mi < 2; ++mi)
#pragma unroll
    for (int ni = 0; ni < 2; ++ni)
      x[mi][ni] = *(const f32x4*)(pin + (e0 + wc * 32 + ni * 16 + llo) * 64 +
                                  chb + mi * 16);
  {
    f32x4 acc[2][2] = {};
    bf8 a0 = *(const bf8*)(Tb + growT * 2048 + (long)fr0 * 32 + fc);
    bf8 a1 = *(const bf8*)(Tb + growT * 2048 + (long)fr1 * 32 + fc);
    bf8 b0 = *(const bf8*)(bo_bf + ((long)bbt * 512 + jt * 64 + br0) * 32 + fc);
    bf8 b1 = *(const bf8*)(bo_bf + ((long)bbt * 512 + jt * 64 + br1) * 32 + fc);
    acc[0][0] = MFMA(a0, b0, acc[0][0]);
    acc[0][1] = MFMA(a0, b1, acc[0][1]);
    acc[1][0] = MFMA(a1, b0, acc[1][0]);
    acc[1][1] = MFMA(a1, b1, acc[1][1]);
    float nrm = op_norm[0];
#pragma unroll
    for (int mi = 0; mi < 2; ++mi) {
      f32x4 bo4 = *(const f32x4*)(b_out + chb + mi * 16);
#pragma unroll
      for (int ni = 0; ni < 2; ++ni)
#pragma unroll
        for (int r = 0; r < 4; ++r)
          x[mi][ni][r] += (acc[mi][ni][r] + bo4[r]) * nrm;
    }
  }
#pragma unroll
  for (int ni = 0; ni < 2; ++ni) {
    float s = 0.f, ss = 0.f;
#pragma unroll
    for (int mi = 0; mi < 2; ++mi)
#pragma unroll
      for (int r = 0; r < 4; ++r) { float v = x[mi][ni][r]; s += v; ss += v * v; }
    int e = wc * 32 + ni * 16 + llo;
    spS[grp][e][wr * 4 + lhi] = s;
    spQ[grp][e][wr * 4 + lhi] = ss;
  }
  const short* t_in = t4 + (long)bbt * 8388608;
  int te = t & 63, tq = t >> 6;
  float tt[8];
  {
    float sB = 0.f, ssB = 0.f;
#pragma unroll
    for (int k = 0; k < 8; ++k) {
      float v = bf2f(t_in[(long)(tq * 8 + k) * NNe + el + te]);
      tt[k] = v; sB += v; ssB += v * v;
    }
    spB[grp][tq][0][te] = sB; spB[grp][tq][1][te] = ssB;
  }
  __syncthreads();   // (1)
  {
    float ts = spB[grp][0][0][te] + spB[grp][1][0][te] + spB[grp][2][0][te] +
               spB[grp][3][0][te];
    float tss = spB[grp][0][1][te] + spB[grp][1][1][te] + spB[grp][2][1][te] +
                spB[grp][3][1][te];
    float mu = ts * 0.03125f, var = tss * 0.03125f - mu * mu;
    float rs = rsqrtf(var + LNEPS);
    bf8 pk;
#pragma unroll
    for (int k = 0; k < 8; ++k) {
      int c = tq * 8 + k;
      pk[k] = f2bf((tt[k] - mu) * rs * g_tmo[c] + b_tmo[c]);
    }
    *(bf8*)&Tlb[grp][te * 40 + tq * 8] = pk;
  }
  float mu1[2], rs1[2];
#pragma unroll
  for (int ni = 0; ni < 2; ++ni) {
    int e = wc * 32 + ni * 16 + llo;
    float s = 0.f, q2 = 0.f;
#pragma unroll
    for (int k = 0; k < 8; ++k) { s += spS[grp][e][k]; q2 += spQ[grp][e][k]; }
    float mu = s * 0.015625f, var = q2 * 0.015625f - mu * mu;
    mu1[ni] = mu; rs1[ni] = rsqrtf(var + LNEPS);
  }
#pragma unroll
  for (int mi = 0; mi < 2; ++mi) {
    f32x4 gv = *(const f32x4*)(g_tm + chb + mi * 16);
    f32x4 bv = *(const f32x4*)(b_tm + chb + mi * 16);
#pragma unroll
    for (int ni = 0; ni < 2; ++ni) {
      int e = wc * 32 + ni * 16 + llo;
      bf4 pk;
#pragma unroll
      for (int r = 0; r < 4; ++r)
        pk[r] = f2bf((x[mi][ni][r] - mu1[ni]) * rs1[ni] * gv[r] + bv[r]);
      *(bf4*)&Zb[grp][e * 72 + chb + mi * 16] = pk;
    }
  }
  __syncthreads();   // (2)
  f32x4 accg[2][2] = {};
  f32x4 accz[2][2] = {};
#pragma unroll
  for (int ks = 0; ks < 2; ++ks) {
    bf8 a0 = *(const bf8*)&Wbuf[fr0 * 72 + ks * 32 + fc];
    bf8 a1 = *(const bf8*)&Wbuf[fr1 * 72 + ks * 32 + fc];
    bf8 z0 = *(const bf8*)&Zb[grp][br0 * 72 + ks * 32 + fc];
    bf8 z1 = *(const bf8*)&Zb[grp][br1 * 72 + ks * 32 + fc];
    accg[0][0] = MFMA(a0, z0, accg[0][0]);
    accg[0][1] = MFMA(a0, z1, accg[0][1]);
    accg[1][0] = MFMA(a1, z0, accg[1][0]);
    accg[1][1] = MFMA(a1, z1, accg[1][1]);
  }
  {
    bf8 a0 = *(const bf8*)&Wzb[fr0 * 36 + fc];
    bf8 a1 = *(const bf8*)&Wzb[fr1 * 36 + fc];
    bf8 t0 = *(const bf8*)&Tlb[grp][br0 * 40 + fc];
    bf8 t1 = *(const bf8*)&Tlb[grp][br1 * 40 + fc];
    accz[0][0] = MFMA(a0, t0, accz[0][0]);
    accz[0][1] = MFMA(a0, t1, accz[0][1]);
    accz[1][0] = MFMA(a1, t0, accz[1][0]);
    accz[1][1] = MFMA(a1, t1, accz[1][1]);
  }
#pragma unroll
  for (int mi = 0; mi < 2; ++mi) {
    f32x4 bgv = *(const f32x4*)(b_g + chb + mi * 16);
    f32x4 bzv = *(const f32x4*)(b_z + chb + mi * 16);
#pragma unroll
    for (int ni = 0; ni < 2; ++ni)
#pragma unroll
      for (int r = 0; r < 4; ++r)
        x[mi][ni][r] += (accg[mi][ni][r] + bgv[r]) * (accz[mi][ni][r] + bzv[r]);
  }
#pragma unroll
  for (int ni = 0; ni < 2; ++ni) {
    float s = 0.f, ss = 0.f;
#pragma unroll
    for (int mi = 0; mi < 2; ++mi)
#pragma unroll
      for (int r = 0; r < 4; ++r) { float v = x[mi][ni][r]; s += v; ss += v * v; }
    int e = wc * 32 + ni * 16 + llo;
    spS[grp][e][wr * 4 + lhi] = s;
    spQ[grp][e][wr * 4 + lhi] = ss;
  }
  __syncthreads();   // (3)
  *(bf8*)&Wbuf[r0 * 72 + c0] = w1r;
#pragma unroll
  for (int ni = 0; ni < 2; ++ni) {
    int e = wc * 32 + ni * 16 + llo;
    float s = 0.f, q2 = 0.f;
#pragma unroll
    for (int k = 0; k < 8; ++k) { s += spS[grp][e][k]; q2 += spQ[grp][e][k]; }
    float mu = s * 0.015625f, var = q2 * 0.015625f - mu * mu;
    mu1[ni] = mu; rs1[ni] = rsqrtf(var + LNEPS);
  }
#pragma unroll
  for (int mi = 0; mi < 2; ++mi) {
    f32x4 gv = *(const f32x4*)(g_pf + chb + mi * 16);
    f32x4 bv = *(const f32x4*)(b_pf + chb + mi * 16);
#pragma unroll
    for (int ni = 0; ni < 2; ++ni) {
      int e = wc * 32 + ni * 16 + llo;
      bf4 pk;
#pragma unroll
      for (int r = 0; r < 4; ++r)
        pk[r] = f2bf((x[mi][ni][r] - mu1[ni]) * rs1[ni] * gv[r] + bv[r]);
      *(bf4*)&Zb[grp][e * 72 + chb + mi * 16] = pk;
    }
  }
  __syncthreads();   // (4)
  f32x4 acc1[2][2] = {};
#pragma unroll
  for (int ks = 0; ks < 2; ++ks) {
    bf8 a0 = *(const bf8*)&Wbuf[fr0 * 72 + ks * 32 + fc];
    bf8 a1 = *(const bf8*)&Wbuf[fr1 * 72 + ks * 32 + fc];
    bf8 z0 = *(const bf8*)&Zb[grp][br0 * 72 + ks * 32 + fc];
    bf8 z1 = *(const bf8*)&Zb[grp][br1 * 72 + ks * 32 + fc];
    acc1[0][0] = MFMA(a0, z0, acc1[0][0]);
    acc1[0][1] = MFMA(a0, z1, acc1[0][1]);
    acc1[1][0] = MFMA(a1, z0, acc1[1][0]);
    acc1[1][1] = MFMA(a1, z1, acc1[1][1]);
  }
  __syncthreads();   // (5)
  *(bf8*)&Wbuf[r0 * 72 + c0] = w2r;
#pragma unroll
  for (int mi = 0; mi < 2; ++mi) {
    f32x4 bv = *(const f32x4*)(b1 + chb + mi * 16);
#pragma unroll
    for (int ni = 0; ni < 2; ++ni) {
      int e = wc * 32 + ni * 16 + llo;
      bf4 pk;
#pragma unroll
      for (int r = 0; r < 4; ++r) pk[r] = f2bf(gelu_fast(acc1[mi][ni][r] + bv[r]));
      *(bf4*)&Zb[grp][e * 72 + chb + mi * 16] = pk;
    }
  }
  __syncthreads();   // (6)
  f32x4 acc2[2][2] = {};
#pragma unroll
  for (int ks = 0; ks < 2; ++ks) {
    bf8 a0 = *(const bf8*)&Wbuf[fr0 * 72 + ks * 32 + fc];
    bf8 a1 = *(const bf8*)&Wbuf[fr1 * 72 + ks * 32 + fc];
    bf8 z0 = *(const bf8*)&Zb[grp][br0 * 72 + ks * 32 + fc];
    bf8 z1 = *(const bf8*)&Zb[grp][br1 * 72 + ks * 32 + fc];
    acc2[0][0] = MFMA(a0, z0, acc2[0][0]);
    acc2[0][1] = MFMA(a0, z1, acc2[0][1]);
    acc2[1][0] = MFMA(a1, z0, acc2[1][0]);
    acc2[1][1] = MFMA(a1, z1, acc2[1][1]);
  }
#pragma unroll
  for (int mi = 0; mi < 2; ++mi) {
    f32x4 bv = *(const f32x4*)(b2 + chb + mi * 16);
#pragma unroll
    for (int ni = 0; ni < 2; ++ni) {
#pragma unroll
      for (int r = 0; r < 4; ++r) x[mi][ni][r] += acc2[mi][ni][r] + bv[r];
      *(f32x4*)(pout + (e0 + wc * 32 + ni * 16 + llo) * 64 + chb + mi * 16) =
          x[mi][ni];
    }
  }
}

extern "C" void kernel_launch(void* const* d_in, const int* in_sizes, int n_in,
                              void* d_out, int out_size, void* d_ws, size_t ws_size,
                              hipStream_t stream) {
  const float* x = (const float*)d_in[0];
  const float* pair = (const float*)d_in[1];
  const float* attn_mask = (const float*)d_in[2];
  const float* op_mask = (const float*)d_in[3];
  const float* op_norm = (const float*)d_in[4];
  const float* wq = (const float*)d_in[6];
  const float* wk = (const float*)d_in[7];
  const float* wv_ = (const float*)d_in[8];
  const float* wg = (const float*)d_in[9];
  const float* bg = (const float*)d_in[10];
  const float* wo = (const float*)d_in[11];
  const float* bo = (const float*)d_in[12];
  const float* ln_pair_g = (const float*)d_in[13];
  const float* ln_pair_b = (const float*)d_in[14];
  const float* wb = (const float*)d_in[15];
  const float* bb = (const float*)d_in[16];
  const float* ln_attn_g = (const float*)d_in[17];
  const float* ln_attn_b = (const float*)d_in[18];
  const float* ln_ffn_g = (const float*)d_in[19];
  const float* ln_ffn_b = (const float*)d_in[20];
  const float* w_ffn1 = (const float*)d_in[21];
  const float* b_ffn1 = (const float*)d_in[22];
  const float* w_ffn2 = (const float*)d_in[23];
  const float* b_ffn2 = (const float*)d_in[24];
  const float* ln_opm_g = (const float*)d_in[25];
  const float* ln_opm_b = (const float*)d_in[26];
  const float* w_opm_in = (const float*)d_in[27];
  const float* b_opm_in = (const float*)d_in[28];
  const float* w_opm_out = (const float*)d_in[29];
  const float* b_opm_out = (const float*)d_in[30];
  const float* ln_tm_g = (const float*)d_in[31];
  const float* ln_tm_b = (const float*)d_in[32];
  const float* w_tm_abp = (const float*)d_in[33];
  const float* b_tm_abp = (const float*)d_in[34];
  const float* w_tm_abg = (const float*)d_in[35];
  const float* b_tm_abg = (const float*)d_in[36];
  const float* w_tm_g = (const float*)d_in[37];
  const float* b_tm_g = (const float*)d_in[38];
  const float* w_tm_z = (const float*)d_in[39];
  const float* b_tm_z = (const float*)d_in[40];
  const float* ln_tmo_g = (const float*)d_in[41];
  const float* ln_tmo_b = (const float*)d_in[42];
  const float* ln_pffn_g = (const float*)d_in[43];
  const float* ln_pffn_b = (const float*)d_in[44];
  const float* w_pffn1 = (const float*)d_in[45];
  const float* b_pffn1 = (const float*)d_in[46];
  const float* w_pffn2 = (const float*)d_in[47];
  const float* b_pffn2 = (const float*)d_in[48];

  float* ws = (float*)d_ws;
  short* wbf = (short*)ws;
  short* wq_bf = wbf + 0;            // contiguous [3072][768] qkvg block
  short* wo_bf = wbf + 2359296;
  short* wf1_bf = wbf + 2949120;
  short* wf2_bf = wbf + 5308416;
  short* wop_bf = wbf + 7667712;
  short* wb_a = wbf + 7716864;
  short* wabp_a = wbf + 7717376;
  short* wabg_a = wbf + 7721472;
  short* wtg_a = wbf + 7725568;
  short* wtz_a = wbf + 7729664;
  short* wp1_a = wbf + 7731712;
  short* wp2_a = wbf + 7735808;

  short* h_bf = (short*)(ws + 3869952);
  short* q_bf = (short*)(ws + 4656384);
  short* k_bf = (short*)(ws + 5442816);
  short* vT_bf = (short*)(ws + 6229248);
  float* gb = ws + 7015680;
  short* gb_bf = (short*)(ws + 10161408);
  float* x1b = ws + 10947840;
  short* biasb_bf = (short*)(ws + 12520704);   // 8388608 bf16
  short* attn_bf = (short*)(ws + 16715008);    // 8388608 bf16
  short* mffn_bf = (short*)(ws + 20909312);    // 6291456 bf16
  float* abb = ws + 24055040;                  // 131072 f32
  short* abb_bf = (short*)(ws + 24186112);     // 65536 bf16 (bo, all batches)
  short* Tb_bf = (short*)(ws + 24218880);      // 4194304 bf16 (all batches)
  short* aN4 = (short*)(ws + 59870464);        // 4 x 8388608 bf16
  short* bN4 = (short*)(ws + 76647680);
  short* t4 = (short*)(ws + 93424896);

  float* xo = (float*)d_out;
  float* pair1 = xo + 1572864;

  const float qscale = 0.1020620726159658f;  // 96^-0.5

  // --- weight casts (merged) ---
  castw_kernel<<<30234, 256, 0, stream>>>(wq, wk, wv_, wg, wo, w_ffn1, w_ffn2, w_opm_in,
                                          wb, w_tm_abp, w_tm_abg, w_tm_g, w_tm_z,
                                          w_pffn1, w_pffn2, wbf, qscale);
  // --- attention ---
  ln_bf_kernel<<<2048, 256, 0, stream>>>(x, h_bf, ln_attn_g, ln_attn_b, 768);
  gemm_qkvg<<<dim3(24, 16, 1), 256, 0, stream>>>(h_bf, wq_bf, q_bf, k_bf, vT_bf, gb, bg);
  pair_bias_mfma<<<8192, 512, 0, stream>>>(pair, ln_pair_g, ln_pair_b, wb_a, bb, biasb_bf);
  attn_fused<<<dim3(32, 8, 4), 256, 0, stream>>>(q_bf, k_bf, biasb_bf, attn_mask, attn_bf);
  // AV with fused output gate
  gemm_bf<<<dim3(2, 8, 32), 256, 0, stream>>>(attn_bf, 512, 2097152, 262144,
                                              vT_bf, 512, 393216, 49152,
                                              nullptr, 0, 393216, 96, gb_bf, 768,
                                              gb, 768, 393216, 96, nullptr,
                                              512, 96, 512, 2, 0, 8);
  gemm128<<<dim3(6, 16, 1), 256, 0, stream>>>(gb_bf, wo_bf, 768, x, bo, x1b);
  // --- FFN ---
  ln_bf_kernel<<<2048, 256, 0, stream>>>(x1b, h_bf, ln_ffn_g, ln_ffn_b, 768);
  gemm_ffn1<<<dim3(24, 16, 1), 256, 0, stream>>>(h_bf, wf1_bf, mffn_bf, b_ffn1);
  gemm128<<<dim3(6, 16, 1), 256, 0, stream>>>(mffn_bf, wf2_bf, 3072, x1b, b_ffn2, xo);
  // --- outer product mean prep ---
  ln_bf_kernel<<<2048, 256, 0, stream>>>(xo, h_bf, ln_opm_g, ln_opm_b, 768);
  gemm_bf<<<dim3(1, 32, 1), 256, 0, stream>>>(h_bf, 768, 0, 0, wop_bf, 768, 0, 0,
                                              abb, 64, 0, 0, nullptr, 0,
                                              nullptr, 0, 0, 0, b_opm_in,
                                              2048, 64, 768, 0, 0, 1);
  opmask_kernel<<<512, 256, 0, stream>>>(abb, op_mask, abb_bf);
  opm_T_kernel<<<dim3(256, 64, 1), dim3(32, 8, 1), 0, stream>>>(abb, w_opm_out, Tb_bf);
  // --- pair stack (batched over all 4 batches) ---
  opm_ab_fused<<<dim3(4, 512, 4), 512, 0, stream>>>(
      pair, Tb_bf, abb_bf, b_opm_out, op_norm,
      ln_tm_g, ln_tm_b, wabp_a, b_tm_abp, wabg_a, b_tm_abg, aN4, bN4);
  tm_tri_mfma<<<dim3(4, 4, 128), 512, 0, stream>>>(aN4, bN4, t4);
  upd_pffn_fused<<<8192, 512, 0, stream>>>(
      pair, pair1, t4, Tb_bf, abb_bf, b_opm_out, op_norm,
      ln_tm_g, ln_tm_b, wtg_a, b_tm_g, wtz_a, b_tm_z,
      ln_tmo_g, ln_tmo_b, ln_pffn_g, ln_pffn_b, wp1_a, b_pffn1, wp2_a, b_pffn2);
}